// Round 6
// baseline (5252.520 us; speedup 1.0000x reference)
//
#include <hip/hip_runtime.h>
#include <hip/hip_bf16.h>
#include <math.h>
#include <stdint.h>

// ViT config
#define VB   32
#define VS   197
#define VD   768
#define VNH  12
#define VDQ  64
#define VL   12
#define VMLP 3072
#define VC   1000
#define VP   256
#define VNPAT 196
#define VTOK (VB * VS)            // 6304
#define TOKD ((size_t)VTOK * VD)  // 4841472 floats

typedef __attribute__((ext_vector_type(4))) float f32x4;
typedef __attribute__((ext_vector_type(8))) short short8;

typedef __attribute__((address_space(1))) const unsigned int GU;
typedef __attribute__((address_space(3))) unsigned int LU;

__device__ __forceinline__ void gload_lds16(const void* g, void* l) {
    __builtin_amdgcn_global_load_lds((GU*)(uintptr_t)g, (LU*)(uintptr_t)l, 16, 0, 0);
}

// ---------------------------------------------------------------------------
// patchify: X (B,224,224) fp32 -> patches (B*196, 256) bf16
// ---------------------------------------------------------------------------
__global__ void patchify_k(const float* __restrict__ X, __hip_bfloat16* __restrict__ P) {
    int idx = blockIdx.x * 256 + threadIdx.x;
    const int total = VB * VNPAT * VP;
    if (idx >= total) return;
    int i  = idx & 255;
    int p  = (idx >> 8) % VNPAT;
    int b  = (idx >> 8) / VNPAT;
    int pr = p / 14, pc = p % 14;
    int a  = i >> 4, c2 = i & 15;
    P[idx] = __float2bfloat16(X[((size_t)b * 224 + pr * 16 + a) * 224 + pc * 16 + c2]);
}

// ---------------------------------------------------------------------------
// cls token + sinusoidal positional embeddings (x fp32)
// ---------------------------------------------------------------------------
__global__ void pos_cls_k(float* __restrict__ x, const float* __restrict__ cls) {
    size_t idx = (size_t)blockIdx.x * 256 + threadIdx.x;
    if (idx >= TOKD) return;
    int j = (int)(idx % VD);
    int s = (int)((idx / VD) % VS);
    float jj = (float)(j & ~1);
    float freq = expf(-(jj / (float)VD) * 9.2103403719761836f);
    float ang  = (float)s * freq;
    float pe   = (j & 1) ? cosf(ang) : sinf(ang);
    if (s == 0) x[idx] = cls[j] + pe;
    else        x[idx] += pe;
}

// ---------------------------------------------------------------------------
// LayerNorm: x fp32 -> y bf16. One block per token.
// ---------------------------------------------------------------------------
__global__ __launch_bounds__(256) void layernorm_k(
    const float* __restrict__ x, __hip_bfloat16* __restrict__ y,
    const float* __restrict__ g, const float* __restrict__ bta)
{
    int t = blockIdx.x;
    const float* xr = x + (size_t)t * VD;
    __hip_bfloat16* yr = y + (size_t)t * VD;
    int tid = threadIdx.x;
    float v[3];
    float s = 0.f;
    #pragma unroll
    for (int i = 0; i < 3; i++) { v[i] = xr[tid + i * 256]; s += v[i]; }
    __shared__ float red[8];
    #pragma unroll
    for (int off = 32; off; off >>= 1) s += __shfl_xor(s, off);
    int lane = tid & 63, w = tid >> 6;
    if (!lane) red[w] = s;
    __syncthreads();
    float mu = (red[0] + red[1] + red[2] + red[3]) * (1.f / VD);
    float s2 = 0.f;
    #pragma unroll
    for (int i = 0; i < 3; i++) { float d0 = v[i] - mu; s2 += d0 * d0; }
    #pragma unroll
    for (int off = 32; off; off >>= 1) s2 += __shfl_xor(s2, off);
    if (!lane) red[4 + w] = s2;
    __syncthreads();
    float var = (red[4] + red[5] + red[6] + red[7]) * (1.f / VD);
    float rs = rsqrtf(var + 1e-5f);
    #pragma unroll
    for (int i = 0; i < 3; i++) {
        int j = tid + i * 256;
        yr[j] = __float2bfloat16((v[i] - mu) * rs * g[j] + bta[j]);
    }
}

// ---------------------------------------------------------------------------
// Guarded transpose + bf16 convert: in (R,C) fp32 -> out (C,R) bf16.
// (used for patch_W and head_W only)
// ---------------------------------------------------------------------------
__global__ __launch_bounds__(256) void tpose_k(
    const float* __restrict__ in, __hip_bfloat16* __restrict__ out, int R, int C)
{
    __shared__ float t[32][33];
    int c0 = blockIdx.x * 32, r0 = blockIdx.y * 32;
    int tc = threadIdx.x & 31, tr = threadIdx.x >> 5;
    #pragma unroll
    for (int p = 0; p < 4; p++) {
        int r = r0 + tr + p * 8;
        t[tr + p * 8][tc] = (r < R && c0 + tc < C) ? in[(size_t)r * C + c0 + tc] : 0.f;
    }
    __syncthreads();
    #pragma unroll
    for (int p = 0; p < 4; p++) {
        int c = c0 + tr + p * 8;
        if (c < C && r0 + tc < R)
            out[(size_t)c * R + r0 + tc] = __float2bfloat16(t[tc][tr + p * 8]);
    }
}

// wT layout (shorts): qkv [2304][768] @0; proj [768][768] @OFF_PROJ;
// mlp1 [3072][768] @OFF_M1; mlp2 [768][3072] @OFF_M2.
#define OFF_PROJ (2304 * 768)
#define OFF_M1   (OFF_PROJ + 768 * 768)
#define OFF_M2   (OFF_M1 + 3072 * 768)
#define WT_TOTAL (OFF_M2 + 768 * 3072)   // 7,077,888 shorts = 14.16 MB

// ---------------------------------------------------------------------------
// One-launch per-layer weight prep: transpose+bf16 all of qkv/proj/mlp1/mlp2.
// 6912 blocks of 256 threads; 32x32 tile each (all dims mult of 32).
// ---------------------------------------------------------------------------
__global__ __launch_bounds__(256) void wprep_k(
    const float* __restrict__ Wq, const float* __restrict__ Wk,
    const float* __restrict__ Wv, const float* __restrict__ Wp,
    const float* __restrict__ W1, const float* __restrict__ W2,
    __hip_bfloat16* __restrict__ wT)
{
    __shared__ float t[32][33];
    int z = blockIdx.x;
    const float* src; __hip_bfloat16* dst;
    int C, ldd, r0, c0;
    if (z < 1728) {               // qkv: 36 heads x (24 r-tiles x 2 c-tiles)
        int head = z / 48, tt = z % 48;
        int m = head / VNH, h = head % VNH;
        src = (m == 0 ? Wq : m == 1 ? Wk : Wv) + (size_t)h * VD * VDQ;
        dst = wT + ((size_t)m * VD + h * VDQ) * VD;
        C = VDQ; ldd = VD;
        r0 = (tt >> 1) * 32; c0 = (tt & 1) * 32;
    } else if (z < 2304) {        // proj: 24x24
        int z2 = z - 1728;
        src = Wp; dst = wT + OFF_PROJ;
        C = VD; ldd = VD;
        r0 = (z2 / 24) * 32; c0 = (z2 % 24) * 32;
    } else if (z < 4608) {        // mlp1: src [768][3072] -> 24 x 96 tiles
        int z3 = z - 2304;
        src = W1; dst = wT + OFF_M1;
        C = VMLP; ldd = VD;
        r0 = (z3 / 96) * 32; c0 = (z3 % 96) * 32;
    } else {                      // mlp2: src [3072][768] -> 96 x 24 tiles
        int z4 = z - 4608;
        src = W2; dst = wT + OFF_M2;
        C = VD; ldd = VMLP;
        r0 = (z4 / 24) * 32; c0 = (z4 % 24) * 32;
    }
    int tc = threadIdx.x & 31, tr = threadIdx.x >> 5;
    #pragma unroll
    for (int p = 0; p < 4; p++)
        t[tr + p * 8][tc] = src[(size_t)(r0 + tr + p * 8) * C + c0 + tc];
    __syncthreads();
    #pragma unroll
    for (int p = 0; p < 4; p++)
        dst[(size_t)(c0 + tr + p * 8) * ldd + r0 + tc] = __float2bfloat16(t[tc][tr + p * 8]);
}

// combined qkv bias for ALL layers: cb[l][2304]
__global__ void cball_k(const float* __restrict__ bq, const float* __restrict__ bk,
                        const float* __restrict__ bv, float* __restrict__ cb) {
    int idx = blockIdx.x * 256 + threadIdx.x;
    if (idx >= VL * 3 * VD) return;
    int l = idx / (3 * VD), n = idx % (3 * VD);
    int m = n / VD, wi = n % VD;
    const float* p = (m == 0) ? bq : (m == 1) ? bk : bv;
    cb[idx] = p[l * VD + wi];
}

// extract cls rows of x -> bf16 [32][768]
__global__ void cls_k(const float* __restrict__ x, __hip_bfloat16* __restrict__ out) {
    int idx = blockIdx.x * 256 + threadIdx.x;
    if (idx >= VB * VD) return;
    int b = idx / VD, d = idx % VD;
    out[idx] = __float2bfloat16(x[(size_t)b * VS * VD + d]);
}

// ---------------------------------------------------------------------------
// bf16 MFMA GEMM (m97-style 128x128, BK=64, LDS) — round-3 known-good.
// EPI: 0 = fp32 store w/ patch rowmap; 2 = fp32 accumulate; 4 = fp32 store.
// ---------------------------------------------------------------------------
template<int EPI>
__global__ __launch_bounds__(256) void bgemm_k(
    const __hip_bfloat16* __restrict__ A,
    const __hip_bfloat16* __restrict__ BT,
    const float* __restrict__ bias,
    void* __restrict__ Co,
    int M, int K, int ldc, int Ncols)
{
    __shared__ short A_s[128][64];
    __shared__ short B_s[128][64];
    const int tid = threadIdx.x;
    const int w = tid >> 6, l = tid & 63;
    const int row0 = blockIdx.y * 128, col0 = blockIdx.x * 128;
    const int wm = (w >> 1) << 6, wn = (w & 1) << 6;
    f32x4 acc[4][4] = {};

    const int lr = l >> 3;
    const int sslot = (l & 7) ^ lr;
    int arow[4], brow[4];
    #pragma unroll
    for (int i = 0; i < 4; i++) {
        int r = (4 * w + i) * 8 + lr;
        arow[i] = min(row0 + r, M - 1);
        brow[i] = min(col0 + r, Ncols - 1);
    }
    for (int k0 = 0; k0 < K; k0 += 64) {
        __syncthreads();
        #pragma unroll
        for (int i = 0; i < 4; i++) {
            int ch = 4 * w + i;
            gload_lds16((const void*)(A + (size_t)arow[i] * K + k0 + (sslot << 3)),
                        (void*)(&A_s[ch * 8][0]));
            gload_lds16((const void*)(BT + (size_t)brow[i] * K + k0 + (sslot << 3)),
                        (void*)(&B_s[ch * 8][0]));
        }
        __syncthreads();
        #pragma unroll
        for (int ks = 0; ks < 2; ks++) {
            const int s16 = (ks << 2) + (l >> 4);
            short8 av[4], bv[4];
            #pragma unroll
            for (int i = 0; i < 4; i++) {
                int ar = wm + i * 16 + (l & 15);
                av[i] = *(const short8*)((const char*)&A_s[ar][0] + ((s16 ^ (ar & 7)) << 4));
                int br = wn + i * 16 + (l & 15);
                bv[i] = *(const short8*)((const char*)&B_s[br][0] + ((s16 ^ (br & 7)) << 4));
            }
            #pragma unroll
            for (int i = 0; i < 4; i++)
                #pragma unroll
                for (int j = 0; j < 4; j++)
                    acc[i][j] = __builtin_amdgcn_mfma_f32_16x16x32_bf16(av[i], bv[j], acc[i][j], 0, 0, 0);
        }
    }
    const int rbase = row0 + wm + ((l >> 4) << 2);
    const int cbase = col0 + wn + (l & 15);
    #pragma unroll
    for (int i = 0; i < 4; i++) {
        #pragma unroll
        for (int q = 0; q < 4; q++) {
            int rr = rbase + i * 16 + q;
            if (rr >= M) continue;
            #pragma unroll
            for (int j = 0; j < 4; j++) {
                int c = cbase + j * 16;
                if (c >= Ncols) continue;
                float v = acc[i][j][q] + bias[c];
                if (EPI == 0) {
                    int orow = rr + rr / VNPAT + 1;
                    ((float*)Co)[(size_t)orow * ldc + c] = v;
                } else if (EPI == 1) {
                    ((__hip_bfloat16*)Co)[(size_t)rr * ldc + c] = __float2bfloat16(v);
                } else if (EPI == 2) {
                    ((float*)Co)[(size_t)rr * ldc + c] += v;
                } else if (EPI == 3) {
                    float gl = 0.5f * v * (1.f + erff(v * 0.70710678118654752f));
                    ((__hip_bfloat16*)Co)[(size_t)rr * ldc + c] = __float2bfloat16(gl);
                } else {
                    ((float*)Co)[(size_t)rr * ldc + c] = v;
                }
            }
        }
    }
}

// ---------------------------------------------------------------------------
// bgemm4_k: LDS-free global-direct MFMA GEMM. 128x128 tile, 256 threads,
// 4 waves (2x2), 4x4 16x16x32 frags/wave. A/B fragments loaded straight from
// global (per wave: 16 rows x 64 contiguous bytes per load -> coalesced,
// L1/L2-served). No barriers at all; 2-deep register double-buffer (static
// names per rule #20). Requires K mult of 64. Row indices clamped.
// EPI: 1 = bf16 store; 3 = exact-GELU -> bf16 store.
// ---------------------------------------------------------------------------
template<int EPI>
__global__ __launch_bounds__(256) void bgemm4_k(
    const __hip_bfloat16* __restrict__ A,
    const __hip_bfloat16* __restrict__ BT,
    const float* __restrict__ bias,
    void* __restrict__ Co,
    int M, int K, int ldc, int Ncols)
{
    const int tid = threadIdx.x;
    const int w = tid >> 6, l = tid & 63;
    const int fr = l & 15, g = l >> 4;
    const int row0 = blockIdx.y * 128, col0 = blockIdx.x * 128;
    const int wm = (w >> 1) << 6, wn = (w & 1) << 6;
    f32x4 acc[4][4] = {};
    const __hip_bfloat16 *ap[4], *bp[4];
    #pragma unroll
    for (int i = 0; i < 4; i++) {
        ap[i] = A  + (size_t)min(row0 + wm + i * 16 + fr, M - 1) * K + 8 * g;
        bp[i] = BT + (size_t)min(col0 + wn + i * 16 + fr, Ncols - 1) * K + 8 * g;
    }
    short8 a0[4], b0[4], a1[4], b1[4];
    #pragma unroll
    for (int i = 0; i < 4; i++) {
        a0[i] = *(const short8*)(ap[i]);
        b0[i] = *(const short8*)(bp[i]);
    }
    const int nt = K >> 5;                  // K mult of 64 -> nt even
    for (int t = 0; t < nt; t += 2) {
        const int k1 = (t + 1) << 5;
        #pragma unroll
        for (int i = 0; i < 4; i++) {
            a1[i] = *(const short8*)(ap[i] + k1);
            b1[i] = *(const short8*)(bp[i] + k1);
        }
        #pragma unroll
        for (int i = 0; i < 4; i++)
            #pragma unroll
            for (int j = 0; j < 4; j++)
                acc[i][j] = __builtin_amdgcn_mfma_f32_16x16x32_bf16(a0[i], b0[j], acc[i][j], 0, 0, 0);
        if (t + 2 < nt) {
            const int k2 = (t + 2) << 5;
            #pragma unroll
            for (int i = 0; i < 4; i++) {
                a0[i] = *(const short8*)(ap[i] + k2);
                b0[i] = *(const short8*)(bp[i] + k2);
            }
        }
        #pragma unroll
        for (int i = 0; i < 4; i++)
            #pragma unroll
            for (int j = 0; j < 4; j++)
                acc[i][j] = __builtin_amdgcn_mfma_f32_16x16x32_bf16(a1[i], b1[j], acc[i][j], 0, 0, 0);
    }
    const int rbase = row0 + wm + (g << 2);
    const int cbase = col0 + wn + fr;
    #pragma unroll
    for (int i = 0; i < 4; i++) {
        #pragma unroll
        for (int q = 0; q < 4; q++) {
            int rr = rbase + i * 16 + q;
            if (rr >= M) continue;
            #pragma unroll
            for (int j = 0; j < 4; j++) {
                int c = cbase + j * 16;
                if (c >= Ncols) continue;
                float v = acc[i][j][q] + bias[c];
                if (EPI == 1) {
                    ((__hip_bfloat16*)Co)[(size_t)rr * ldc + c] = __float2bfloat16(v);
                } else {
                    float gl = 0.5f * v * (1.f + erff(v * 0.70710678118654752f));
                    ((__hip_bfloat16*)Co)[(size_t)rr * ldc + c] = __float2bfloat16(gl);
                }
            }
        }
    }
}

// ---------------------------------------------------------------------------
// MFMA attention (unchanged). One block per (b,h), 4 waves.
// ---------------------------------------------------------------------------
__device__ __forceinline__ int swz_idx(int row, int k) {
    return row * 256 + (((k >> 3) ^ (row & 7)) << 3) + (k & 7);
}
__device__ __forceinline__ unsigned pack_bf16(float a, float b) {
    __hip_bfloat16 x = __float2bfloat16(a), y = __float2bfloat16(b);
    unsigned short ux = *(unsigned short*)&x, uy = *(unsigned short*)&y;
    return (unsigned)ux | ((unsigned)uy << 16);
}

__global__ __launch_bounds__(256) void attn3_k(
    const __hip_bfloat16* __restrict__ qkv, __hip_bfloat16* __restrict__ o)
{
    __shared__ short V_t[64 * 256];
    __shared__ short P_s[4][16 * 256];
    const int bh = blockIdx.x;
    const int b = bh / VNH, h = bh % VNH;
    const int tid = threadIdx.x, w = tid >> 6, l = tid & 63;
    const int g = l >> 4, c16 = l & 15;

    const __hip_bfloat16* base = qkv + (size_t)(b * VS) * (3 * VD) + h * VDQ;

    {
        const __hip_bfloat16* vbase = base + 2 * VD;
        int t = tid & 31, e0 = (tid >> 5) * 8;
        #pragma unroll
        for (int it = 0; it < 7; it++) {
            int tt = it * 32 + t;
            if (tt < VS) {
                short8 vv = *(const short8*)(vbase + (size_t)tt * (3 * VD) + e0);
                #pragma unroll
                for (int j = 0; j < 8; j++) V_t[swz_idx(e0 + j, tt)] = vv[j];
            }
        }
        for (int idx = tid; idx < 64 * 27; idx += 256) {
            int e = idx / 27, k = 197 + idx % 27;
            V_t[swz_idx(e, k)] = 0;
        }
    }
    {
        unsigned* p0 = (unsigned*)&P_s[w][swz_idx(c16, 208 + g * 4)];
        p0[0] = 0; p0[1] = 0;
    }
    __syncthreads();

    for (int qt = w; qt < 13; qt += 4) {
        const int q0 = qt * 16;
        int qr = min(q0 + c16, VS - 1);
        const __hip_bfloat16* qp = base + (size_t)qr * (3 * VD) + g * 8;
        short8 qa0 = *(const short8*)(qp);
        short8 qa1 = *(const short8*)(qp + 32);

        f32x4 st[13];
        #pragma unroll
        for (int t = 0; t < 13; t++) {
            int kr = min(t * 16 + c16, VS - 1);
            const __hip_bfloat16* kp = base + VD + (size_t)kr * (3 * VD) + g * 8;
            short8 ka0 = *(const short8*)(kp);
            short8 ka1 = *(const short8*)(kp + 32);
            f32x4 z = {};
            z = __builtin_amdgcn_mfma_f32_16x16x32_bf16(ka0, qa0, z, 0, 0, 0);
            z = __builtin_amdgcn_mfma_f32_16x16x32_bf16(ka1, qa1, z, 0, 0, 0);
            st[t] = z;
        }
        #pragma unroll
        for (int t = 0; t < 13; t++) {
            #pragma unroll
            for (int r = 0; r < 4; r++) {
                float v = st[t][r] * 0.125f;
                if (t == 12 && (4 * g + r) >= 5) v = -3.0e38f;
                st[t][r] = v;
            }
        }
        float m = -3.0e38f;
        #pragma unroll
        for (int t = 0; t < 13; t++)
            #pragma unroll
            for (int r = 0; r < 4; r++) m = fmaxf(m, st[t][r]);
        m = fmaxf(m, __shfl_xor(m, 16));
        m = fmaxf(m, __shfl_xor(m, 32));
        float sum = 0.f;
        #pragma unroll
        for (int t = 0; t < 13; t++)
            #pragma unroll
            for (int r = 0; r < 4; r++) { float e = expf(st[t][r] - m); st[t][r] = e; sum += e; }
        sum += __shfl_xor(sum, 16);
        sum += __shfl_xor(sum, 32);
        float inv = 1.f / sum;
        #pragma unroll
        for (int t = 0; t < 13; t++) {
            int k0 = 16 * t + 4 * g;
            unsigned* pp = (unsigned*)&P_s[w][swz_idx(c16, k0)];
            pp[0] = pack_bf16(st[t][0] * inv, st[t][1] * inv);
            pp[1] = pack_bf16(st[t][2] * inv, st[t][3] * inv);
        }
        f32x4 acc[4] = {};
        #pragma unroll
        for (int ki = 0; ki < 7; ki++) {
            int k0 = ki * 32 + g * 8;
            short8 pa = *(const short8*)&P_s[w][swz_idx(c16, k0)];
            #pragma unroll
            for (int et = 0; et < 4; et++) {
                short8 vbf = *(const short8*)&V_t[swz_idx(et * 16 + c16, k0)];
                acc[et] = __builtin_amdgcn_mfma_f32_16x16x32_bf16(pa, vbf, acc[et], 0, 0, 0);
            }
        }
        #pragma unroll
        for (int et = 0; et < 4; et++) {
            #pragma unroll
            for (int r = 0; r < 4; r++) {
                int q = q0 + 4 * g + r;
                if (q < VS)
                    o[((size_t)(b * VS) + q) * VD + h * VDQ + et * 16 + c16] =
                        __float2bfloat16(acc[et][r]);
            }
        }
    }
}

// ---------------------------------------------------------------------------
extern "C" void kernel_launch(void* const* d_in, const int* in_sizes, int n_in,
                              void* d_out, int out_size, void* d_ws, size_t ws_size,
                              hipStream_t stream) {
    (void)in_sizes; (void)n_in; (void)out_size; (void)ws_size;
    const float* X       = (const float*)d_in[0];
    const float* patch_W = (const float*)d_in[1];
    const float* patch_b = (const float*)d_in[2];
    const float* cls_tok = (const float*)d_in[3];
    const float* ln1_g   = (const float*)d_in[4];
    const float* ln1_b   = (const float*)d_in[5];
    const float* Wq      = (const float*)d_in[6];
    const float* bq      = (const float*)d_in[7];
    const float* Wk      = (const float*)d_in[8];
    const float* bk      = (const float*)d_in[9];
    const float* Wv      = (const float*)d_in[10];
    const float* bv      = (const float*)d_in[11];
    const float* proj_W  = (const float*)d_in[12];
    const float* proj_b  = (const float*)d_in[13];
    const float* ln2_g   = (const float*)d_in[14];
    const float* ln2_b   = (const float*)d_in[15];
    const float* mlp_W1  = (const float*)d_in[16];
    const float* mlp_b1  = (const float*)d_in[17];
    const float* mlp_W2  = (const float*)d_in[18];
    const float* mlp_b2  = (const float*)d_in[19];
    const float* head_W  = (const float*)d_in[20];
    const float* head_b  = (const float*)d_in[21];

    char* ws = (char*)d_ws;
    float*          x   = (float*)ws;                             // 19.37 MB fp32
    __hip_bfloat16* tb  = (__hip_bfloat16*)(ws + 19365888);       // 9.68 MB bf16
    __hip_bfloat16* big = (__hip_bfloat16*)(ws + 29048832);       // 38.73 MB
    __hip_bfloat16* wT  = (__hip_bfloat16*)(ws + 67780608);       // 14.16 MB
    float*          cbA = (float*)(ws + 81936384);                // 110 KB (12x2304)

    cball_k<<<(VL * 3 * VD + 255) / 256, 256, 0, stream>>>(bq, bk, bv, cbA);

    patchify_k<<<(VB * VNPAT * VP + 255) / 256, 256, 0, stream>>>(X, big);
    {
        dim3 g(VD / 32, VP / 32);
        tpose_k<<<g, 256, 0, stream>>>(patch_W, wT, VP, VD);
    }
    {
        dim3 g(VD / 128, VB * VNPAT / 128);
        bgemm_k<0><<<g, 256, 0, stream>>>(big, wT, patch_b, x, VB * VNPAT, VP, VD, VD);
    }
    pos_cls_k<<<(unsigned)((TOKD + 255) / 256), 256, 0, stream>>>(x, cls_tok);

    const size_t WSZ = (size_t)VNH * VD * VDQ;
    for (int l = 0; l < VL; l++) {
        // all 4 weight transposes in one launch
        wprep_k<<<6912, 256, 0, stream>>>(
            Wq + l * WSZ, Wk + l * WSZ, Wv + l * WSZ,
            proj_W + (size_t)l * VD * VD,
            mlp_W1 + (size_t)l * VD * VMLP,
            mlp_W2 + (size_t)l * VMLP * VD, wT);

        layernorm_k<<<VTOK, 256, 0, stream>>>(x, tb, ln1_g + l * VD, ln1_b + l * VD);

        {
            // fused QKV GEMM (global-direct): grid 18 x 50
            dim3 g(3 * VD / 128, (VTOK + 127) / 128);
            bgemm4_k<1><<<g, 256, 0, stream>>>(tb, wT, cbA + l * 3 * VD, big,
                                               VTOK, VD, 3 * VD, 3 * VD);
        }
        attn3_k<<<VB * VNH, 256, 0, stream>>>(big, tb);

        {
            dim3 g(VD / 128, (VTOK + 127) / 128);
            bgemm_k<2><<<g, 256, 0, stream>>>(tb, wT + OFF_PROJ, proj_b + l * VD, x,
                                              VTOK, VD, VD, VD);
        }
        layernorm_k<<<VTOK, 256, 0, stream>>>(x, tb, ln2_g + l * VD, ln2_b + l * VD);
        {
            // MLP1 (global-direct, GELU epilogue): grid 24 x 50
            dim3 g(VMLP / 128, (VTOK + 127) / 128);
            bgemm4_k<3><<<g, 256, 0, stream>>>(tb, wT + OFF_M1, mlp_b1 + l * VMLP, big,
                                               VTOK, VD, VMLP, VMLP);
        }
        {
            dim3 g(VD / 128, (VTOK + 127) / 128);
            bgemm_k<2><<<g, 256, 0, stream>>>(big, wT + OFF_M2, mlp_b2 + l * VD, x,
                                              VTOK, VMLP, VD, VD);
        }
    }
    // head: cls rows -> bf16, transpose head_W, 128^2 MFMA GEMM with N-guard
    cls_k<<<(VB * VD + 255) / 256, 256, 0, stream>>>(x, tb);
    {
        dim3 gt((VC + 31) / 32, VD / 32);
        tpose_k<<<gt, 256, 0, stream>>>(head_W, wT, VD, VC);
        dim3 g((VC + 127) / 128, 1);
        bgemm_k<4><<<g, 256, 0, stream>>>(tb, wT, head_b, (float*)d_out,
                                          VB, VD, VC, VC);
    }
}

// Round 7
// 3656.939 us; speedup vs baseline: 1.4363x; 1.4363x over previous
//
#include <hip/hip_runtime.h>
#include <hip/hip_bf16.h>
#include <math.h>
#include <stdint.h>

// ViT config
#define VB   32
#define VS   197
#define VD   768
#define VNH  12
#define VDQ  64
#define VL   12
#define VMLP 3072
#define VC   1000
#define VP   256
#define VNPAT 196
#define VTOK (VB * VS)            // 6304
#define TOKD ((size_t)VTOK * VD)  // 4841472 floats

typedef __attribute__((ext_vector_type(4))) float f32x4;
typedef __attribute__((ext_vector_type(8))) short short8;

typedef __attribute__((address_space(1))) const unsigned int GU;
typedef __attribute__((address_space(3))) unsigned int LU;

__device__ __forceinline__ void gload_lds16(const void* g, void* l) {
    __builtin_amdgcn_global_load_lds((GU*)(uintptr_t)g, (LU*)(uintptr_t)l, 16, 0, 0);
}

// ---------------------------------------------------------------------------
// patchify: X (B,224,224) fp32 -> patches (B*196, 256) bf16
// ---------------------------------------------------------------------------
__global__ void patchify_k(const float* __restrict__ X, __hip_bfloat16* __restrict__ P) {
    int idx = blockIdx.x * 256 + threadIdx.x;
    const int total = VB * VNPAT * VP;
    if (idx >= total) return;
    int i  = idx & 255;
    int p  = (idx >> 8) % VNPAT;
    int b  = (idx >> 8) / VNPAT;
    int pr = p / 14, pc = p % 14;
    int a  = i >> 4, c2 = i & 15;
    P[idx] = __float2bfloat16(X[((size_t)b * 224 + pr * 16 + a) * 224 + pc * 16 + c2]);
}

// ---------------------------------------------------------------------------
// cls token + sinusoidal positional embeddings (x fp32)
// ---------------------------------------------------------------------------
__global__ void pos_cls_k(float* __restrict__ x, const float* __restrict__ cls) {
    size_t idx = (size_t)blockIdx.x * 256 + threadIdx.x;
    if (idx >= TOKD) return;
    int j = (int)(idx % VD);
    int s = (int)((idx / VD) % VS);
    float jj = (float)(j & ~1);
    float freq = expf(-(jj / (float)VD) * 9.2103403719761836f);
    float ang  = (float)s * freq;
    float pe   = (j & 1) ? cosf(ang) : sinf(ang);
    if (s == 0) x[idx] = cls[j] + pe;
    else        x[idx] += pe;
}

// ---------------------------------------------------------------------------
// LayerNorm: x fp32 -> y bf16. One block per token.
// ---------------------------------------------------------------------------
__global__ __launch_bounds__(256) void layernorm_k(
    const float* __restrict__ x, __hip_bfloat16* __restrict__ y,
    const float* __restrict__ g, const float* __restrict__ bta)
{
    int t = blockIdx.x;
    const float* xr = x + (size_t)t * VD;
    __hip_bfloat16* yr = y + (size_t)t * VD;
    int tid = threadIdx.x;
    float v[3];
    float s = 0.f;
    #pragma unroll
    for (int i = 0; i < 3; i++) { v[i] = xr[tid + i * 256]; s += v[i]; }
    __shared__ float red[8];
    #pragma unroll
    for (int off = 32; off; off >>= 1) s += __shfl_xor(s, off);
    int lane = tid & 63, w = tid >> 6;
    if (!lane) red[w] = s;
    __syncthreads();
    float mu = (red[0] + red[1] + red[2] + red[3]) * (1.f / VD);
    float s2 = 0.f;
    #pragma unroll
    for (int i = 0; i < 3; i++) { float d0 = v[i] - mu; s2 += d0 * d0; }
    #pragma unroll
    for (int off = 32; off; off >>= 1) s2 += __shfl_xor(s2, off);
    if (!lane) red[4 + w] = s2;
    __syncthreads();
    float var = (red[4] + red[5] + red[6] + red[7]) * (1.f / VD);
    float rs = rsqrtf(var + 1e-5f);
    #pragma unroll
    for (int i = 0; i < 3; i++) {
        int j = tid + i * 256;
        yr[j] = __float2bfloat16((v[i] - mu) * rs * g[j] + bta[j]);
    }
}

// ---------------------------------------------------------------------------
// Guarded transpose + bf16 convert: in (R,C) fp32 -> out (C,R) bf16.
// (used for patch_W and head_W only)
// ---------------------------------------------------------------------------
__global__ __launch_bounds__(256) void tpose_k(
    const float* __restrict__ in, __hip_bfloat16* __restrict__ out, int R, int C)
{
    __shared__ float t[32][33];
    int c0 = blockIdx.x * 32, r0 = blockIdx.y * 32;
    int tc = threadIdx.x & 31, tr = threadIdx.x >> 5;
    #pragma unroll
    for (int p = 0; p < 4; p++) {
        int r = r0 + tr + p * 8;
        t[tr + p * 8][tc] = (r < R && c0 + tc < C) ? in[(size_t)r * C + c0 + tc] : 0.f;
    }
    __syncthreads();
    #pragma unroll
    for (int p = 0; p < 4; p++) {
        int c = c0 + tr + p * 8;
        if (c < C && r0 + tc < R)
            out[(size_t)c * R + r0 + tc] = __float2bfloat16(t[tc][tr + p * 8]);
    }
}

// wT layout (shorts): qkv [2304][768] @0; proj [768][768] @OFF_PROJ;
// mlp1 [3072][768] @OFF_M1; mlp2 [768][3072] @OFF_M2.
#define OFF_PROJ (2304 * 768)
#define OFF_M1   (OFF_PROJ + 768 * 768)
#define OFF_M2   (OFF_M1 + 3072 * 768)

// ---------------------------------------------------------------------------
// One-launch per-layer weight prep: transpose+bf16 all of qkv/proj/mlp1/mlp2.
// 6912 blocks of 256 threads; 32x32 tile each (all dims mult of 32).
// ---------------------------------------------------------------------------
__global__ __launch_bounds__(256) void wprep_k(
    const float* __restrict__ Wq, const float* __restrict__ Wk,
    const float* __restrict__ Wv, const float* __restrict__ Wp,
    const float* __restrict__ W1, const float* __restrict__ W2,
    __hip_bfloat16* __restrict__ wT)
{
    __shared__ float t[32][33];
    int z = blockIdx.x;
    const float* src; __hip_bfloat16* dst;
    int C, ldd, r0, c0;
    if (z < 1728) {               // qkv: 36 heads x (24 r-tiles x 2 c-tiles)
        int head = z / 48, tt = z % 48;
        int m = head / VNH, h = head % VNH;
        src = (m == 0 ? Wq : m == 1 ? Wk : Wv) + (size_t)h * VD * VDQ;
        dst = wT + ((size_t)m * VD + h * VDQ) * VD;
        C = VDQ; ldd = VD;
        r0 = (tt >> 1) * 32; c0 = (tt & 1) * 32;
    } else if (z < 2304) {        // proj: 24x24
        int z2 = z - 1728;
        src = Wp; dst = wT + OFF_PROJ;
        C = VD; ldd = VD;
        r0 = (z2 / 24) * 32; c0 = (z2 % 24) * 32;
    } else if (z < 4608) {        // mlp1: src [768][3072] -> 24 x 96 tiles
        int z3 = z - 2304;
        src = W1; dst = wT + OFF_M1;
        C = VMLP; ldd = VD;
        r0 = (z3 / 96) * 32; c0 = (z3 % 96) * 32;
    } else {                      // mlp2: src [3072][768] -> 96 x 24 tiles
        int z4 = z - 4608;
        src = W2; dst = wT + OFF_M2;
        C = VD; ldd = VMLP;
        r0 = (z4 / 24) * 32; c0 = (z4 % 24) * 32;
    }
    int tc = threadIdx.x & 31, tr = threadIdx.x >> 5;
    #pragma unroll
    for (int p = 0; p < 4; p++)
        t[tr + p * 8][tc] = src[(size_t)(r0 + tr + p * 8) * C + c0 + tc];
    __syncthreads();
    #pragma unroll
    for (int p = 0; p < 4; p++)
        dst[(size_t)(c0 + tr + p * 8) * ldd + r0 + tc] = __float2bfloat16(t[tc][tr + p * 8]);
}

// combined qkv bias for ALL layers: cb[l][2304]
__global__ void cball_k(const float* __restrict__ bq, const float* __restrict__ bk,
                        const float* __restrict__ bv, float* __restrict__ cb) {
    int idx = blockIdx.x * 256 + threadIdx.x;
    if (idx >= VL * 3 * VD) return;
    int l = idx / (3 * VD), n = idx % (3 * VD);
    int m = n / VD, wi = n % VD;
    const float* p = (m == 0) ? bq : (m == 1) ? bk : bv;
    cb[idx] = p[l * VD + wi];
}

// extract cls rows of x -> bf16 [32][768]
__global__ void cls_k(const float* __restrict__ x, __hip_bfloat16* __restrict__ out) {
    int idx = blockIdx.x * 256 + threadIdx.x;
    if (idx >= VB * VD) return;
    int b = idx / VD, d = idx % VD;
    out[idx] = __float2bfloat16(x[(size_t)b * VS * VD + d]);
}

// ---------------------------------------------------------------------------
// bf16 MFMA GEMM (m97-style 128x128, BK=64, LDS) — round-3 known-good.
// EPI: 0 = fp32 store w/ patch rowmap; 1 = bf16 store; 2 = fp32 accumulate;
//      3 = exact-GELU -> bf16; 4 = plain fp32 store.
// ---------------------------------------------------------------------------
template<int EPI>
__global__ __launch_bounds__(256) void bgemm_k(
    const __hip_bfloat16* __restrict__ A,
    const __hip_bfloat16* __restrict__ BT,
    const float* __restrict__ bias,
    void* __restrict__ Co,
    int M, int K, int ldc, int Ncols)
{
    __shared__ short A_s[128][64];
    __shared__ short B_s[128][64];
    const int tid = threadIdx.x;
    const int w = tid >> 6, l = tid & 63;
    const int row0 = blockIdx.y * 128, col0 = blockIdx.x * 128;
    const int wm = (w >> 1) << 6, wn = (w & 1) << 6;
    f32x4 acc[4][4] = {};

    const int lr = l >> 3;
    const int sslot = (l & 7) ^ lr;
    int arow[4], brow[4];
    #pragma unroll
    for (int i = 0; i < 4; i++) {
        int r = (4 * w + i) * 8 + lr;
        arow[i] = min(row0 + r, M - 1);
        brow[i] = min(col0 + r, Ncols - 1);
    }
    for (int k0 = 0; k0 < K; k0 += 64) {
        __syncthreads();
        #pragma unroll
        for (int i = 0; i < 4; i++) {
            int ch = 4 * w + i;
            gload_lds16((const void*)(A + (size_t)arow[i] * K + k0 + (sslot << 3)),
                        (void*)(&A_s[ch * 8][0]));
            gload_lds16((const void*)(BT + (size_t)brow[i] * K + k0 + (sslot << 3)),
                        (void*)(&B_s[ch * 8][0]));
        }
        __syncthreads();
        #pragma unroll
        for (int ks = 0; ks < 2; ks++) {
            const int s16 = (ks << 2) + (l >> 4);
            short8 av[4], bv[4];
            #pragma unroll
            for (int i = 0; i < 4; i++) {
                int ar = wm + i * 16 + (l & 15);
                av[i] = *(const short8*)((const char*)&A_s[ar][0] + ((s16 ^ (ar & 7)) << 4));
                int br = wn + i * 16 + (l & 15);
                bv[i] = *(const short8*)((const char*)&B_s[br][0] + ((s16 ^ (br & 7)) << 4));
            }
            #pragma unroll
            for (int i = 0; i < 4; i++)
                #pragma unroll
                for (int j = 0; j < 4; j++)
                    acc[i][j] = __builtin_amdgcn_mfma_f32_16x16x32_bf16(av[i], bv[j], acc[i][j], 0, 0, 0);
        }
    }
    const int rbase = row0 + wm + ((l >> 4) << 2);
    const int cbase = col0 + wn + (l & 15);
    #pragma unroll
    for (int i = 0; i < 4; i++) {
        #pragma unroll
        for (int q = 0; q < 4; q++) {
            int rr = rbase + i * 16 + q;
            if (rr >= M) continue;
            #pragma unroll
            for (int j = 0; j < 4; j++) {
                int c = cbase + j * 16;
                if (c >= Ncols) continue;
                float v = acc[i][j][q] + bias[c];
                if (EPI == 0) {
                    int orow = rr + rr / VNPAT + 1;
                    ((float*)Co)[(size_t)orow * ldc + c] = v;
                } else if (EPI == 1) {
                    ((__hip_bfloat16*)Co)[(size_t)rr * ldc + c] = __float2bfloat16(v);
                } else if (EPI == 2) {
                    ((float*)Co)[(size_t)rr * ldc + c] += v;
                } else if (EPI == 3) {
                    float gl = 0.5f * v * (1.f + erff(v * 0.70710678118654752f));
                    ((__hip_bfloat16*)Co)[(size_t)rr * ldc + c] = __float2bfloat16(gl);
                } else {
                    ((float*)Co)[(size_t)rr * ldc + c] = v;
                }
            }
        }
    }
}

// ---------------------------------------------------------------------------
// MFMA attention. Two blocks per (b,h) (q-tile halves), 256 threads, 4 waves.
// blockIdx.x = half (0: q-tiles 0-6, 1: q-tiles 7-12), blockIdx.y = b*NH+h.
// s_setprio(1) around both MFMA clusters (m191: +4-7% on multi-wave attn).
// ---------------------------------------------------------------------------
__device__ __forceinline__ int swz_idx(int row, int k) {
    return row * 256 + (((k >> 3) ^ (row & 7)) << 3) + (k & 7);
}
__device__ __forceinline__ unsigned pack_bf16(float a, float b) {
    __hip_bfloat16 x = __float2bfloat16(a), y = __float2bfloat16(b);
    unsigned short ux = *(unsigned short*)&x, uy = *(unsigned short*)&y;
    return (unsigned)ux | ((unsigned)uy << 16);
}

__global__ __launch_bounds__(256) void attn3_k(
    const __hip_bfloat16* __restrict__ qkv, __hip_bfloat16* __restrict__ o)
{
    __shared__ short V_t[64 * 256];
    __shared__ short P_s[4][16 * 256];
    const int half = blockIdx.x;
    const int bh = blockIdx.y;
    const int b = bh / VNH, h = bh % VNH;
    const int tid = threadIdx.x, w = tid >> 6, l = tid & 63;
    const int g = l >> 4, c16 = l & 15;

    const __hip_bfloat16* base = qkv + (size_t)(b * VS) * (3 * VD) + h * VDQ;

    {
        const __hip_bfloat16* vbase = base + 2 * VD;
        int t = tid & 31, e0 = (tid >> 5) * 8;
        #pragma unroll
        for (int it = 0; it < 7; it++) {
            int tt = it * 32 + t;
            if (tt < VS) {
                short8 vv = *(const short8*)(vbase + (size_t)tt * (3 * VD) + e0);
                #pragma unroll
                for (int j = 0; j < 8; j++) V_t[swz_idx(e0 + j, tt)] = vv[j];
            }
        }
        for (int idx = tid; idx < 64 * 27; idx += 256) {
            int e = idx / 27, k = 197 + idx % 27;
            V_t[swz_idx(e, k)] = 0;
        }
    }
    {
        unsigned* p0 = (unsigned*)&P_s[w][swz_idx(c16, 208 + g * 4)];
        p0[0] = 0; p0[1] = 0;
    }
    __syncthreads();

    const int qt_end = half ? 13 : 7;
    for (int qt = 7 * half + w; qt < qt_end; qt += 4) {
        const int q0 = qt * 16;
        int qr = min(q0 + c16, VS - 1);
        const __hip_bfloat16* qp = base + (size_t)qr * (3 * VD) + g * 8;
        short8 qa0 = *(const short8*)(qp);
        short8 qa1 = *(const short8*)(qp + 32);

        f32x4 st[13];
        __builtin_amdgcn_s_setprio(1);
        #pragma unroll
        for (int t = 0; t < 13; t++) {
            int kr = min(t * 16 + c16, VS - 1);
            const __hip_bfloat16* kp = base + VD + (size_t)kr * (3 * VD) + g * 8;
            short8 ka0 = *(const short8*)(kp);
            short8 ka1 = *(const short8*)(kp + 32);
            f32x4 z = {};
            z = __builtin_amdgcn_mfma_f32_16x16x32_bf16(ka0, qa0, z, 0, 0, 0);
            z = __builtin_amdgcn_mfma_f32_16x16x32_bf16(ka1, qa1, z, 0, 0, 0);
            st[t] = z;
        }
        __builtin_amdgcn_s_setprio(0);
        #pragma unroll
        for (int t = 0; t < 13; t++) {
            #pragma unroll
            for (int r = 0; r < 4; r++) {
                float v = st[t][r] * 0.125f;
                if (t == 12 && (4 * g + r) >= 5) v = -3.0e38f;
                st[t][r] = v;
            }
        }
        float m = -3.0e38f;
        #pragma unroll
        for (int t = 0; t < 13; t++)
            #pragma unroll
            for (int r = 0; r < 4; r++) m = fmaxf(m, st[t][r]);
        m = fmaxf(m, __shfl_xor(m, 16));
        m = fmaxf(m, __shfl_xor(m, 32));
        float sum = 0.f;
        #pragma unroll
        for (int t = 0; t < 13; t++)
            #pragma unroll
            for (int r = 0; r < 4; r++) { float e = expf(st[t][r] - m); st[t][r] = e; sum += e; }
        sum += __shfl_xor(sum, 16);
        sum += __shfl_xor(sum, 32);
        float inv = 1.f / sum;
        #pragma unroll
        for (int t = 0; t < 13; t++) {
            int k0 = 16 * t + 4 * g;
            unsigned* pp = (unsigned*)&P_s[w][swz_idx(c16, k0)];
            pp[0] = pack_bf16(st[t][0] * inv, st[t][1] * inv);
            pp[1] = pack_bf16(st[t][2] * inv, st[t][3] * inv);
        }
        f32x4 acc[4] = {};
        __builtin_amdgcn_s_setprio(1);
        #pragma unroll
        for (int ki = 0; ki < 7; ki++) {
            int k0 = ki * 32 + g * 8;
            short8 pa = *(const short8*)&P_s[w][swz_idx(c16, k0)];
            #pragma unroll
            for (int et = 0; et < 4; et++) {
                short8 vbf = *(const short8*)&V_t[swz_idx(et * 16 + c16, k0)];
                acc[et] = __builtin_amdgcn_mfma_f32_16x16x32_bf16(pa, vbf, acc[et], 0, 0, 0);
            }
        }
        __builtin_amdgcn_s_setprio(0);
        #pragma unroll
        for (int et = 0; et < 4; et++) {
            #pragma unroll
            for (int r = 0; r < 4; r++) {
                int q = q0 + 4 * g + r;
                if (q < VS)
                    o[((size_t)(b * VS) + q) * VD + h * VDQ + et * 16 + c16] =
                        __float2bfloat16(acc[et][r]);
            }
        }
    }
}

// ---------------------------------------------------------------------------
extern "C" void kernel_launch(void* const* d_in, const int* in_sizes, int n_in,
                              void* d_out, int out_size, void* d_ws, size_t ws_size,
                              hipStream_t stream) {
    (void)in_sizes; (void)n_in; (void)out_size; (void)ws_size;
    const float* X       = (const float*)d_in[0];
    const float* patch_W = (const float*)d_in[1];
    const float* patch_b = (const float*)d_in[2];
    const float* cls_tok = (const float*)d_in[3];
    const float* ln1_g   = (const float*)d_in[4];
    const float* ln1_b   = (const float*)d_in[5];
    const float* Wq      = (const float*)d_in[6];
    const float* bq      = (const float*)d_in[7];
    const float* Wk      = (const float*)d_in[8];
    const float* bk      = (const float*)d_in[9];
    const float* Wv      = (const float*)d_in[10];
    const float* bv      = (const float*)d_in[11];
    const float* proj_W  = (const float*)d_in[12];
    const float* proj_b  = (const float*)d_in[13];
    const float* ln2_g   = (const float*)d_in[14];
    const float* ln2_b   = (const float*)d_in[15];
    const float* mlp_W1  = (const float*)d_in[16];
    const float* mlp_b1  = (const float*)d_in[17];
    const float* mlp_W2  = (const float*)d_in[18];
    const float* mlp_b2  = (const float*)d_in[19];
    const float* head_W  = (const float*)d_in[20];
    const float* head_b  = (const float*)d_in[21];

    char* ws = (char*)d_ws;
    float*          x   = (float*)ws;                             // 19.37 MB fp32
    __hip_bfloat16* tb  = (__hip_bfloat16*)(ws + 19365888);       // 9.68 MB bf16
    __hip_bfloat16* big = (__hip_bfloat16*)(ws + 29048832);       // 38.73 MB
    __hip_bfloat16* wT  = (__hip_bfloat16*)(ws + 67780608);       // 14.16 MB
    float*          cbA = (float*)(ws + 81936384);                // 110 KB (12x2304)

    cball_k<<<(VL * 3 * VD + 255) / 256, 256, 0, stream>>>(bq, bk, bv, cbA);

    patchify_k<<<(VB * VNPAT * VP + 255) / 256, 256, 0, stream>>>(X, big);
    {
        dim3 g(VD / 32, VP / 32);
        tpose_k<<<g, 256, 0, stream>>>(patch_W, wT, VP, VD);
    }
    {
        dim3 g(VD / 128, VB * VNPAT / 128);
        bgemm_k<0><<<g, 256, 0, stream>>>(big, wT, patch_b, x, VB * VNPAT, VP, VD, VD);
    }
    pos_cls_k<<<(unsigned)((TOKD + 255) / 256), 256, 0, stream>>>(x, cls_tok);

    const size_t WSZ = (size_t)VNH * VD * VDQ;
    for (int l = 0; l < VL; l++) {
        // all 4 weight transposes in one launch
        wprep_k<<<6912, 256, 0, stream>>>(
            Wq + l * WSZ, Wk + l * WSZ, Wv + l * WSZ,
            proj_W + (size_t)l * VD * VD,
            mlp_W1 + (size_t)l * VD * VMLP,
            mlp_W2 + (size_t)l * VMLP * VD, wT);

        layernorm_k<<<VTOK, 256, 0, stream>>>(x, tb, ln1_g + l * VD, ln1_b + l * VD);

        {
            // fused QKV GEMM (LDS m97 structure): grid 18 x 50
            dim3 g(3 * VD / 128, (VTOK + 127) / 128);
            bgemm_k<1><<<g, 256, 0, stream>>>(tb, wT, cbA + l * 3 * VD, big,
                                              VTOK, VD, 3 * VD, 3 * VD);
        }
        {
            dim3 ga(2, VB * VNH);
            attn3_k<<<ga, 256, 0, stream>>>(big, tb);
        }
        {
            dim3 g(VD / 128, (VTOK + 127) / 128);
            bgemm_k<2><<<g, 256, 0, stream>>>(tb, wT + OFF_PROJ, proj_b + l * VD, x,
                                              VTOK, VD, VD, VD);
        }
        layernorm_k<<<VTOK, 256, 0, stream>>>(x, tb, ln2_g + l * VD, ln2_b + l * VD);
        {
            // MLP1 (GELU epilogue): grid 24 x 50
            dim3 g(VMLP / 128, (VTOK + 127) / 128);
            bgemm_k<3><<<g, 256, 0, stream>>>(tb, wT + OFF_M1, mlp_b1 + l * VMLP, big,
                                              VTOK, VD, VMLP, VMLP);
        }
        {
            dim3 g(VD / 128, (VTOK + 127) / 128);
            bgemm_k<2><<<g, 256, 0, stream>>>(big, wT + OFF_M2, mlp_b2 + l * VD, x,
                                              VTOK, VMLP, VD, VD);
        }
    }
    // head: cls rows -> bf16, transpose head_W, 128^2 MFMA GEMM with N-guard
    cls_k<<<(VB * VD + 255) / 256, 256, 0, stream>>>(x, tb);
    {
        dim3 gt((VC + 31) / 32, VD / 32);
        tpose_k<<<gt, 256, 0, stream>>>(head_W, wT, VD, VC);
        dim3 g((VC + 127) / 128, 1);
        bgemm_k<4><<<g, 256, 0, stream>>>(tb, wT, head_b, (float*)d_out,
                                          VB, VD, VC, VC);
    }
}

// Round 8
// 3378.167 us; speedup vs baseline: 1.5548x; 1.0825x over previous
//
#include <hip/hip_runtime.h>
#include <hip/hip_bf16.h>
#include <math.h>
#include <stdint.h>

// ViT config
#define VB   32
#define VS   197
#define VD   768
#define VNH  12
#define VDQ  64
#define VL   12
#define VMLP 3072
#define VC   1000
#define VP   256
#define VNPAT 196
#define VTOK (VB * VS)            // 6304
#define TOKD ((size_t)VTOK * VD)  // 4841472 floats

typedef __attribute__((ext_vector_type(4))) float f32x4;
typedef __attribute__((ext_vector_type(8))) short short8;

typedef __attribute__((address_space(1))) const unsigned int GU;
typedef __attribute__((address_space(3))) unsigned int LU;

__device__ __forceinline__ void gload_lds16(const void* g, void* l) {
    __builtin_amdgcn_global_load_lds((GU*)(uintptr_t)g, (LU*)(uintptr_t)l, 16, 0, 0);
}

// T1: bijective XCD-aware block swizzle (m204). Consecutive logical tiles
// land on the same XCD -> A-panel L2 reuse.
__device__ __forceinline__ void xcd_swz(int gx, int gy, int& bx, int& by) {
    int nwg = gx * gy;
    int hw = by * gx + bx;
    int q = nwg >> 3, r = nwg & 7;
    int xcd = hw & 7, off = hw >> 3;
    int lid = (xcd < r ? xcd * (q + 1) : r * (q + 1) + (xcd - r) * q) + off;
    bx = lid % gx; by = lid / gx;
}

// ---------------------------------------------------------------------------
// patchify: X (B,224,224) fp32 -> patches (B*196, 256) bf16
// ---------------------------------------------------------------------------
__global__ void patchify_k(const float* __restrict__ X, __hip_bfloat16* __restrict__ P) {
    int idx = blockIdx.x * 256 + threadIdx.x;
    const int total = VB * VNPAT * VP;
    if (idx >= total) return;
    int i  = idx & 255;
    int p  = (idx >> 8) % VNPAT;
    int b  = (idx >> 8) / VNPAT;
    int pr = p / 14, pc = p % 14;
    int a  = i >> 4, c2 = i & 15;
    P[idx] = __float2bfloat16(X[((size_t)b * 224 + pr * 16 + a) * 224 + pc * 16 + c2]);
}

// ---------------------------------------------------------------------------
// cls token + sinusoidal positional embeddings (x fp32)
// ---------------------------------------------------------------------------
__global__ void pos_cls_k(float* __restrict__ x, const float* __restrict__ cls) {
    size_t idx = (size_t)blockIdx.x * 256 + threadIdx.x;
    if (idx >= TOKD) return;
    int j = (int)(idx % VD);
    int s = (int)((idx / VD) % VS);
    float jj = (float)(j & ~1);
    float freq = expf(-(jj / (float)VD) * 9.2103403719761836f);
    float ang  = (float)s * freq;
    float pe   = (j & 1) ? cosf(ang) : sinf(ang);
    if (s == 0) x[idx] = cls[j] + pe;
    else        x[idx] += pe;
}

// ---------------------------------------------------------------------------
// LayerNorm: x fp32 -> y bf16. One block per token. (layer-0 LN1 only)
// ---------------------------------------------------------------------------
__global__ __launch_bounds__(256) void layernorm_k(
    const float* __restrict__ x, __hip_bfloat16* __restrict__ y,
    const float* __restrict__ g, const float* __restrict__ bta)
{
    int t = blockIdx.x;
    const float* xr = x + (size_t)t * VD;
    __hip_bfloat16* yr = y + (size_t)t * VD;
    int tid = threadIdx.x;
    float v[3];
    float s = 0.f;
    #pragma unroll
    for (int i = 0; i < 3; i++) { v[i] = xr[tid + i * 256]; s += v[i]; }
    __shared__ float red[8];
    #pragma unroll
    for (int off = 32; off; off >>= 1) s += __shfl_xor(s, off);
    int lane = tid & 63, w = tid >> 6;
    if (!lane) red[w] = s;
    __syncthreads();
    float mu = (red[0] + red[1] + red[2] + red[3]) * (1.f / VD);
    float s2 = 0.f;
    #pragma unroll
    for (int i = 0; i < 3; i++) { float d0 = v[i] - mu; s2 += d0 * d0; }
    #pragma unroll
    for (int off = 32; off; off >>= 1) s2 += __shfl_xor(s2, off);
    if (!lane) red[4 + w] = s2;
    __syncthreads();
    float var = (red[4] + red[5] + red[6] + red[7]) * (1.f / VD);
    float rs = rsqrtf(var + 1e-5f);
    #pragma unroll
    for (int i = 0; i < 3; i++) {
        int j = tid + i * 256;
        yr[j] = __float2bfloat16((v[i] - mu) * rs * g[j] + bta[j]);
    }
}

// ---------------------------------------------------------------------------
// Fused split-K combine + residual + (optional) LayerNorm.
// x[t] += p0[t] + p1[t] + bias ; if DO_LN: y[t] = LN(x[t]) (bf16).
// One block per token.
// ---------------------------------------------------------------------------
template<int DO_LN>
__global__ __launch_bounds__(256) void combineln_k(
    float* __restrict__ x, const float* __restrict__ p0, const float* __restrict__ p1,
    const float* __restrict__ bias, const float* __restrict__ g,
    const float* __restrict__ bta, __hip_bfloat16* __restrict__ y)
{
    int t = blockIdx.x;
    size_t base = (size_t)t * VD;
    int tid = threadIdx.x;
    float v[3];
    float s = 0.f;
    #pragma unroll
    for (int i = 0; i < 3; i++) {
        int j = tid + i * 256;
        float val = x[base + j] + p0[base + j] + p1[base + j] + bias[j];
        x[base + j] = val;
        v[i] = val; s += val;
    }
    if (DO_LN) {
        __shared__ float red[8];
        #pragma unroll
        for (int off = 32; off; off >>= 1) s += __shfl_xor(s, off);
        int lane = tid & 63, w = tid >> 6;
        if (!lane) red[w] = s;
        __syncthreads();
        float mu = (red[0] + red[1] + red[2] + red[3]) * (1.f / VD);
        float s2 = 0.f;
        #pragma unroll
        for (int i = 0; i < 3; i++) { float d0 = v[i] - mu; s2 += d0 * d0; }
        #pragma unroll
        for (int off = 32; off; off >>= 1) s2 += __shfl_xor(s2, off);
        if (!lane) red[4 + w] = s2;
        __syncthreads();
        float var = (red[4] + red[5] + red[6] + red[7]) * (1.f / VD);
        float rs = rsqrtf(var + 1e-5f);
        #pragma unroll
        for (int i = 0; i < 3; i++) {
            int j = tid + i * 256;
            y[base + j] = __float2bfloat16((v[i] - mu) * rs * g[j] + bta[j]);
        }
    }
}

// ---------------------------------------------------------------------------
// Guarded transpose + bf16 convert: in (R,C) fp32 -> out (C,R) bf16.
// (used for patch_W and head_W only)
// ---------------------------------------------------------------------------
__global__ __launch_bounds__(256) void tpose_k(
    const float* __restrict__ in, __hip_bfloat16* __restrict__ out, int R, int C)
{
    __shared__ float t[32][33];
    int c0 = blockIdx.x * 32, r0 = blockIdx.y * 32;
    int tc = threadIdx.x & 31, tr = threadIdx.x >> 5;
    #pragma unroll
    for (int p = 0; p < 4; p++) {
        int r = r0 + tr + p * 8;
        t[tr + p * 8][tc] = (r < R && c0 + tc < C) ? in[(size_t)r * C + c0 + tc] : 0.f;
    }
    __syncthreads();
    #pragma unroll
    for (int p = 0; p < 4; p++) {
        int c = c0 + tr + p * 8;
        if (c < C && r0 + tc < R)
            out[(size_t)c * R + r0 + tc] = __float2bfloat16(t[tc][tr + p * 8]);
    }
}

// wT layout (shorts): qkv [2304][768] @0; proj [768][768] @OFF_PROJ;
// mlp1 [3072][768] @OFF_M1; mlp2 [768][3072] @OFF_M2.
#define OFF_PROJ (2304 * 768)
#define OFF_M1   (OFF_PROJ + 768 * 768)
#define OFF_M2   (OFF_M1 + 3072 * 768)

// ---------------------------------------------------------------------------
// One-launch per-layer weight prep: transpose+bf16 all of qkv/proj/mlp1/mlp2.
// ---------------------------------------------------------------------------
__global__ __launch_bounds__(256) void wprep_k(
    const float* __restrict__ Wq, const float* __restrict__ Wk,
    const float* __restrict__ Wv, const float* __restrict__ Wp,
    const float* __restrict__ W1, const float* __restrict__ W2,
    __hip_bfloat16* __restrict__ wT)
{
    __shared__ float t[32][33];
    int z = blockIdx.x;
    const float* src; __hip_bfloat16* dst;
    int C, ldd, r0, c0;
    if (z < 1728) {               // qkv: 36 heads x (24 r-tiles x 2 c-tiles)
        int head = z / 48, tt = z % 48;
        int m = head / VNH, h = head % VNH;
        src = (m == 0 ? Wq : m == 1 ? Wk : Wv) + (size_t)h * VD * VDQ;
        dst = wT + ((size_t)m * VD + h * VDQ) * VD;
        C = VDQ; ldd = VD;
        r0 = (tt >> 1) * 32; c0 = (tt & 1) * 32;
    } else if (z < 2304) {        // proj: 24x24
        int z2 = z - 1728;
        src = Wp; dst = wT + OFF_PROJ;
        C = VD; ldd = VD;
        r0 = (z2 / 24) * 32; c0 = (z2 % 24) * 32;
    } else if (z < 4608) {        // mlp1: src [768][3072] -> 24 x 96 tiles
        int z3 = z - 2304;
        src = W1; dst = wT + OFF_M1;
        C = VMLP; ldd = VD;
        r0 = (z3 / 96) * 32; c0 = (z3 % 96) * 32;
    } else {                      // mlp2: src [3072][768] -> 96 x 24 tiles
        int z4 = z - 4608;
        src = W2; dst = wT + OFF_M2;
        C = VD; ldd = VMLP;
        r0 = (z4 / 24) * 32; c0 = (z4 % 24) * 32;
    }
    int tc = threadIdx.x & 31, tr = threadIdx.x >> 5;
    #pragma unroll
    for (int p = 0; p < 4; p++)
        t[tr + p * 8][tc] = src[(size_t)(r0 + tr + p * 8) * C + c0 + tc];
    __syncthreads();
    #pragma unroll
    for (int p = 0; p < 4; p++)
        dst[(size_t)(c0 + tr + p * 8) * ldd + r0 + tc] = __float2bfloat16(t[tc][tr + p * 8]);
}

// combined qkv bias for ALL layers: cb[l][2304]
__global__ void cball_k(const float* __restrict__ bq, const float* __restrict__ bk,
                        const float* __restrict__ bv, float* __restrict__ cb) {
    int idx = blockIdx.x * 256 + threadIdx.x;
    if (idx >= VL * 3 * VD) return;
    int l = idx / (3 * VD), n = idx % (3 * VD);
    int m = n / VD, wi = n % VD;
    const float* p = (m == 0) ? bq : (m == 1) ? bk : bv;
    cb[idx] = p[l * VD + wi];
}

// extract cls rows of x -> bf16 [32][768]
__global__ void cls_k(const float* __restrict__ x, __hip_bfloat16* __restrict__ out) {
    int idx = blockIdx.x * 256 + threadIdx.x;
    if (idx >= VB * VD) return;
    int b = idx / VD, d = idx % VD;
    out[idx] = __float2bfloat16(x[(size_t)b * VS * VD + d]);
}

// ---------------------------------------------------------------------------
// bf16 MFMA GEMM (m97-style 128x128, BK=64, LDS) + XCD swizzle.
// EPI: 0 = fp32 store w/ patch rowmap; 1 = bf16 store; 2 = fp32 accumulate;
//      3 = exact-GELU -> bf16; 4 = plain fp32 store.
// ---------------------------------------------------------------------------
template<int EPI>
__global__ __launch_bounds__(256) void bgemm_k(
    const __hip_bfloat16* __restrict__ A,
    const __hip_bfloat16* __restrict__ BT,
    const float* __restrict__ bias,
    void* __restrict__ Co,
    int M, int K, int ldc, int Ncols)
{
    __shared__ short A_s[128][64];
    __shared__ short B_s[128][64];
    int bx = blockIdx.x, by = blockIdx.y;
    xcd_swz(gridDim.x, gridDim.y, bx, by);
    const int tid = threadIdx.x;
    const int w = tid >> 6, l = tid & 63;
    const int row0 = by * 128, col0 = bx * 128;
    const int wm = (w >> 1) << 6, wn = (w & 1) << 6;
    f32x4 acc[4][4] = {};

    const int lr = l >> 3;
    const int sslot = (l & 7) ^ lr;
    int arow[4], brow[4];
    #pragma unroll
    for (int i = 0; i < 4; i++) {
        int r = (4 * w + i) * 8 + lr;
        arow[i] = min(row0 + r, M - 1);
        brow[i] = min(col0 + r, Ncols - 1);
    }
    for (int k0 = 0; k0 < K; k0 += 64) {
        __syncthreads();
        #pragma unroll
        for (int i = 0; i < 4; i++) {
            int ch = 4 * w + i;
            gload_lds16((const void*)(A + (size_t)arow[i] * K + k0 + (sslot << 3)),
                        (void*)(&A_s[ch * 8][0]));
            gload_lds16((const void*)(BT + (size_t)brow[i] * K + k0 + (sslot << 3)),
                        (void*)(&B_s[ch * 8][0]));
        }
        __syncthreads();
        #pragma unroll
        for (int ks = 0; ks < 2; ks++) {
            const int s16 = (ks << 2) + (l >> 4);
            short8 av[4], bv[4];
            #pragma unroll
            for (int i = 0; i < 4; i++) {
                int ar = wm + i * 16 + (l & 15);
                av[i] = *(const short8*)((const char*)&A_s[ar][0] + ((s16 ^ (ar & 7)) << 4));
                int br = wn + i * 16 + (l & 15);
                bv[i] = *(const short8*)((const char*)&B_s[br][0] + ((s16 ^ (br & 7)) << 4));
            }
            #pragma unroll
            for (int i = 0; i < 4; i++)
                #pragma unroll
                for (int j = 0; j < 4; j++)
                    acc[i][j] = __builtin_amdgcn_mfma_f32_16x16x32_bf16(av[i], bv[j], acc[i][j], 0, 0, 0);
        }
    }
    const int rbase = row0 + wm + ((l >> 4) << 2);
    const int cbase = col0 + wn + (l & 15);
    #pragma unroll
    for (int i = 0; i < 4; i++) {
        #pragma unroll
        for (int q = 0; q < 4; q++) {
            int rr = rbase + i * 16 + q;
            if (rr >= M) continue;
            #pragma unroll
            for (int j = 0; j < 4; j++) {
                int c = cbase + j * 16;
                if (c >= Ncols) continue;
                float v = acc[i][j][q] + bias[c];
                if (EPI == 0) {
                    int orow = rr + rr / VNPAT + 1;
                    ((float*)Co)[(size_t)orow * ldc + c] = v;
                } else if (EPI == 1) {
                    ((__hip_bfloat16*)Co)[(size_t)rr * ldc + c] = __float2bfloat16(v);
                } else if (EPI == 2) {
                    ((float*)Co)[(size_t)rr * ldc + c] += v;
                } else if (EPI == 3) {
                    float gl = 0.5f * v * (1.f + erff(v * 0.70710678118654752f));
                    ((__hip_bfloat16*)Co)[(size_t)rr * ldc + c] = __float2bfloat16(gl);
                } else {
                    ((float*)Co)[(size_t)rr * ldc + c] = v;
                }
            }
        }
    }
}

// ---------------------------------------------------------------------------
// Split-K=2 partial GEMM: P[ks][M][ldc] = A[:, ks*K/2:(ks+1)*K/2] @ BT^T.
// Same 128x128 m97 structure; grid (N/128, M-tiles, 2); no bias (combine adds).
// ---------------------------------------------------------------------------
__global__ __launch_bounds__(256) void bgemm5_k(
    const __hip_bfloat16* __restrict__ A,
    const __hip_bfloat16* __restrict__ BT,
    float* __restrict__ P,
    int M, int K, int ldc)
{
    __shared__ short A_s[128][64];
    __shared__ short B_s[128][64];
    int bx = blockIdx.x, by = blockIdx.y;
    xcd_swz(gridDim.x, gridDim.y, bx, by);
    const int ks = blockIdx.z;
    const int khalf = K >> 1;
    const __hip_bfloat16* Ab  = A  + (size_t)ks * khalf;
    const __hip_bfloat16* BTb = BT + (size_t)ks * khalf;
    float* Pb = P + (size_t)ks * TOKD;

    const int tid = threadIdx.x;
    const int w = tid >> 6, l = tid & 63;
    const int row0 = by * 128, col0 = bx * 128;
    const int wm = (w >> 1) << 6, wn = (w & 1) << 6;
    f32x4 acc[4][4] = {};

    const int lr = l >> 3;
    const int sslot = (l & 7) ^ lr;
    int arow[4], brow[4];
    #pragma unroll
    for (int i = 0; i < 4; i++) {
        int r = (4 * w + i) * 8 + lr;
        arow[i] = min(row0 + r, M - 1);
        brow[i] = col0 + r;
    }
    for (int k0 = 0; k0 < khalf; k0 += 64) {
        __syncthreads();
        #pragma unroll
        for (int i = 0; i < 4; i++) {
            int ch = 4 * w + i;
            gload_lds16((const void*)(Ab + (size_t)arow[i] * K + k0 + (sslot << 3)),
                        (void*)(&A_s[ch * 8][0]));
            gload_lds16((const void*)(BTb + (size_t)brow[i] * K + k0 + (sslot << 3)),
                        (void*)(&B_s[ch * 8][0]));
        }
        __syncthreads();
        #pragma unroll
        for (int ks2 = 0; ks2 < 2; ks2++) {
            const int s16 = (ks2 << 2) + (l >> 4);
            short8 av[4], bv[4];
            #pragma unroll
            for (int i = 0; i < 4; i++) {
                int ar = wm + i * 16 + (l & 15);
                av[i] = *(const short8*)((const char*)&A_s[ar][0] + ((s16 ^ (ar & 7)) << 4));
                int br = wn + i * 16 + (l & 15);
                bv[i] = *(const short8*)((const char*)&B_s[br][0] + ((s16 ^ (br & 7)) << 4));
            }
            #pragma unroll
            for (int i = 0; i < 4; i++)
                #pragma unroll
                for (int j = 0; j < 4; j++)
                    acc[i][j] = __builtin_amdgcn_mfma_f32_16x16x32_bf16(av[i], bv[j], acc[i][j], 0, 0, 0);
        }
    }
    const int rbase = row0 + wm + ((l >> 4) << 2);
    const int cbase = col0 + wn + (l & 15);
    #pragma unroll
    for (int i = 0; i < 4; i++) {
        #pragma unroll
        for (int q = 0; q < 4; q++) {
            int rr = rbase + i * 16 + q;
            if (rr >= M) continue;
            #pragma unroll
            for (int j = 0; j < 4; j++) {
                int c = cbase + j * 16;
                Pb[(size_t)rr * ldc + c] = acc[i][j][q];
            }
        }
    }
}

// ---------------------------------------------------------------------------
// MFMA attention. Two blocks per (b,h), 256 threads, 4 waves. (r7 version)
// ---------------------------------------------------------------------------
__device__ __forceinline__ int swz_idx(int row, int k) {
    return row * 256 + (((k >> 3) ^ (row & 7)) << 3) + (k & 7);
}
__device__ __forceinline__ unsigned pack_bf16(float a, float b) {
    __hip_bfloat16 x = __float2bfloat16(a), y = __float2bfloat16(b);
    unsigned short ux = *(unsigned short*)&x, uy = *(unsigned short*)&y;
    return (unsigned)ux | ((unsigned)uy << 16);
}

__global__ __launch_bounds__(256) void attn3_k(
    const __hip_bfloat16* __restrict__ qkv, __hip_bfloat16* __restrict__ o)
{
    __shared__ short V_t[64 * 256];
    __shared__ short P_s[4][16 * 256];
    const int half = blockIdx.x;
    const int bh = blockIdx.y;
    const int b = bh / VNH, h = bh % VNH;
    const int tid = threadIdx.x, w = tid >> 6, l = tid & 63;
    const int g = l >> 4, c16 = l & 15;

    const __hip_bfloat16* base = qkv + (size_t)(b * VS) * (3 * VD) + h * VDQ;

    {
        const __hip_bfloat16* vbase = base + 2 * VD;
        int t = tid & 31, e0 = (tid >> 5) * 8;
        #pragma unroll
        for (int it = 0; it < 7; it++) {
            int tt = it * 32 + t;
            if (tt < VS) {
                short8 vv = *(const short8*)(vbase + (size_t)tt * (3 * VD) + e0);
                #pragma unroll
                for (int j = 0; j < 8; j++) V_t[swz_idx(e0 + j, tt)] = vv[j];
            }
        }
        for (int idx = tid; idx < 64 * 27; idx += 256) {
            int e = idx / 27, k = 197 + idx % 27;
            V_t[swz_idx(e, k)] = 0;
        }
    }
    {
        unsigned* p0 = (unsigned*)&P_s[w][swz_idx(c16, 208 + g * 4)];
        p0[0] = 0; p0[1] = 0;
    }
    __syncthreads();

    const int qt_end = half ? 13 : 7;
    for (int qt = 7 * half + w; qt < qt_end; qt += 4) {
        const int q0 = qt * 16;
        int qr = min(q0 + c16, VS - 1);
        const __hip_bfloat16* qp = base + (size_t)qr * (3 * VD) + g * 8;
        short8 qa0 = *(const short8*)(qp);
        short8 qa1 = *(const short8*)(qp + 32);

        f32x4 st[13];
        __builtin_amdgcn_s_setprio(1);
        #pragma unroll
        for (int t = 0; t < 13; t++) {
            int kr = min(t * 16 + c16, VS - 1);
            const __hip_bfloat16* kp = base + VD + (size_t)kr * (3 * VD) + g * 8;
            short8 ka0 = *(const short8*)(kp);
            short8 ka1 = *(const short8*)(kp + 32);
            f32x4 z = {};
            z = __builtin_amdgcn_mfma_f32_16x16x32_bf16(ka0, qa0, z, 0, 0, 0);
            z = __builtin_amdgcn_mfma_f32_16x16x32_bf16(ka1, qa1, z, 0, 0, 0);
            st[t] = z;
        }
        __builtin_amdgcn_s_setprio(0);
        #pragma unroll
        for (int t = 0; t < 13; t++) {
            #pragma unroll
            for (int r = 0; r < 4; r++) {
                float v = st[t][r] * 0.125f;
                if (t == 12 && (4 * g + r) >= 5) v = -3.0e38f;
                st[t][r] = v;
            }
        }
        float m = -3.0e38f;
        #pragma unroll
        for (int t = 0; t < 13; t++)
            #pragma unroll
            for (int r = 0; r < 4; r++) m = fmaxf(m, st[t][r]);
        m = fmaxf(m, __shfl_xor(m, 16));
        m = fmaxf(m, __shfl_xor(m, 32));
        float sum = 0.f;
        #pragma unroll
        for (int t = 0; t < 13; t++)
            #pragma unroll
            for (int r = 0; r < 4; r++) { float e = expf(st[t][r] - m); st[t][r] = e; sum += e; }
        sum += __shfl_xor(sum, 16);
        sum += __shfl_xor(sum, 32);
        float inv = 1.f / sum;
        #pragma unroll
        for (int t = 0; t < 13; t++) {
            int k0 = 16 * t + 4 * g;
            unsigned* pp = (unsigned*)&P_s[w][swz_idx(c16, k0)];
            pp[0] = pack_bf16(st[t][0] * inv, st[t][1] * inv);
            pp[1] = pack_bf16(st[t][2] * inv, st[t][3] * inv);
        }
        f32x4 acc[4] = {};
        __builtin_amdgcn_s_setprio(1);
        #pragma unroll
        for (int ki = 0; ki < 7; ki++) {
            int k0 = ki * 32 + g * 8;
            short8 pa = *(const short8*)&P_s[w][swz_idx(c16, k0)];
            #pragma unroll
            for (int et = 0; et < 4; et++) {
                short8 vbf = *(const short8*)&V_t[swz_idx(et * 16 + c16, k0)];
                acc[et] = __builtin_amdgcn_mfma_f32_16x16x32_bf16(pa, vbf, acc[et], 0, 0, 0);
            }
        }
        __builtin_amdgcn_s_setprio(0);
        #pragma unroll
        for (int et = 0; et < 4; et++) {
            #pragma unroll
            for (int r = 0; r < 4; r++) {
                int q = q0 + 4 * g + r;
                if (q < VS)
                    o[((size_t)(b * VS) + q) * VD + h * VDQ + et * 16 + c16] =
                        __float2bfloat16(acc[et][r]);
            }
        }
    }
}

// ---------------------------------------------------------------------------
extern "C" void kernel_launch(void* const* d_in, const int* in_sizes, int n_in,
                              void* d_out, int out_size, void* d_ws, size_t ws_size,
                              hipStream_t stream) {
    (void)in_sizes; (void)n_in; (void)out_size; (void)ws_size;
    const float* X       = (const float*)d_in[0];
    const float* patch_W = (const float*)d_in[1];
    const float* patch_b = (const float*)d_in[2];
    const float* cls_tok = (const float*)d_in[3];
    const float* ln1_g   = (const float*)d_in[4];
    const float* ln1_b   = (const float*)d_in[5];
    const float* Wq      = (const float*)d_in[6];
    const float* bq      = (const float*)d_in[7];
    const float* Wk      = (const float*)d_in[8];
    const float* bk      = (const float*)d_in[9];
    const float* Wv      = (const float*)d_in[10];
    const float* bv      = (const float*)d_in[11];
    const float* proj_W  = (const float*)d_in[12];
    const float* proj_b  = (const float*)d_in[13];
    const float* ln2_g   = (const float*)d_in[14];
    const float* ln2_b   = (const float*)d_in[15];
    const float* mlp_W1  = (const float*)d_in[16];
    const float* mlp_b1  = (const float*)d_in[17];
    const float* mlp_W2  = (const float*)d_in[18];
    const float* mlp_b2  = (const float*)d_in[19];
    const float* head_W  = (const float*)d_in[20];
    const float* head_b  = (const float*)d_in[21];

    char* ws = (char*)d_ws;
    float*          x    = (float*)ws;                            // 19.37 MB fp32
    __hip_bfloat16* tb   = (__hip_bfloat16*)(ws + 19365888);      // 9.68 MB bf16
    __hip_bfloat16* big  = (__hip_bfloat16*)(ws + 29048832);      // 38.73 MB
    __hip_bfloat16* wT   = (__hip_bfloat16*)(ws + 67780608);      // 14.16 MB
    float*          cbA  = (float*)(ws + 81936384);               // 110 KB (12x2304)
    float*          pbuf = (float*)(ws + 82046976);               // 38.73 MB (2x TOKD fp32)

    cball_k<<<(VL * 3 * VD + 255) / 256, 256, 0, stream>>>(bq, bk, bv, cbA);

    patchify_k<<<(VB * VNPAT * VP + 255) / 256, 256, 0, stream>>>(X, big);
    {
        dim3 g(VD / 32, VP / 32);
        tpose_k<<<g, 256, 0, stream>>>(patch_W, wT, VP, VD);
    }
    {
        dim3 g(VD / 128, VB * VNPAT / 128);
        bgemm_k<0><<<g, 256, 0, stream>>>(big, wT, patch_b, x, VB * VNPAT, VP, VD, VD);
    }
    pos_cls_k<<<(unsigned)((TOKD + 255) / 256), 256, 0, stream>>>(x, cls_tok);

    const size_t WSZ = (size_t)VNH * VD * VDQ;
    for (int l = 0; l < VL; l++) {
        // all 4 weight transposes in one launch
        wprep_k<<<6912, 256, 0, stream>>>(
            Wq + l * WSZ, Wk + l * WSZ, Wv + l * WSZ,
            proj_W + (size_t)l * VD * VD,
            mlp_W1 + (size_t)l * VD * VMLP,
            mlp_W2 + (size_t)l * VMLP * VD, wT);

        if (l == 0)
            layernorm_k<<<VTOK, 256, 0, stream>>>(x, tb, ln1_g, ln1_b);

        {
            // fused QKV GEMM: grid 18 x 50 (swizzled)
            dim3 g(3 * VD / 128, (VTOK + 127) / 128);
            bgemm_k<1><<<g, 256, 0, stream>>>(tb, wT, cbA + l * 3 * VD, big,
                                              VTOK, VD, 3 * VD, 3 * VD);
        }
        {
            dim3 ga(2, VB * VNH);
            attn3_k<<<ga, 256, 0, stream>>>(big, tb);
        }
        {
            // proj split-K=2 -> partials, then combine + residual + LN2
            dim3 g(VD / 128, (VTOK + 127) / 128, 2);
            bgemm5_k<<<g, 256, 0, stream>>>(tb, wT + OFF_PROJ, pbuf, VTOK, VD, VD);
            combineln_k<1><<<VTOK, 256, 0, stream>>>(
                x, pbuf, pbuf + TOKD, proj_b + l * VD,
                ln2_g + l * VD, ln2_b + l * VD, tb);
        }
        {
            // MLP1 (GELU epilogue): grid 24 x 50 (swizzled)
            dim3 g(VMLP / 128, (VTOK + 127) / 128);
            bgemm_k<3><<<g, 256, 0, stream>>>(tb, wT + OFF_M1, mlp_b1 + l * VMLP, big,
                                              VTOK, VD, VMLP, VMLP);
        }
        {
            // MLP2 split-K=2 -> partials, then combine + residual (+ next LN1)
            dim3 g(VD / 128, (VTOK + 127) / 128, 2);
            bgemm5_k<<<g, 256, 0, stream>>>(big, wT + OFF_M2, pbuf, VTOK, VMLP, VD);
            if (l + 1 < VL)
                combineln_k<1><<<VTOK, 256, 0, stream>>>(
                    x, pbuf, pbuf + TOKD, mlp_b2 + l * VD,
                    ln1_g + (l + 1) * VD, ln1_b + (l + 1) * VD, tb);
            else
                combineln_k<0><<<VTOK, 256, 0, stream>>>(
                    x, pbuf, pbuf + TOKD, mlp_b2 + l * VD,
                    nullptr, nullptr, nullptr);
        }
    }
    // head: cls rows -> bf16, transpose head_W, 128^2 MFMA GEMM with N-guard
    cls_k<<<(VB * VD + 255) / 256, 256, 0, stream>>>(x, tb);
    {
        dim3 gt((VC + 31) / 32, VD / 32);
        tpose_k<<<gt, 256, 0, stream>>>(head_W, wT, VD, VC);
        dim3 g((VC + 127) / 128, 1);
        bgemm_k<4><<<g, 256, 0, stream>>>(tb, wT, head_b, (float*)d_out,
                                          VB, VD, VC, VC);
    }
}

// Round 9
// 3321.777 us; speedup vs baseline: 1.5812x; 1.0170x over previous
//
#include <hip/hip_runtime.h>
#include <hip/hip_bf16.h>
#include <math.h>
#include <stdint.h>

// ViT config
#define VB   32
#define VS   197
#define VD   768
#define VNH  12
#define VDQ  64
#define VL   12
#define VMLP 3072
#define VC   1000
#define VP   256
#define VNPAT 196
#define VTOK (VB * VS)            // 6304
#define TOKD ((size_t)VTOK * VD)  // 4841472 floats

typedef __attribute__((ext_vector_type(4))) float f32x4;
typedef __attribute__((ext_vector_type(8))) short short8;

typedef __attribute__((address_space(1))) const unsigned int GU;
typedef __attribute__((address_space(3))) unsigned int LU;

__device__ __forceinline__ void gload_lds16(const void* g, void* l) {
    __builtin_amdgcn_global_load_lds((GU*)(uintptr_t)g, (LU*)(uintptr_t)l, 16, 0, 0);
}

// T1: bijective XCD-aware block swizzle (m204).
__device__ __forceinline__ void xcd_swz(int gx, int gy, int& bx, int& by) {
    int nwg = gx * gy;
    int hw = by * gx + bx;
    int q = nwg >> 3, r = nwg & 7;
    int xcd = hw & 7, off = hw >> 3;
    int lid = (xcd < r ? xcd * (q + 1) : r * (q + 1) + (xcd - r) * q) + off;
    bx = lid % gx; by = lid / gx;
}

// Fast tanh-form GELU: x * e/(1+e), e = 2^(2*log2(e)*t), t = 0.79788x(1+0.044715x^2).
// Max |err| vs exact-erf GELU ~1e-3 << bf16 quantization of the hidden state.
__device__ __forceinline__ float gelu_f(float x) {
    float t = 0.7978845608f * x * fmaf(0.044715f, x * x, 1.0f);
    float a = fminf(t * 2.8853900818f, 80.0f);   // clamp: avoid inf/inf
    float e = __builtin_amdgcn_exp2f(a);
    return x * e * __builtin_amdgcn_rcpf(1.0f + e);
}

// ---------------------------------------------------------------------------
// patchify: X (B,224,224) fp32 -> patches (B*196, 256) bf16
// ---------------------------------------------------------------------------
__global__ void patchify_k(const float* __restrict__ X, __hip_bfloat16* __restrict__ P) {
    int idx = blockIdx.x * 256 + threadIdx.x;
    const int total = VB * VNPAT * VP;
    if (idx >= total) return;
    int i  = idx & 255;
    int p  = (idx >> 8) % VNPAT;
    int b  = (idx >> 8) / VNPAT;
    int pr = p / 14, pc = p % 14;
    int a  = i >> 4, c2 = i & 15;
    P[idx] = __float2bfloat16(X[((size_t)b * 224 + pr * 16 + a) * 224 + pc * 16 + c2]);
}

// ---------------------------------------------------------------------------
// cls token + sinusoidal positional embeddings (x fp32)
// ---------------------------------------------------------------------------
__global__ void pos_cls_k(float* __restrict__ x, const float* __restrict__ cls) {
    size_t idx = (size_t)blockIdx.x * 256 + threadIdx.x;
    if (idx >= TOKD) return;
    int j = (int)(idx % VD);
    int s = (int)((idx / VD) % VS);
    float jj = (float)(j & ~1);
    float freq = expf(-(jj / (float)VD) * 9.2103403719761836f);
    float ang  = (float)s * freq;
    float pe   = (j & 1) ? cosf(ang) : sinf(ang);
    if (s == 0) x[idx] = cls[j] + pe;
    else        x[idx] += pe;
}

// ---------------------------------------------------------------------------
// LayerNorm: x fp32 -> y bf16. One block per token. (layer-0 LN1 only)
// ---------------------------------------------------------------------------
__global__ __launch_bounds__(256) void layernorm_k(
    const float* __restrict__ x, __hip_bfloat16* __restrict__ y,
    const float* __restrict__ g, const float* __restrict__ bta)
{
    int t = blockIdx.x;
    const float* xr = x + (size_t)t * VD;
    __hip_bfloat16* yr = y + (size_t)t * VD;
    int tid = threadIdx.x;
    float v[3];
    float s = 0.f;
    #pragma unroll
    for (int i = 0; i < 3; i++) { v[i] = xr[tid + i * 256]; s += v[i]; }
    __shared__ float red[8];
    #pragma unroll
    for (int off = 32; off; off >>= 1) s += __shfl_xor(s, off);
    int lane = tid & 63, w = tid >> 6;
    if (!lane) red[w] = s;
    __syncthreads();
    float mu = (red[0] + red[1] + red[2] + red[3]) * (1.f / VD);
    float s2 = 0.f;
    #pragma unroll
    for (int i = 0; i < 3; i++) { float d0 = v[i] - mu; s2 += d0 * d0; }
    #pragma unroll
    for (int off = 32; off; off >>= 1) s2 += __shfl_xor(s2, off);
    if (!lane) red[4 + w] = s2;
    __syncthreads();
    float var = (red[4] + red[5] + red[6] + red[7]) * (1.f / VD);
    float rs = rsqrtf(var + 1e-5f);
    #pragma unroll
    for (int i = 0; i < 3; i++) {
        int j = tid + i * 256;
        yr[j] = __float2bfloat16((v[i] - mu) * rs * g[j] + bta[j]);
    }
}

// ---------------------------------------------------------------------------
// Fused split-K combine + residual + (optional) LayerNorm.
// ---------------------------------------------------------------------------
template<int DO_LN>
__global__ __launch_bounds__(256) void combineln_k(
    float* __restrict__ x, const float* __restrict__ p0, const float* __restrict__ p1,
    const float* __restrict__ bias, const float* __restrict__ g,
    const float* __restrict__ bta, __hip_bfloat16* __restrict__ y)
{
    int t = blockIdx.x;
    size_t base = (size_t)t * VD;
    int tid = threadIdx.x;
    float v[3];
    float s = 0.f;
    #pragma unroll
    for (int i = 0; i < 3; i++) {
        int j = tid + i * 256;
        float val = x[base + j] + p0[base + j] + p1[base + j] + bias[j];
        x[base + j] = val;
        v[i] = val; s += val;
    }
    if (DO_LN) {
        __shared__ float red[8];
        #pragma unroll
        for (int off = 32; off; off >>= 1) s += __shfl_xor(s, off);
        int lane = tid & 63, w = tid >> 6;
        if (!lane) red[w] = s;
        __syncthreads();
        float mu = (red[0] + red[1] + red[2] + red[3]) * (1.f / VD);
        float s2 = 0.f;
        #pragma unroll
        for (int i = 0; i < 3; i++) { float d0 = v[i] - mu; s2 += d0 * d0; }
        #pragma unroll
        for (int off = 32; off; off >>= 1) s2 += __shfl_xor(s2, off);
        if (!lane) red[4 + w] = s2;
        __syncthreads();
        float var = (red[4] + red[5] + red[6] + red[7]) * (1.f / VD);
        float rs = rsqrtf(var + 1e-5f);
        #pragma unroll
        for (int i = 0; i < 3; i++) {
            int j = tid + i * 256;
            y[base + j] = __float2bfloat16((v[i] - mu) * rs * g[j] + bta[j]);
        }
    }
}

// ---------------------------------------------------------------------------
// Guarded transpose + bf16 convert: in (R,C) fp32 -> out (C,R) bf16.
// (used for patch_W and head_W only)
// ---------------------------------------------------------------------------
__global__ __launch_bounds__(256) void tpose_k(
    const float* __restrict__ in, __hip_bfloat16* __restrict__ out, int R, int C)
{
    __shared__ float t[32][33];
    int c0 = blockIdx.x * 32, r0 = blockIdx.y * 32;
    int tc = threadIdx.x & 31, tr = threadIdx.x >> 5;
    #pragma unroll
    for (int p = 0; p < 4; p++) {
        int r = r0 + tr + p * 8;
        t[tr + p * 8][tc] = (r < R && c0 + tc < C) ? in[(size_t)r * C + c0 + tc] : 0.f;
    }
    __syncthreads();
    #pragma unroll
    for (int p = 0; p < 4; p++) {
        int c = c0 + tr + p * 8;
        if (c < C && r0 + tc < R)
            out[(size_t)c * R + r0 + tc] = __float2bfloat16(t[tc][tr + p * 8]);
    }
}

// wT layout (shorts): qkv [2304][768] @0; proj [768][768] @OFF_PROJ;
// mlp1 [3072][768] @OFF_M1; mlp2 [768][3072] @OFF_M2.
#define OFF_PROJ (2304 * 768)
#define OFF_M1   (OFF_PROJ + 768 * 768)
#define OFF_M2   (OFF_M1 + 3072 * 768)

__device__ __forceinline__ unsigned pack2bf(float a, float b) {
    __hip_bfloat16 x = __float2bfloat16(a), y = __float2bfloat16(b);
    unsigned short ux = *(unsigned short*)&x, uy = *(unsigned short*)&y;
    return (unsigned)ux | ((unsigned)uy << 16);
}

// ---------------------------------------------------------------------------
// One-launch per-layer weight prep (vectorized): float4 loads, packed uint
// stores. 6912 blocks of 256 threads; 32x32 tile each.
// ---------------------------------------------------------------------------
__global__ __launch_bounds__(256) void wprep_k(
    const float* __restrict__ Wq, const float* __restrict__ Wk,
    const float* __restrict__ Wv, const float* __restrict__ Wp,
    const float* __restrict__ W1, const float* __restrict__ W2,
    __hip_bfloat16* __restrict__ wT)
{
    __shared__ float t[32][33];
    int z = blockIdx.x;
    const float* src; __hip_bfloat16* dst;
    int C, ldd, r0, c0;
    if (z < 1728) {               // qkv: 36 heads x (24 r-tiles x 2 c-tiles)
        int head = z / 48, tt = z % 48;
        int m = head / VNH, h = head % VNH;
        src = (m == 0 ? Wq : m == 1 ? Wk : Wv) + (size_t)h * VD * VDQ;
        dst = wT + ((size_t)m * VD + h * VDQ) * VD;
        C = VDQ; ldd = VD;
        r0 = (tt >> 1) * 32; c0 = (tt & 1) * 32;
    } else if (z < 2304) {        // proj: 24x24
        int z2 = z - 1728;
        src = Wp; dst = wT + OFF_PROJ;
        C = VD; ldd = VD;
        r0 = (z2 / 24) * 32; c0 = (z2 % 24) * 32;
    } else if (z < 4608) {        // mlp1: src [768][3072] -> 24 x 96 tiles
        int z3 = z - 2304;
        src = W1; dst = wT + OFF_M1;
        C = VMLP; ldd = VD;
        r0 = (z3 / 96) * 32; c0 = (z3 % 96) * 32;
    } else {                      // mlp2: src [3072][768] -> 96 x 24 tiles
        int z4 = z - 4608;
        src = W2; dst = wT + OFF_M2;
        C = VD; ldd = VMLP;
        r0 = (z4 / 24) * 32; c0 = (z4 % 24) * 32;
    }
    int tid = threadIdx.x;
    // load: thread -> row r = tid>>3, 4 cols at (tid&7)*4
    {
        int r = tid >> 3, cq = (tid & 7) << 2;
        float4 v = *(const float4*)&src[(size_t)(r0 + r) * C + c0 + cq];
        t[r][cq] = v.x; t[r][cq + 1] = v.y; t[r][cq + 2] = v.z; t[r][cq + 3] = v.w;
    }
    __syncthreads();
    // store transposed: thread -> out-row c = tid>>3, 4 out-cols at (tid&7)*4
    {
        int c = tid >> 3, rq = (tid & 7) << 2;
        unsigned u0 = pack2bf(t[rq][c],     t[rq + 1][c]);
        unsigned u1 = pack2bf(t[rq + 2][c], t[rq + 3][c]);
        unsigned* dp = (unsigned*)&dst[(size_t)(c0 + c) * ldd + r0 + rq];
        dp[0] = u0; dp[1] = u1;
    }
}

// combined qkv bias for ALL layers: cb[l][2304]
__global__ void cball_k(const float* __restrict__ bq, const float* __restrict__ bk,
                        const float* __restrict__ bv, float* __restrict__ cb) {
    int idx = blockIdx.x * 256 + threadIdx.x;
    if (idx >= VL * 3 * VD) return;
    int l = idx / (3 * VD), n = idx % (3 * VD);
    int m = n / VD, wi = n % VD;
    const float* p = (m == 0) ? bq : (m == 1) ? bk : bv;
    cb[idx] = p[l * VD + wi];
}

// extract cls rows of x -> bf16 [32][768]
__global__ void cls_k(const float* __restrict__ x, __hip_bfloat16* __restrict__ out) {
    int idx = blockIdx.x * 256 + threadIdx.x;
    if (idx >= VB * VD) return;
    int b = idx / VD, d = idx % VD;
    out[idx] = __float2bfloat16(x[(size_t)b * VS * VD + d]);
}

// ---------------------------------------------------------------------------
// bf16 MFMA GEMM (m97-style 128x128, BK=64, LDS) + XCD swizzle.
// EPI: 0 = fp32 store w/ patch rowmap; 1 = bf16 store; 2 = fp32 accumulate;
//      3 = fast-GELU -> bf16; 4 = plain fp32 store.
// ---------------------------------------------------------------------------
template<int EPI>
__global__ __launch_bounds__(256) void bgemm_k(
    const __hip_bfloat16* __restrict__ A,
    const __hip_bfloat16* __restrict__ BT,
    const float* __restrict__ bias,
    void* __restrict__ Co,
    int M, int K, int ldc, int Ncols)
{
    __shared__ short A_s[128][64];
    __shared__ short B_s[128][64];
    int bx = blockIdx.x, by = blockIdx.y;
    xcd_swz(gridDim.x, gridDim.y, bx, by);
    const int tid = threadIdx.x;
    const int w = tid >> 6, l = tid & 63;
    const int row0 = by * 128, col0 = bx * 128;
    const int wm = (w >> 1) << 6, wn = (w & 1) << 6;
    f32x4 acc[4][4] = {};

    const int lr = l >> 3;
    const int sslot = (l & 7) ^ lr;
    int arow[4], brow[4];
    #pragma unroll
    for (int i = 0; i < 4; i++) {
        int r = (4 * w + i) * 8 + lr;
        arow[i] = min(row0 + r, M - 1);
        brow[i] = min(col0 + r, Ncols - 1);
    }
    for (int k0 = 0; k0 < K; k0 += 64) {
        __syncthreads();
        #pragma unroll
        for (int i = 0; i < 4; i++) {
            int ch = 4 * w + i;
            gload_lds16((const void*)(A + (size_t)arow[i] * K + k0 + (sslot << 3)),
                        (void*)(&A_s[ch * 8][0]));
            gload_lds16((const void*)(BT + (size_t)brow[i] * K + k0 + (sslot << 3)),
                        (void*)(&B_s[ch * 8][0]));
        }
        __syncthreads();
        #pragma unroll
        for (int ks = 0; ks < 2; ks++) {
            const int s16 = (ks << 2) + (l >> 4);
            short8 av[4], bv[4];
            #pragma unroll
            for (int i = 0; i < 4; i++) {
                int ar = wm + i * 16 + (l & 15);
                av[i] = *(const short8*)((const char*)&A_s[ar][0] + ((s16 ^ (ar & 7)) << 4));
                int br = wn + i * 16 + (l & 15);
                bv[i] = *(const short8*)((const char*)&B_s[br][0] + ((s16 ^ (br & 7)) << 4));
            }
            #pragma unroll
            for (int i = 0; i < 4; i++)
                #pragma unroll
                for (int j = 0; j < 4; j++)
                    acc[i][j] = __builtin_amdgcn_mfma_f32_16x16x32_bf16(av[i], bv[j], acc[i][j], 0, 0, 0);
        }
    }
    const int rbase = row0 + wm + ((l >> 4) << 2);
    const int cbase = col0 + wn + (l & 15);
    #pragma unroll
    for (int i = 0; i < 4; i++) {
        #pragma unroll
        for (int q = 0; q < 4; q++) {
            int rr = rbase + i * 16 + q;
            if (rr >= M) continue;
            #pragma unroll
            for (int j = 0; j < 4; j++) {
                int c = cbase + j * 16;
                if (c >= Ncols) continue;
                float v = acc[i][j][q] + bias[c];
                if (EPI == 0) {
                    int orow = rr + rr / VNPAT + 1;
                    ((float*)Co)[(size_t)orow * ldc + c] = v;
                } else if (EPI == 1) {
                    ((__hip_bfloat16*)Co)[(size_t)rr * ldc + c] = __float2bfloat16(v);
                } else if (EPI == 2) {
                    ((float*)Co)[(size_t)rr * ldc + c] += v;
                } else if (EPI == 3) {
                    ((__hip_bfloat16*)Co)[(size_t)rr * ldc + c] = __float2bfloat16(gelu_f(v));
                } else {
                    ((float*)Co)[(size_t)rr * ldc + c] = v;
                }
            }
        }
    }
}

// ---------------------------------------------------------------------------
// Split-K=2 partial GEMM: P[ks][M][ldc] = A[:, ks*K/2:(ks+1)*K/2] @ BT^T.
// ---------------------------------------------------------------------------
__global__ __launch_bounds__(256) void bgemm5_k(
    const __hip_bfloat16* __restrict__ A,
    const __hip_bfloat16* __restrict__ BT,
    float* __restrict__ P,
    int M, int K, int ldc)
{
    __shared__ short A_s[128][64];
    __shared__ short B_s[128][64];
    int bx = blockIdx.x, by = blockIdx.y;
    xcd_swz(gridDim.x, gridDim.y, bx, by);
    const int ks = blockIdx.z;
    const int khalf = K >> 1;
    const __hip_bfloat16* Ab  = A  + (size_t)ks * khalf;
    const __hip_bfloat16* BTb = BT + (size_t)ks * khalf;
    float* Pb = P + (size_t)ks * TOKD;

    const int tid = threadIdx.x;
    const int w = tid >> 6, l = tid & 63;
    const int row0 = by * 128, col0 = bx * 128;
    const int wm = (w >> 1) << 6, wn = (w & 1) << 6;
    f32x4 acc[4][4] = {};

    const int lr = l >> 3;
    const int sslot = (l & 7) ^ lr;
    int arow[4], brow[4];
    #pragma unroll
    for (int i = 0; i < 4; i++) {
        int r = (4 * w + i) * 8 + lr;
        arow[i] = min(row0 + r, M - 1);
        brow[i] = col0 + r;
    }
    for (int k0 = 0; k0 < khalf; k0 += 64) {
        __syncthreads();
        #pragma unroll
        for (int i = 0; i < 4; i++) {
            int ch = 4 * w + i;
            gload_lds16((const void*)(Ab + (size_t)arow[i] * K + k0 + (sslot << 3)),
                        (void*)(&A_s[ch * 8][0]));
            gload_lds16((const void*)(BTb + (size_t)brow[i] * K + k0 + (sslot << 3)),
                        (void*)(&B_s[ch * 8][0]));
        }
        __syncthreads();
        #pragma unroll
        for (int ks2 = 0; ks2 < 2; ks2++) {
            const int s16 = (ks2 << 2) + (l >> 4);
            short8 av[4], bv[4];
            #pragma unroll
            for (int i = 0; i < 4; i++) {
                int ar = wm + i * 16 + (l & 15);
                av[i] = *(const short8*)((const char*)&A_s[ar][0] + ((s16 ^ (ar & 7)) << 4));
                int br = wn + i * 16 + (l & 15);
                bv[i] = *(const short8*)((const char*)&B_s[br][0] + ((s16 ^ (br & 7)) << 4));
            }
            #pragma unroll
            for (int i = 0; i < 4; i++)
                #pragma unroll
                for (int j = 0; j < 4; j++)
                    acc[i][j] = __builtin_amdgcn_mfma_f32_16x16x32_bf16(av[i], bv[j], acc[i][j], 0, 0, 0);
        }
    }
    const int rbase = row0 + wm + ((l >> 4) << 2);
    const int cbase = col0 + wn + (l & 15);
    #pragma unroll
    for (int i = 0; i < 4; i++) {
        #pragma unroll
        for (int q = 0; q < 4; q++) {
            int rr = rbase + i * 16 + q;
            if (rr >= M) continue;
            #pragma unroll
            for (int j = 0; j < 4; j++) {
                int c = cbase + j * 16;
                Pb[(size_t)rr * ldc + c] = acc[i][j][q];
            }
        }
    }
}

// ---------------------------------------------------------------------------
// MFMA attention. Two blocks per (b,h), 256 threads, 4 waves.
// ---------------------------------------------------------------------------
__device__ __forceinline__ int swz_idx(int row, int k) {
    return row * 256 + (((k >> 3) ^ (row & 7)) << 3) + (k & 7);
}

__global__ __launch_bounds__(256) void attn3_k(
    const __hip_bfloat16* __restrict__ qkv, __hip_bfloat16* __restrict__ o)
{
    __shared__ short V_t[64 * 256];
    __shared__ short P_s[4][16 * 256];
    const int half = blockIdx.x;
    const int bh = blockIdx.y;
    const int b = bh / VNH, h = bh % VNH;
    const int tid = threadIdx.x, w = tid >> 6, l = tid & 63;
    const int g = l >> 4, c16 = l & 15;

    const __hip_bfloat16* base = qkv + (size_t)(b * VS) * (3 * VD) + h * VDQ;

    {
        const __hip_bfloat16* vbase = base + 2 * VD;
        int t = tid & 31, e0 = (tid >> 5) * 8;
        #pragma unroll
        for (int it = 0; it < 7; it++) {
            int tt = it * 32 + t;
            if (tt < VS) {
                short8 vv = *(const short8*)(vbase + (size_t)tt * (3 * VD) + e0);
                #pragma unroll
                for (int j = 0; j < 8; j++) V_t[swz_idx(e0 + j, tt)] = vv[j];
            }
        }
        for (int idx = tid; idx < 64 * 27; idx += 256) {
            int e = idx / 27, k = 197 + idx % 27;
            V_t[swz_idx(e, k)] = 0;
        }
    }
    {
        unsigned* p0 = (unsigned*)&P_s[w][swz_idx(c16, 208 + g * 4)];
        p0[0] = 0; p0[1] = 0;
    }
    __syncthreads();

    const int qt_end = half ? 13 : 7;
    for (int qt = 7 * half + w; qt < qt_end; qt += 4) {
        const int q0 = qt * 16;
        int qr = min(q0 + c16, VS - 1);
        const __hip_bfloat16* qp = base + (size_t)qr * (3 * VD) + g * 8;
        short8 qa0 = *(const short8*)(qp);
        short8 qa1 = *(const short8*)(qp + 32);

        f32x4 st[13];
        __builtin_amdgcn_s_setprio(1);
        #pragma unroll
        for (int t = 0; t < 13; t++) {
            int kr = min(t * 16 + c16, VS - 1);
            const __hip_bfloat16* kp = base + VD + (size_t)kr * (3 * VD) + g * 8;
            short8 ka0 = *(const short8*)(kp);
            short8 ka1 = *(const short8*)(kp + 32);
            f32x4 z = {};
            z = __builtin_amdgcn_mfma_f32_16x16x32_bf16(ka0, qa0, z, 0, 0, 0);
            z = __builtin_amdgcn_mfma_f32_16x16x32_bf16(ka1, qa1, z, 0, 0, 0);
            st[t] = z;
        }
        __builtin_amdgcn_s_setprio(0);
        #pragma unroll
        for (int t = 0; t < 13; t++) {
            #pragma unroll
            for (int r = 0; r < 4; r++) {
                float v = st[t][r] * 0.125f;
                if (t == 12 && (4 * g + r) >= 5) v = -3.0e38f;
                st[t][r] = v;
            }
        }
        float m = -3.0e38f;
        #pragma unroll
        for (int t = 0; t < 13; t++)
            #pragma unroll
            for (int r = 0; r < 4; r++) m = fmaxf(m, st[t][r]);
        m = fmaxf(m, __shfl_xor(m, 16));
        m = fmaxf(m, __shfl_xor(m, 32));
        float sum = 0.f;
        #pragma unroll
        for (int t = 0; t < 13; t++)
            #pragma unroll
            for (int r = 0; r < 4; r++) { float e = expf(st[t][r] - m); st[t][r] = e; sum += e; }
        sum += __shfl_xor(sum, 16);
        sum += __shfl_xor(sum, 32);
        float inv = 1.f / sum;
        #pragma unroll
        for (int t = 0; t < 13; t++) {
            int k0 = 16 * t + 4 * g;
            unsigned* pp = (unsigned*)&P_s[w][swz_idx(c16, k0)];
            pp[0] = pack2bf(st[t][0] * inv, st[t][1] * inv);
            pp[1] = pack2bf(st[t][2] * inv, st[t][3] * inv);
        }
        f32x4 acc[4] = {};
        __builtin_amdgcn_s_setprio(1);
        #pragma unroll
        for (int ki = 0; ki < 7; ki++) {
            int k0 = ki * 32 + g * 8;
            short8 pa = *(const short8*)&P_s[w][swz_idx(c16, k0)];
            #pragma unroll
            for (int et = 0; et < 4; et++) {
                short8 vbf = *(const short8*)&V_t[swz_idx(et * 16 + c16, k0)];
                acc[et] = __builtin_amdgcn_mfma_f32_16x16x32_bf16(pa, vbf, acc[et], 0, 0, 0);
            }
        }
        __builtin_amdgcn_s_setprio(0);
        #pragma unroll
        for (int et = 0; et < 4; et++) {
            #pragma unroll
            for (int r = 0; r < 4; r++) {
                int q = q0 + 4 * g + r;
                if (q < VS)
                    o[((size_t)(b * VS) + q) * VD + h * VDQ + et * 16 + c16] =
                        __float2bfloat16(acc[et][r]);
            }
        }
    }
}

// ---------------------------------------------------------------------------
extern "C" void kernel_launch(void* const* d_in, const int* in_sizes, int n_in,
                              void* d_out, int out_size, void* d_ws, size_t ws_size,
                              hipStream_t stream) {
    (void)in_sizes; (void)n_in; (void)out_size; (void)ws_size;
    const float* X       = (const float*)d_in[0];
    const float* patch_W = (const float*)d_in[1];
    const float* patch_b = (const float*)d_in[2];
    const float* cls_tok = (const float*)d_in[3];
    const float* ln1_g   = (const float*)d_in[4];
    const float* ln1_b   = (const float*)d_in[5];
    const float* Wq      = (const float*)d_in[6];
    const float* bq      = (const float*)d_in[7];
    const float* Wk      = (const float*)d_in[8];
    const float* bk      = (const float*)d_in[9];
    const float* Wv      = (const float*)d_in[10];
    const float* bv      = (const float*)d_in[11];
    const float* proj_W  = (const float*)d_in[12];
    const float* proj_b  = (const float*)d_in[13];
    const float* ln2_g   = (const float*)d_in[14];
    const float* ln2_b   = (const float*)d_in[15];
    const float* mlp_W1  = (const float*)d_in[16];
    const float* mlp_b1  = (const float*)d_in[17];
    const float* mlp_W2  = (const float*)d_in[18];
    const float* mlp_b2  = (const float*)d_in[19];
    const float* head_W  = (const float*)d_in[20];
    const float* head_b  = (const float*)d_in[21];

    char* ws = (char*)d_ws;
    float*          x    = (float*)ws;                            // 19.37 MB fp32
    __hip_bfloat16* tb   = (__hip_bfloat16*)(ws + 19365888);      // 9.68 MB bf16
    __hip_bfloat16* big  = (__hip_bfloat16*)(ws + 29048832);      // 38.73 MB
    __hip_bfloat16* wT   = (__hip_bfloat16*)(ws + 67780608);      // 14.16 MB
    float*          cbA  = (float*)(ws + 81936384);               // 110 KB (12x2304)
    float*          pbuf = (float*)(ws + 82046976);               // 38.73 MB (2x TOKD fp32)

    cball_k<<<(VL * 3 * VD + 255) / 256, 256, 0, stream>>>(bq, bk, bv, cbA);

    patchify_k<<<(VB * VNPAT * VP + 255) / 256, 256, 0, stream>>>(X, big);
    {
        dim3 g(VD / 32, VP / 32);
        tpose_k<<<g, 256, 0, stream>>>(patch_W, wT, VP, VD);
    }
    {
        dim3 g(VD / 128, VB * VNPAT / 128);
        bgemm_k<0><<<g, 256, 0, stream>>>(big, wT, patch_b, x, VB * VNPAT, VP, VD, VD);
    }
    pos_cls_k<<<(unsigned)((TOKD + 255) / 256), 256, 0, stream>>>(x, cls_tok);

    const size_t WSZ = (size_t)VNH * VD * VDQ;
    for (int l = 0; l < VL; l++) {
        wprep_k<<<6912, 256, 0, stream>>>(
            Wq + l * WSZ, Wk + l * WSZ, Wv + l * WSZ,
            proj_W + (size_t)l * VD * VD,
            mlp_W1 + (size_t)l * VD * VMLP,
            mlp_W2 + (size_t)l * VMLP * VD, wT);

        if (l == 0)
            layernorm_k<<<VTOK, 256, 0, stream>>>(x, tb, ln1_g, ln1_b);

        {
            // fused QKV GEMM: grid 18 x 50 (swizzled)
            dim3 g(3 * VD / 128, (VTOK + 127) / 128);
            bgemm_k<1><<<g, 256, 0, stream>>>(tb, wT, cbA + l * 3 * VD, big,
                                              VTOK, VD, 3 * VD, 3 * VD);
        }
        {
            dim3 ga(2, VB * VNH);
            attn3_k<<<ga, 256, 0, stream>>>(big, tb);
        }
        {
            // proj split-K=2 -> partials, then combine + residual + LN2
            dim3 g(VD / 128, (VTOK + 127) / 128, 2);
            bgemm5_k<<<g, 256, 0, stream>>>(tb, wT + OFF_PROJ, pbuf, VTOK, VD, VD);
            combineln_k<1><<<VTOK, 256, 0, stream>>>(
                x, pbuf, pbuf + TOKD, proj_b + l * VD,
                ln2_g + l * VD, ln2_b + l * VD, tb);
        }
        {
            // MLP1 (fast-GELU epilogue): grid 24 x 50 (swizzled)
            dim3 g(VMLP / 128, (VTOK + 127) / 128);
            bgemm_k<3><<<g, 256, 0, stream>>>(tb, wT + OFF_M1, mlp_b1 + l * VMLP, big,
                                              VTOK, VD, VMLP, VMLP);
        }
        {
            // MLP2 split-K=2 -> partials, then combine + residual (+ next LN1)
            dim3 g(VD / 128, (VTOK + 127) / 128, 2);
            bgemm5_k<<<g, 256, 0, stream>>>(big, wT + OFF_M2, pbuf, VTOK, VMLP, VD);
            if (l + 1 < VL)
                combineln_k<1><<<VTOK, 256, 0, stream>>>(
                    x, pbuf, pbuf + TOKD, mlp_b2 + l * VD,
                    ln1_g + (l + 1) * VD, ln1_b + (l + 1) * VD, tb);
            else
                combineln_k<0><<<VTOK, 256, 0, stream>>>(
                    x, pbuf, pbuf + TOKD, mlp_b2 + l * VD,
                    nullptr, nullptr, nullptr);
        }
    }
    // head
    cls_k<<<(VB * VD + 255) / 256, 256, 0, stream>>>(x, tb);
    {
        dim3 gt((VC + 31) / 32, VD / 32);
        tpose_k<<<gt, 256, 0, stream>>>(head_W, wT, VD, VC);
        dim3 g((VC + 127) / 128, 1);
        bgemm_k<4><<<g, 256, 0, stream>>>(tb, wT, head_b, (float*)d_out,
                                          VB, VD, VC, VC);
    }
}

// Round 10
// 3125.477 us; speedup vs baseline: 1.6805x; 1.0628x over previous
//
#include <hip/hip_runtime.h>
#include <hip/hip_bf16.h>
#include <math.h>
#include <stdint.h>

// ViT config
#define VB   32
#define VS   197
#define VD   768
#define VNH  12
#define VDQ  64
#define VL   12
#define VMLP 3072
#define VC   1000
#define VP   256
#define VNPAT 196
#define VTOK (VB * VS)            // 6304
#define TOKD ((size_t)VTOK * VD)  // 4841472 floats

typedef __attribute__((ext_vector_type(4))) float f32x4;
typedef __attribute__((ext_vector_type(8))) short short8;

typedef __attribute__((address_space(1))) const unsigned int GU;
typedef __attribute__((address_space(3))) unsigned int LU;

__device__ __forceinline__ void gload_lds16(const void* g, void* l) {
    __builtin_amdgcn_global_load_lds((GU*)(uintptr_t)g, (LU*)(uintptr_t)l, 16, 0, 0);
}

// T1: bijective XCD-aware block swizzle (m204).
__device__ __forceinline__ void xcd_swz(int gx, int gy, int& bx, int& by) {
    int nwg = gx * gy;
    int hw = by * gx + bx;
    int q = nwg >> 3, r = nwg & 7;
    int xcd = hw & 7, off = hw >> 3;
    int lid = (xcd < r ? xcd * (q + 1) : r * (q + 1) + (xcd - r) * q) + off;
    bx = lid % gx; by = lid / gx;
}

// Fast tanh-form GELU.
__device__ __forceinline__ float gelu_f(float x) {
    float t = 0.7978845608f * x * fmaf(0.044715f, x * x, 1.0f);
    float a = fminf(t * 2.8853900818f, 80.0f);
    float e = __builtin_amdgcn_exp2f(a);
    return x * e * __builtin_amdgcn_rcpf(1.0f + e);
}

// ---------------------------------------------------------------------------
__global__ void patchify_k(const float* __restrict__ X, __hip_bfloat16* __restrict__ P) {
    int idx = blockIdx.x * 256 + threadIdx.x;
    const int total = VB * VNPAT * VP;
    if (idx >= total) return;
    int i  = idx & 255;
    int p  = (idx >> 8) % VNPAT;
    int b  = (idx >> 8) / VNPAT;
    int pr = p / 14, pc = p % 14;
    int a  = i >> 4, c2 = i & 15;
    P[idx] = __float2bfloat16(X[((size_t)b * 224 + pr * 16 + a) * 224 + pc * 16 + c2]);
}

__global__ void pos_cls_k(float* __restrict__ x, const float* __restrict__ cls) {
    size_t idx = (size_t)blockIdx.x * 256 + threadIdx.x;
    if (idx >= TOKD) return;
    int j = (int)(idx % VD);
    int s = (int)((idx / VD) % VS);
    float jj = (float)(j & ~1);
    float freq = expf(-(jj / (float)VD) * 9.2103403719761836f);
    float ang  = (float)s * freq;
    float pe   = (j & 1) ? cosf(ang) : sinf(ang);
    if (s == 0) x[idx] = cls[j] + pe;
    else        x[idx] += pe;
}

__global__ __launch_bounds__(256) void layernorm_k(
    const float* __restrict__ x, __hip_bfloat16* __restrict__ y,
    const float* __restrict__ g, const float* __restrict__ bta)
{
    int t = blockIdx.x;
    const float* xr = x + (size_t)t * VD;
    __hip_bfloat16* yr = y + (size_t)t * VD;
    int tid = threadIdx.x;
    float v[3];
    float s = 0.f;
    #pragma unroll
    for (int i = 0; i < 3; i++) { v[i] = xr[tid + i * 256]; s += v[i]; }
    __shared__ float red[8];
    #pragma unroll
    for (int off = 32; off; off >>= 1) s += __shfl_xor(s, off);
    int lane = tid & 63, w = tid >> 6;
    if (!lane) red[w] = s;
    __syncthreads();
    float mu = (red[0] + red[1] + red[2] + red[3]) * (1.f / VD);
    float s2 = 0.f;
    #pragma unroll
    for (int i = 0; i < 3; i++) { float d0 = v[i] - mu; s2 += d0 * d0; }
    #pragma unroll
    for (int off = 32; off; off >>= 1) s2 += __shfl_xor(s2, off);
    if (!lane) red[4 + w] = s2;
    __syncthreads();
    float var = (red[4] + red[5] + red[6] + red[7]) * (1.f / VD);
    float rs = rsqrtf(var + 1e-5f);
    #pragma unroll
    for (int i = 0; i < 3; i++) {
        int j = tid + i * 256;
        yr[j] = __float2bfloat16((v[i] - mu) * rs * g[j] + bta[j]);
    }
}

template<int DO_LN>
__global__ __launch_bounds__(256) void combineln_k(
    float* __restrict__ x, const float* __restrict__ p0, const float* __restrict__ p1,
    const float* __restrict__ bias, const float* __restrict__ g,
    const float* __restrict__ bta, __hip_bfloat16* __restrict__ y)
{
    int t = blockIdx.x;
    size_t base = (size_t)t * VD;
    int tid = threadIdx.x;
    float v[3];
    float s = 0.f;
    #pragma unroll
    for (int i = 0; i < 3; i++) {
        int j = tid + i * 256;
        float val = x[base + j] + p0[base + j] + p1[base + j] + bias[j];
        x[base + j] = val;
        v[i] = val; s += val;
    }
    if (DO_LN) {
        __shared__ float red[8];
        #pragma unroll
        for (int off = 32; off; off >>= 1) s += __shfl_xor(s, off);
        int lane = tid & 63, w = tid >> 6;
        if (!lane) red[w] = s;
        __syncthreads();
        float mu = (red[0] + red[1] + red[2] + red[3]) * (1.f / VD);
        float s2 = 0.f;
        #pragma unroll
        for (int i = 0; i < 3; i++) { float d0 = v[i] - mu; s2 += d0 * d0; }
        #pragma unroll
        for (int off = 32; off; off >>= 1) s2 += __shfl_xor(s2, off);
        if (!lane) red[4 + w] = s2;
        __syncthreads();
        float var = (red[4] + red[5] + red[6] + red[7]) * (1.f / VD);
        float rs = rsqrtf(var + 1e-5f);
        #pragma unroll
        for (int i = 0; i < 3; i++) {
            int j = tid + i * 256;
            y[base + j] = __float2bfloat16((v[i] - mu) * rs * g[j] + bta[j]);
        }
    }
}

__global__ __launch_bounds__(256) void tpose_k(
    const float* __restrict__ in, __hip_bfloat16* __restrict__ out, int R, int C)
{
    __shared__ float t[32][33];
    int c0 = blockIdx.x * 32, r0 = blockIdx.y * 32;
    int tc = threadIdx.x & 31, tr = threadIdx.x >> 5;
    #pragma unroll
    for (int p = 0; p < 4; p++) {
        int r = r0 + tr + p * 8;
        t[tr + p * 8][tc] = (r < R && c0 + tc < C) ? in[(size_t)r * C + c0 + tc] : 0.f;
    }
    __syncthreads();
    #pragma unroll
    for (int p = 0; p < 4; p++) {
        int c = c0 + tr + p * 8;
        if (c < C && r0 + tc < R)
            out[(size_t)c * R + r0 + tc] = __float2bfloat16(t[tc][tr + p * 8]);
    }
}

#define OFF_PROJ (2304 * 768)
#define OFF_M1   (OFF_PROJ + 768 * 768)
#define OFF_M2   (OFF_M1 + 3072 * 768)

__device__ __forceinline__ unsigned pack2bf(float a, float b) {
    __hip_bfloat16 x = __float2bfloat16(a), y = __float2bfloat16(b);
    unsigned short ux = *(unsigned short*)&x, uy = *(unsigned short*)&y;
    return (unsigned)ux | ((unsigned)uy << 16);
}

__global__ __launch_bounds__(256) void wprep_k(
    const float* __restrict__ Wq, const float* __restrict__ Wk,
    const float* __restrict__ Wv, const float* __restrict__ Wp,
    const float* __restrict__ W1, const float* __restrict__ W2,
    __hip_bfloat16* __restrict__ wT)
{
    __shared__ float t[32][33];
    int z = blockIdx.x;
    const float* src; __hip_bfloat16* dst;
    int C, ldd, r0, c0;
    if (z < 1728) {
        int head = z / 48, tt = z % 48;
        int m = head / VNH, h = head % VNH;
        src = (m == 0 ? Wq : m == 1 ? Wk : Wv) + (size_t)h * VD * VDQ;
        dst = wT + ((size_t)m * VD + h * VDQ) * VD;
        C = VDQ; ldd = VD;
        r0 = (tt >> 1) * 32; c0 = (tt & 1) * 32;
    } else if (z < 2304) {
        int z2 = z - 1728;
        src = Wp; dst = wT + OFF_PROJ;
        C = VD; ldd = VD;
        r0 = (z2 / 24) * 32; c0 = (z2 % 24) * 32;
    } else if (z < 4608) {
        int z3 = z - 2304;
        src = W1; dst = wT + OFF_M1;
        C = VMLP; ldd = VD;
        r0 = (z3 / 96) * 32; c0 = (z3 % 96) * 32;
    } else {
        int z4 = z - 4608;
        src = W2; dst = wT + OFF_M2;
        C = VD; ldd = VMLP;
        r0 = (z4 / 24) * 32; c0 = (z4 % 24) * 32;
    }
    int tid = threadIdx.x;
    {
        int r = tid >> 3, cq = (tid & 7) << 2;
        float4 v = *(const float4*)&src[(size_t)(r0 + r) * C + c0 + cq];
        t[r][cq] = v.x; t[r][cq + 1] = v.y; t[r][cq + 2] = v.z; t[r][cq + 3] = v.w;
    }
    __syncthreads();
    {
        int c = tid >> 3, rq = (tid & 7) << 2;
        unsigned u0 = pack2bf(t[rq][c],     t[rq + 1][c]);
        unsigned u1 = pack2bf(t[rq + 2][c], t[rq + 3][c]);
        unsigned* dp = (unsigned*)&dst[(size_t)(c0 + c) * ldd + r0 + rq];
        dp[0] = u0; dp[1] = u1;
    }
}

__global__ void cball_k(const float* __restrict__ bq, const float* __restrict__ bk,
                        const float* __restrict__ bv, float* __restrict__ cb) {
    int idx = blockIdx.x * 256 + threadIdx.x;
    if (idx >= VL * 3 * VD) return;
    int l = idx / (3 * VD), n = idx % (3 * VD);
    int m = n / VD, wi = n % VD;
    const float* p = (m == 0) ? bq : (m == 1) ? bk : bv;
    cb[idx] = p[l * VD + wi];
}

__global__ void cls_k(const float* __restrict__ x, __hip_bfloat16* __restrict__ out) {
    int idx = blockIdx.x * 256 + threadIdx.x;
    if (idx >= VB * VD) return;
    int b = idx / VD, d = idx % VD;
    out[idx] = __float2bfloat16(x[(size_t)b * VS * VD + d]);
}

// ---------------------------------------------------------------------------
// bf16 MFMA GEMM (m97-style 128x128) + XCD swizzle — for patch/head (+ spares).
// ---------------------------------------------------------------------------
template<int EPI>
__global__ __launch_bounds__(256) void bgemm_k(
    const __hip_bfloat16* __restrict__ A,
    const __hip_bfloat16* __restrict__ BT,
    const float* __restrict__ bias,
    void* __restrict__ Co,
    int M, int K, int ldc, int Ncols)
{
    __shared__ short A_s[128][64];
    __shared__ short B_s[128][64];
    int bx = blockIdx.x, by = blockIdx.y;
    xcd_swz(gridDim.x, gridDim.y, bx, by);
    const int tid = threadIdx.x;
    const int w = tid >> 6, l = tid & 63;
    const int row0 = by * 128, col0 = bx * 128;
    const int wm = (w >> 1) << 6, wn = (w & 1) << 6;
    f32x4 acc[4][4] = {};

    const int lr = l >> 3;
    const int sslot = (l & 7) ^ lr;
    int arow[4], brow[4];
    #pragma unroll
    for (int i = 0; i < 4; i++) {
        int r = (4 * w + i) * 8 + lr;
        arow[i] = min(row0 + r, M - 1);
        brow[i] = min(col0 + r, Ncols - 1);
    }
    for (int k0 = 0; k0 < K; k0 += 64) {
        __syncthreads();
        #pragma unroll
        for (int i = 0; i < 4; i++) {
            int ch = 4 * w + i;
            gload_lds16((const void*)(A + (size_t)arow[i] * K + k0 + (sslot << 3)),
                        (void*)(&A_s[ch * 8][0]));
            gload_lds16((const void*)(BT + (size_t)brow[i] * K + k0 + (sslot << 3)),
                        (void*)(&B_s[ch * 8][0]));
        }
        __syncthreads();
        #pragma unroll
        for (int ks = 0; ks < 2; ks++) {
            const int s16 = (ks << 2) + (l >> 4);
            short8 av[4], bv[4];
            #pragma unroll
            for (int i = 0; i < 4; i++) {
                int ar = wm + i * 16 + (l & 15);
                av[i] = *(const short8*)((const char*)&A_s[ar][0] + ((s16 ^ (ar & 7)) << 4));
                int br = wn + i * 16 + (l & 15);
                bv[i] = *(const short8*)((const char*)&B_s[br][0] + ((s16 ^ (br & 7)) << 4));
            }
            #pragma unroll
            for (int i = 0; i < 4; i++)
                #pragma unroll
                for (int j = 0; j < 4; j++)
                    acc[i][j] = __builtin_amdgcn_mfma_f32_16x16x32_bf16(av[i], bv[j], acc[i][j], 0, 0, 0);
        }
    }
    const int rbase = row0 + wm + ((l >> 4) << 2);
    const int cbase = col0 + wn + (l & 15);
    #pragma unroll
    for (int i = 0; i < 4; i++) {
        #pragma unroll
        for (int q = 0; q < 4; q++) {
            int rr = rbase + i * 16 + q;
            if (rr >= M) continue;
            #pragma unroll
            for (int j = 0; j < 4; j++) {
                int c = cbase + j * 16;
                if (c >= Ncols) continue;
                float v = acc[i][j][q] + bias[c];
                if (EPI == 0) {
                    int orow = rr + rr / VNPAT + 1;
                    ((float*)Co)[(size_t)orow * ldc + c] = v;
                } else if (EPI == 1) {
                    ((__hip_bfloat16*)Co)[(size_t)rr * ldc + c] = __float2bfloat16(v);
                } else if (EPI == 2) {
                    ((float*)Co)[(size_t)rr * ldc + c] += v;
                } else if (EPI == 3) {
                    ((__hip_bfloat16*)Co)[(size_t)rr * ldc + c] = __float2bfloat16(gelu_f(v));
                } else {
                    ((float*)Co)[(size_t)rr * ldc + c] = v;
                }
            }
        }
    }
}

// ---------------------------------------------------------------------------
// bgemm8_k: 256x256 tile, 512 threads (8 waves, 2M x 4N, per-wave 128x64 out),
// BK=32 K-tiles in a 3-slot LDS ring (96 KB), counted vmcnt(4) per K-tile.
// Ledger (provable):
//  - tile t computed in 2 phases from slot t%3; tile t+2 staged (during tile
//    t's phases) into slot (t+2)%3 — disjoint from t%3 and (t+1)%3.
//  - overwrite-safe: slot (t+2)%3 last served tile t-1 whose ds_reads
//    completed (lgkmcnt 0) before a barrier every wave crossed.
//  - landing-safe: per K-tile boundary, each wave waits vmcnt(4) (own 4
//    newest = tile t+2's stages may pend; tile t+1 landed) THEN s_barrier
//    publishes all waves' data before any wave reads tile t+1.
//  - ds_read swizzle = r4's measured-0-conflict scheme (slot ^= (row>>1)&3).
// Requires N multiple of 256, K multiple of 32, K/32 >= 3. M clamped.
// EPI: 1 = bf16 store; 3 = fast-GELU -> bf16 store.
// ---------------------------------------------------------------------------
template<int EPI>
__global__ __launch_bounds__(512) void bgemm8_k(
    const __hip_bfloat16* __restrict__ A,
    const __hip_bfloat16* __restrict__ BT,
    const float* __restrict__ bias,
    __hip_bfloat16* __restrict__ Co,
    int M, int K, int ldc)
{
    __shared__ short SA[3][256][32];
    __shared__ short SB[3][256][32];
    const int tid = threadIdx.x;
    const int w = tid >> 6, l = tid & 63;
    const int fr = l & 15, g = l >> 4;
    const int wr = w >> 2, wc = w & 3;
    const int row0 = blockIdx.y * 256, col0 = blockIdx.x * 256;
    f32x4 acc[8][4] = {};

    // staging: unit u (0,1) = rows u*128..u*128+127 of the 256-row tile,
    // one BK=32 slab (64B rows = 4 16B slots). 512 thr x 1 gload per unit.
    const int sr = tid >> 2;                         // row within half
    const int sslot = (tid & 3) ^ ((sr >> 1) & 3);   // pre-swizzled source slot
    const __hip_bfloat16* aS[2]; const __hip_bfloat16* bS[2];
    #pragma unroll
    for (int u = 0; u < 2; u++) {
        aS[u] = A  + (size_t)min(row0 + u * 128 + sr, M - 1) * K + sslot * 8;
        bS[u] = BT + (size_t)(col0 + u * 128 + sr) * K + sslot * 8;
    }
    const int doff = sr * 64 + (tid & 3) * 16;       // linear dst byte offset

    #define STG_A(ring, t) { const int k0 = (t) << 5;                          \
        gload_lds16(aS[0] + k0, (char*)&SA[ring][0][0] + doff);                \
        gload_lds16(aS[1] + k0, (char*)&SA[ring][0][0] + 8192 + doff); }
    #define STG_B(ring, t) { const int k0 = (t) << 5;                          \
        gload_lds16(bS[0] + k0, (char*)&SB[ring][0][0] + doff);                \
        gload_lds16(bS[1] + k0, (char*)&SB[ring][0][0] + 8192 + doff); }

    const int nt = K >> 5;
    // prologue: stage tiles 0 (slot 0) and 1 (slot 1); publish tile 0.
    STG_A(0, 0); STG_B(0, 0);
    STG_A(1, 1); STG_B(1, 1);
    asm volatile("s_waitcnt vmcnt(4)" ::: "memory");
    __builtin_amdgcn_s_barrier();

    short8 breg[4];
    for (int t = 0; t < nt; t++) {
        const int ring = t % 3;
        const int rs   = (t + 2) % 3;
        const char* sa = (const char*)&SA[ring][0][0];
        const char* sb = (const char*)&SB[ring][0][0];
        short8 areg[4];
        // ---- phase 0: B-frags + A-frags 0..3 ----
        #pragma unroll
        for (int n = 0; n < 4; n++) {
            int br = wc * 64 + n * 16 + fr;
            breg[n] = *(const short8*)(sb + br * 64 + ((g ^ ((br >> 1) & 3)) << 4));
        }
        #pragma unroll
        for (int m = 0; m < 4; m++) {
            int ar = wr * 128 + m * 16 + fr;
            areg[m] = *(const short8*)(sa + ar * 64 + ((g ^ ((ar >> 1) & 3)) << 4));
        }
        if (t + 2 < nt) STG_A(rs, t + 2);
        __builtin_amdgcn_s_barrier();
        asm volatile("s_waitcnt lgkmcnt(0)" ::: "memory");
        __builtin_amdgcn_sched_barrier(0);
        __builtin_amdgcn_s_setprio(1);
        #pragma unroll
        for (int m = 0; m < 4; m++)
            #pragma unroll
            for (int n = 0; n < 4; n++)
                acc[m][n] = __builtin_amdgcn_mfma_f32_16x16x32_bf16(areg[m], breg[n], acc[m][n], 0, 0, 0);
        __builtin_amdgcn_s_setprio(0);
        __builtin_amdgcn_s_barrier();
        // ---- phase 1: A-frags 4..7 (reuse breg) ----
        #pragma unroll
        for (int m = 0; m < 4; m++) {
            int ar = wr * 128 + (m + 4) * 16 + fr;
            areg[m] = *(const short8*)(sa + ar * 64 + ((g ^ ((ar >> 1) & 3)) << 4));
        }
        if (t + 2 < nt) STG_B(rs, t + 2);
        __builtin_amdgcn_s_barrier();
        asm volatile("s_waitcnt lgkmcnt(0)" ::: "memory");
        __builtin_amdgcn_sched_barrier(0);
        __builtin_amdgcn_s_setprio(1);
        #pragma unroll
        for (int m = 0; m < 4; m++)
            #pragma unroll
            for (int n = 0; n < 4; n++)
                acc[m + 4][n] = __builtin_amdgcn_mfma_f32_16x16x32_bf16(areg[m], breg[n], acc[m + 4][n], 0, 0, 0);
        __builtin_amdgcn_s_setprio(0);
        // ---- K-tile boundary: wait (counted) THEN publish-barrier ----
        if (t + 2 < nt) {
            asm volatile("s_waitcnt vmcnt(4)" ::: "memory");
            __builtin_amdgcn_s_barrier();
        } else if (t + 1 < nt) {
            asm volatile("s_waitcnt vmcnt(0)" ::: "memory");
            __builtin_amdgcn_s_barrier();
        }
    }
    #undef STG_A
    #undef STG_B

    const int rb = row0 + wr * 128 + (g << 2);
    const int cb = col0 + wc * 64 + fr;
    #pragma unroll
    for (int m = 0; m < 8; m++) {
        #pragma unroll
        for (int q = 0; q < 4; q++) {
            int rr = rb + m * 16 + q;
            if (rr >= M) continue;
            #pragma unroll
            for (int n = 0; n < 4; n++) {
                int c = cb + n * 16;
                float v = acc[m][n][q] + bias[c];
                if (EPI == 3) v = gelu_f(v);
                Co[(size_t)rr * ldc + c] = __float2bfloat16(v);
            }
        }
    }
}

// ---------------------------------------------------------------------------
// Split-K=2 partial GEMM (proj / MLP2).
// ---------------------------------------------------------------------------
__global__ __launch_bounds__(256) void bgemm5_k(
    const __hip_bfloat16* __restrict__ A,
    const __hip_bfloat16* __restrict__ BT,
    float* __restrict__ P,
    int M, int K, int ldc)
{
    __shared__ short A_s[128][64];
    __shared__ short B_s[128][64];
    int bx = blockIdx.x, by = blockIdx.y;
    xcd_swz(gridDim.x, gridDim.y, bx, by);
    const int ks = blockIdx.z;
    const int khalf = K >> 1;
    const __hip_bfloat16* Ab  = A  + (size_t)ks * khalf;
    const __hip_bfloat16* BTb = BT + (size_t)ks * khalf;
    float* Pb = P + (size_t)ks * TOKD;

    const int tid = threadIdx.x;
    const int w = tid >> 6, l = tid & 63;
    const int row0 = by * 128, col0 = bx * 128;
    const int wm = (w >> 1) << 6, wn = (w & 1) << 6;
    f32x4 acc[4][4] = {};

    const int lr = l >> 3;
    const int sslot = (l & 7) ^ lr;
    int arow[4], brow[4];
    #pragma unroll
    for (int i = 0; i < 4; i++) {
        int r = (4 * w + i) * 8 + lr;
        arow[i] = min(row0 + r, M - 1);
        brow[i] = col0 + r;
    }
    for (int k0 = 0; k0 < khalf; k0 += 64) {
        __syncthreads();
        #pragma unroll
        for (int i = 0; i < 4; i++) {
            int ch = 4 * w + i;
            gload_lds16((const void*)(Ab + (size_t)arow[i] * K + k0 + (sslot << 3)),
                        (void*)(&A_s[ch * 8][0]));
            gload_lds16((const void*)(BTb + (size_t)brow[i] * K + k0 + (sslot << 3)),
                        (void*)(&B_s[ch * 8][0]));
        }
        __syncthreads();
        #pragma unroll
        for (int ks2 = 0; ks2 < 2; ks2++) {
            const int s16 = (ks2 << 2) + (l >> 4);
            short8 av[4], bv[4];
            #pragma unroll
            for (int i = 0; i < 4; i++) {
                int ar = wm + i * 16 + (l & 15);
                av[i] = *(const short8*)((const char*)&A_s[ar][0] + ((s16 ^ (ar & 7)) << 4));
                int br = wn + i * 16 + (l & 15);
                bv[i] = *(const short8*)((const char*)&B_s[br][0] + ((s16 ^ (br & 7)) << 4));
            }
            #pragma unroll
            for (int i = 0; i < 4; i++)
                #pragma unroll
                for (int j = 0; j < 4; j++)
                    acc[i][j] = __builtin_amdgcn_mfma_f32_16x16x32_bf16(av[i], bv[j], acc[i][j], 0, 0, 0);
        }
    }
    const int rbase = row0 + wm + ((l >> 4) << 2);
    const int cbase = col0 + wn + (l & 15);
    #pragma unroll
    for (int i = 0; i < 4; i++) {
        #pragma unroll
        for (int q = 0; q < 4; q++) {
            int rr = rbase + i * 16 + q;
            if (rr >= M) continue;
            #pragma unroll
            for (int j = 0; j < 4; j++) {
                int c = cbase + j * 16;
                Pb[(size_t)rr * ldc + c] = acc[i][j][q];
            }
        }
    }
}

// ---------------------------------------------------------------------------
// MFMA attention. Two blocks per (b,h), 256 threads, 4 waves.
// ---------------------------------------------------------------------------
__device__ __forceinline__ int swz_idx(int row, int k) {
    return row * 256 + (((k >> 3) ^ (row & 7)) << 3) + (k & 7);
}

__global__ __launch_bounds__(256) void attn3_k(
    const __hip_bfloat16* __restrict__ qkv, __hip_bfloat16* __restrict__ o)
{
    __shared__ short V_t[64 * 256];
    __shared__ short P_s[4][16 * 256];
    const int half = blockIdx.x;
    const int bh = blockIdx.y;
    const int b = bh / VNH, h = bh % VNH;
    const int tid = threadIdx.x, w = tid >> 6, l = tid & 63;
    const int g = l >> 4, c16 = l & 15;

    const __hip_bfloat16* base = qkv + (size_t)(b * VS) * (3 * VD) + h * VDQ;

    {
        const __hip_bfloat16* vbase = base + 2 * VD;
        int t = tid & 31, e0 = (tid >> 5) * 8;
        #pragma unroll
        for (int it = 0; it < 7; it++) {
            int tt = it * 32 + t;
            if (tt < VS) {
                short8 vv = *(const short8*)(vbase + (size_t)tt * (3 * VD) + e0);
                #pragma unroll
                for (int j = 0; j < 8; j++) V_t[swz_idx(e0 + j, tt)] = vv[j];
            }
        }
        for (int idx = tid; idx < 64 * 27; idx += 256) {
            int e = idx / 27, k = 197 + idx % 27;
            V_t[swz_idx(e, k)] = 0;
        }
    }
    {
        unsigned* p0 = (unsigned*)&P_s[w][swz_idx(c16, 208 + g * 4)];
        p0[0] = 0; p0[1] = 0;
    }
    __syncthreads();

    const int qt_end = half ? 13 : 7;
    for (int qt = 7 * half + w; qt < qt_end; qt += 4) {
        const int q0 = qt * 16;
        int qr = min(q0 + c16, VS - 1);
        const __hip_bfloat16* qp = base + (size_t)qr * (3 * VD) + g * 8;
        short8 qa0 = *(const short8*)(qp);
        short8 qa1 = *(const short8*)(qp + 32);

        f32x4 st[13];
        __builtin_amdgcn_s_setprio(1);
        #pragma unroll
        for (int t = 0; t < 13; t++) {
            int kr = min(t * 16 + c16, VS - 1);
            const __hip_bfloat16* kp = base + VD + (size_t)kr * (3 * VD) + g * 8;
            short8 ka0 = *(const short8*)(kp);
            short8 ka1 = *(const short8*)(kp + 32);
            f32x4 z = {};
            z = __builtin_amdgcn_mfma_f32_16x16x32_bf16(ka0, qa0, z, 0, 0, 0);
            z = __builtin_amdgcn_mfma_f32_16x16x32_bf16(ka1, qa1, z, 0, 0, 0);
            st[t] = z;
        }
        __builtin_amdgcn_s_setprio(0);
        #pragma unroll
        for (int t = 0; t < 13; t++) {
            #pragma unroll
            for (int r = 0; r < 4; r++) {
                float v = st[t][r] * 0.125f;
                if (t == 12 && (4 * g + r) >= 5) v = -3.0e38f;
                st[t][r] = v;
            }
        }
        float m = -3.0e38f;
        #pragma unroll
        for (int t = 0; t < 13; t++)
            #pragma unroll
            for (int r = 0; r < 4; r++) m = fmaxf(m, st[t][r]);
        m = fmaxf(m, __shfl_xor(m, 16));
        m = fmaxf(m, __shfl_xor(m, 32));
        float sum = 0.f;
        #pragma unroll
        for (int t = 0; t < 13; t++)
            #pragma unroll
            for (int r = 0; r < 4; r++) { float e = expf(st[t][r] - m); st[t][r] = e; sum += e; }
        sum += __shfl_xor(sum, 16);
        sum += __shfl_xor(sum, 32);
        float inv = 1.f / sum;
        #pragma unroll
        for (int t = 0; t < 13; t++) {
            int k0 = 16 * t + 4 * g;
            unsigned* pp = (unsigned*)&P_s[w][swz_idx(c16, k0)];
            pp[0] = pack2bf(st[t][0] * inv, st[t][1] * inv);
            pp[1] = pack2bf(st[t][2] * inv, st[t][3] * inv);
        }
        f32x4 acc[4] = {};
        __builtin_amdgcn_s_setprio(1);
        #pragma unroll
        for (int ki = 0; ki < 7; ki++) {
            int k0 = ki * 32 + g * 8;
            short8 pa = *(const short8*)&P_s[w][swz_idx(c16, k0)];
            #pragma unroll
            for (int et = 0; et < 4; et++) {
                short8 vbf = *(const short8*)&V_t[swz_idx(et * 16 + c16, k0)];
                acc[et] = __builtin_amdgcn_mfma_f32_16x16x32_bf16(pa, vbf, acc[et], 0, 0, 0);
            }
        }
        __builtin_amdgcn_s_setprio(0);
        #pragma unroll
        for (int et = 0; et < 4; et++) {
            #pragma unroll
            for (int r = 0; r < 4; r++) {
                int q = q0 + 4 * g + r;
                if (q < VS)
                    o[((size_t)(b * VS) + q) * VD + h * VDQ + et * 16 + c16] =
                        __float2bfloat16(acc[et][r]);
            }
        }
    }
}

// ---------------------------------------------------------------------------
extern "C" void kernel_launch(void* const* d_in, const int* in_sizes, int n_in,
                              void* d_out, int out_size, void* d_ws, size_t ws_size,
                              hipStream_t stream) {
    (void)in_sizes; (void)n_in; (void)out_size; (void)ws_size;
    const float* X       = (const float*)d_in[0];
    const float* patch_W = (const float*)d_in[1];
    const float* patch_b = (const float*)d_in[2];
    const float* cls_tok = (const float*)d_in[3];
    const float* ln1_g   = (const float*)d_in[4];
    const float* ln1_b   = (const float*)d_in[5];
    const float* Wq      = (const float*)d_in[6];
    const float* bq      = (const float*)d_in[7];
    const float* Wk      = (const float*)d_in[8];
    const float* bk      = (const float*)d_in[9];
    const float* Wv      = (const float*)d_in[10];
    const float* bv      = (const float*)d_in[11];
    const float* proj_W  = (const float*)d_in[12];
    const float* proj_b  = (const float*)d_in[13];
    const float* ln2_g   = (const float*)d_in[14];
    const float* ln2_b   = (const float*)d_in[15];
    const float* mlp_W1  = (const float*)d_in[16];
    const float* mlp_b1  = (const float*)d_in[17];
    const float* mlp_W2  = (const float*)d_in[18];
    const float* mlp_b2  = (const float*)d_in[19];
    const float* head_W  = (const float*)d_in[20];
    const float* head_b  = (const float*)d_in[21];

    char* ws = (char*)d_ws;
    float*          x    = (float*)ws;                            // 19.37 MB fp32
    __hip_bfloat16* tb   = (__hip_bfloat16*)(ws + 19365888);      // 9.68 MB bf16
    __hip_bfloat16* big  = (__hip_bfloat16*)(ws + 29048832);      // 38.73 MB
    __hip_bfloat16* wT   = (__hip_bfloat16*)(ws + 67780608);      // 14.16 MB
    float*          cbA  = (float*)(ws + 81936384);               // 110 KB
    float*          pbuf = (float*)(ws + 82046976);               // 38.73 MB

    cball_k<<<(VL * 3 * VD + 255) / 256, 256, 0, stream>>>(bq, bk, bv, cbA);

    patchify_k<<<(VB * VNPAT * VP + 255) / 256, 256, 0, stream>>>(X, big);
    {
        dim3 g(VD / 32, VP / 32);
        tpose_k<<<g, 256, 0, stream>>>(patch_W, wT, VP, VD);
    }
    {
        dim3 g(VD / 128, VB * VNPAT / 128);
        bgemm_k<0><<<g, 256, 0, stream>>>(big, wT, patch_b, x, VB * VNPAT, VP, VD, VD);
    }
    pos_cls_k<<<(unsigned)((TOKD + 255) / 256), 256, 0, stream>>>(x, cls_tok);

    const size_t WSZ = (size_t)VNH * VD * VDQ;
    for (int l = 0; l < VL; l++) {
        wprep_k<<<6912, 256, 0, stream>>>(
            Wq + l * WSZ, Wk + l * WSZ, Wv + l * WSZ,
            proj_W + (size_t)l * VD * VD,
            mlp_W1 + (size_t)l * VD * VMLP,
            mlp_W2 + (size_t)l * VMLP * VD, wT);

        if (l == 0)
            layernorm_k<<<VTOK, 256, 0, stream>>>(x, tb, ln1_g, ln1_b);

        {
            // fused QKV GEMM: 256² 3-ring pipelined, grid 9 x 25
            dim3 g(3 * VD / 256, (VTOK + 255) / 256);
            bgemm8_k<1><<<g, 512, 0, stream>>>(tb, wT, cbA + l * 3 * VD, big,
                                               VTOK, VD, 3 * VD);
        }
        {
            dim3 ga(2, VB * VNH);
            attn3_k<<<ga, 256, 0, stream>>>(big, tb);
        }
        {
            dim3 g(VD / 128, (VTOK + 127) / 128, 2);
            bgemm5_k<<<g, 256, 0, stream>>>(tb, wT + OFF_PROJ, pbuf, VTOK, VD, VD);
            combineln_k<1><<<VTOK, 256, 0, stream>>>(
                x, pbuf, pbuf + TOKD, proj_b + l * VD,
                ln2_g + l * VD, ln2_b + l * VD, tb);
        }
        {
            // MLP1: 256² 3-ring pipelined + fast-GELU, grid 12 x 25
            dim3 g(VMLP / 256, (VTOK + 255) / 256);
            bgemm8_k<3><<<g, 512, 0, stream>>>(tb, wT + OFF_M1, mlp_b1 + l * VMLP, big,
                                               VTOK, VD, VMLP);
        }
        {
            dim3 g(VD / 128, (VTOK + 127) / 128, 2);
            bgemm5_k<<<g, 256, 0, stream>>>(big, wT + OFF_M2, pbuf, VTOK, VMLP, VD);
            if (l + 1 < VL)
                combineln_k<1><<<VTOK, 256, 0, stream>>>(
                    x, pbuf, pbuf + TOKD, mlp_b2 + l * VD,
                    ln1_g + (l + 1) * VD, ln1_b + (l + 1) * VD, tb);
            else
                combineln_k<0><<<VTOK, 256, 0, stream>>>(
                    x, pbuf, pbuf + TOKD, mlp_b2 + l * VD,
                    nullptr, nullptr, nullptr);
        }
    }
    cls_k<<<(VB * VD + 255) / 256, 256, 0, stream>>>(x, tb);
    {
        dim3 gt((VC + 31) / 32, VD / 32);
        tpose_k<<<gt, 256, 0, stream>>>(head_W, wT, VD, VC);
        dim3 g((VC + 127) / 128, 1);
        bgemm_k<4><<<g, 256, 0, stream>>>(tb, wT, head_b, (float*)d_out,
                                          VB, VD, VC, VC);
    }
}

// Round 11
// 3033.265 us; speedup vs baseline: 1.7316x; 1.0304x over previous
//
#include <hip/hip_runtime.h>
#include <hip/hip_bf16.h>
#include <math.h>
#include <stdint.h>

// ViT config
#define VB   32
#define VS   197
#define VD   768
#define VNH  12
#define VDQ  64
#define VL   12
#define VMLP 3072
#define VC   1000
#define VP   256
#define VNPAT 196
#define VTOK (VB * VS)            // 6304
#define TOKD ((size_t)VTOK * VD)  // 4841472 floats

typedef __attribute__((ext_vector_type(4))) float f32x4;
typedef __attribute__((ext_vector_type(8))) short short8;

typedef __attribute__((address_space(1))) const unsigned int GU;
typedef __attribute__((address_space(3))) unsigned int LU;

__device__ __forceinline__ void gload_lds16(const void* g, void* l) {
    __builtin_amdgcn_global_load_lds((GU*)(uintptr_t)g, (LU*)(uintptr_t)l, 16, 0, 0);
}

// T1: bijective XCD-aware block swizzle (m204).
__device__ __forceinline__ void xcd_swz(int gx, int gy, int& bx, int& by) {
    int nwg = gx * gy;
    int hw = by * gx + bx;
    int q = nwg >> 3, r = nwg & 7;
    int xcd = hw & 7, off = hw >> 3;
    int lid = (xcd < r ? xcd * (q + 1) : r * (q + 1) + (xcd - r) * q) + off;
    bx = lid % gx; by = lid / gx;
}

// Fast tanh-form GELU.
__device__ __forceinline__ float gelu_f(float x) {
    float t = 0.7978845608f * x * fmaf(0.044715f, x * x, 1.0f);
    float a = fminf(t * 2.8853900818f, 80.0f);
    float e = __builtin_amdgcn_exp2f(a);
    return x * e * __builtin_amdgcn_rcpf(1.0f + e);
}

// ---------------------------------------------------------------------------
__global__ void patchify_k(const float* __restrict__ X, __hip_bfloat16* __restrict__ P) {
    int idx = blockIdx.x * 256 + threadIdx.x;
    const int total = VB * VNPAT * VP;
    if (idx >= total) return;
    int i  = idx & 255;
    int p  = (idx >> 8) % VNPAT;
    int b  = (idx >> 8) / VNPAT;
    int pr = p / 14, pc = p % 14;
    int a  = i >> 4, c2 = i & 15;
    P[idx] = __float2bfloat16(X[((size_t)b * 224 + pr * 16 + a) * 224 + pc * 16 + c2]);
}

__global__ void pos_cls_k(float* __restrict__ x, const float* __restrict__ cls) {
    size_t idx = (size_t)blockIdx.x * 256 + threadIdx.x;
    if (idx >= TOKD) return;
    int j = (int)(idx % VD);
    int s = (int)((idx / VD) % VS);
    float jj = (float)(j & ~1);
    float freq = expf(-(jj / (float)VD) * 9.2103403719761836f);
    float ang  = (float)s * freq;
    float pe   = (j & 1) ? cosf(ang) : sinf(ang);
    if (s == 0) x[idx] = cls[j] + pe;
    else        x[idx] += pe;
}

__global__ __launch_bounds__(256) void layernorm_k(
    const float* __restrict__ x, __hip_bfloat16* __restrict__ y,
    const float* __restrict__ g, const float* __restrict__ bta)
{
    int t = blockIdx.x;
    const float* xr = x + (size_t)t * VD;
    __hip_bfloat16* yr = y + (size_t)t * VD;
    int tid = threadIdx.x;
    float v[3];
    float s = 0.f;
    #pragma unroll
    for (int i = 0; i < 3; i++) { v[i] = xr[tid + i * 256]; s += v[i]; }
    __shared__ float red[8];
    #pragma unroll
    for (int off = 32; off; off >>= 1) s += __shfl_xor(s, off);
    int lane = tid & 63, w = tid >> 6;
    if (!lane) red[w] = s;
    __syncthreads();
    float mu = (red[0] + red[1] + red[2] + red[3]) * (1.f / VD);
    float s2 = 0.f;
    #pragma unroll
    for (int i = 0; i < 3; i++) { float d0 = v[i] - mu; s2 += d0 * d0; }
    #pragma unroll
    for (int off = 32; off; off >>= 1) s2 += __shfl_xor(s2, off);
    if (!lane) red[4 + w] = s2;
    __syncthreads();
    float var = (red[4] + red[5] + red[6] + red[7]) * (1.f / VD);
    float rs = rsqrtf(var + 1e-5f);
    #pragma unroll
    for (int i = 0; i < 3; i++) {
        int j = tid + i * 256;
        yr[j] = __float2bfloat16((v[i] - mu) * rs * g[j] + bta[j]);
    }
}

template<int DO_LN>
__global__ __launch_bounds__(256) void combineln_k(
    float* __restrict__ x, const float* __restrict__ p0, const float* __restrict__ p1,
    const float* __restrict__ bias, const float* __restrict__ g,
    const float* __restrict__ bta, __hip_bfloat16* __restrict__ y)
{
    int t = blockIdx.x;
    size_t base = (size_t)t * VD;
    int tid = threadIdx.x;
    float v[3];
    float s = 0.f;
    #pragma unroll
    for (int i = 0; i < 3; i++) {
        int j = tid + i * 256;
        float val = x[base + j] + p0[base + j] + p1[base + j] + bias[j];
        x[base + j] = val;
        v[i] = val; s += val;
    }
    if (DO_LN) {
        __shared__ float red[8];
        #pragma unroll
        for (int off = 32; off; off >>= 1) s += __shfl_xor(s, off);
        int lane = tid & 63, w = tid >> 6;
        if (!lane) red[w] = s;
        __syncthreads();
        float mu = (red[0] + red[1] + red[2] + red[3]) * (1.f / VD);
        float s2 = 0.f;
        #pragma unroll
        for (int i = 0; i < 3; i++) { float d0 = v[i] - mu; s2 += d0 * d0; }
        #pragma unroll
        for (int off = 32; off; off >>= 1) s2 += __shfl_xor(s2, off);
        if (!lane) red[4 + w] = s2;
        __syncthreads();
        float var = (red[4] + red[5] + red[6] + red[7]) * (1.f / VD);
        float rs = rsqrtf(var + 1e-5f);
        #pragma unroll
        for (int i = 0; i < 3; i++) {
            int j = tid + i * 256;
            y[base + j] = __float2bfloat16((v[i] - mu) * rs * g[j] + bta[j]);
        }
    }
}

__global__ __launch_bounds__(256) void tpose_k(
    const float* __restrict__ in, __hip_bfloat16* __restrict__ out, int R, int C)
{
    __shared__ float t[32][33];
    int c0 = blockIdx.x * 32, r0 = blockIdx.y * 32;
    int tc = threadIdx.x & 31, tr = threadIdx.x >> 5;
    #pragma unroll
    for (int p = 0; p < 4; p++) {
        int r = r0 + tr + p * 8;
        t[tr + p * 8][tc] = (r < R && c0 + tc < C) ? in[(size_t)r * C + c0 + tc] : 0.f;
    }
    __syncthreads();
    #pragma unroll
    for (int p = 0; p < 4; p++) {
        int c = c0 + tr + p * 8;
        if (c < C && r0 + tc < R)
            out[(size_t)c * R + r0 + tc] = __float2bfloat16(t[tc][tr + p * 8]);
    }
}

#define OFF_PROJ (2304 * 768)
#define OFF_M1   (OFF_PROJ + 768 * 768)
#define OFF_M2   (OFF_M1 + 3072 * 768)

__device__ __forceinline__ unsigned pack2bf(float a, float b) {
    __hip_bfloat16 x = __float2bfloat16(a), y = __float2bfloat16(b);
    unsigned short ux = *(unsigned short*)&x, uy = *(unsigned short*)&y;
    return (unsigned)ux | ((unsigned)uy << 16);
}

__global__ __launch_bounds__(256) void wprep_k(
    const float* __restrict__ Wq, const float* __restrict__ Wk,
    const float* __restrict__ Wv, const float* __restrict__ Wp,
    const float* __restrict__ W1, const float* __restrict__ W2,
    __hip_bfloat16* __restrict__ wT)
{
    __shared__ float t[32][33];
    int z = blockIdx.x;
    const float* src; __hip_bfloat16* dst;
    int C, ldd, r0, c0;
    if (z < 1728) {
        int head = z / 48, tt = z % 48;
        int m = head / VNH, h = head % VNH;
        src = (m == 0 ? Wq : m == 1 ? Wk : Wv) + (size_t)h * VD * VDQ;
        dst = wT + ((size_t)m * VD + h * VDQ) * VD;
        C = VDQ; ldd = VD;
        r0 = (tt >> 1) * 32; c0 = (tt & 1) * 32;
    } else if (z < 2304) {
        int z2 = z - 1728;
        src = Wp; dst = wT + OFF_PROJ;
        C = VD; ldd = VD;
        r0 = (z2 / 24) * 32; c0 = (z2 % 24) * 32;
    } else if (z < 4608) {
        int z3 = z - 2304;
        src = W1; dst = wT + OFF_M1;
        C = VMLP; ldd = VD;
        r0 = (z3 / 96) * 32; c0 = (z3 % 96) * 32;
    } else {
        int z4 = z - 4608;
        src = W2; dst = wT + OFF_M2;
        C = VD; ldd = VMLP;
        r0 = (z4 / 24) * 32; c0 = (z4 % 24) * 32;
    }
    int tid = threadIdx.x;
    {
        int r = tid >> 3, cq = (tid & 7) << 2;
        float4 v = *(const float4*)&src[(size_t)(r0 + r) * C + c0 + cq];
        t[r][cq] = v.x; t[r][cq + 1] = v.y; t[r][cq + 2] = v.z; t[r][cq + 3] = v.w;
    }
    __syncthreads();
    {
        int c = tid >> 3, rq = (tid & 7) << 2;
        unsigned u0 = pack2bf(t[rq][c],     t[rq + 1][c]);
        unsigned u1 = pack2bf(t[rq + 2][c], t[rq + 3][c]);
        unsigned* dp = (unsigned*)&dst[(size_t)(c0 + c) * ldd + r0 + rq];
        dp[0] = u0; dp[1] = u1;
    }
}

__global__ void cball_k(const float* __restrict__ bq, const float* __restrict__ bk,
                        const float* __restrict__ bv, float* __restrict__ cb) {
    int idx = blockIdx.x * 256 + threadIdx.x;
    if (idx >= VL * 3 * VD) return;
    int l = idx / (3 * VD), n = idx % (3 * VD);
    int m = n / VD, wi = n % VD;
    const float* p = (m == 0) ? bq : (m == 1) ? bk : bv;
    cb[idx] = p[l * VD + wi];
}

__global__ void cls_k(const float* __restrict__ x, __hip_bfloat16* __restrict__ out) {
    int idx = blockIdx.x * 256 + threadIdx.x;
    if (idx >= VB * VD) return;
    int b = idx / VD, d = idx % VD;
    out[idx] = __float2bfloat16(x[(size_t)b * VS * VD + d]);
}

// ---------------------------------------------------------------------------
// bf16 MFMA GEMM (m97-style 128x128) + XCD swizzle — patch/head (+ spares).
// ---------------------------------------------------------------------------
template<int EPI>
__global__ __launch_bounds__(256) void bgemm_k(
    const __hip_bfloat16* __restrict__ A,
    const __hip_bfloat16* __restrict__ BT,
    const float* __restrict__ bias,
    void* __restrict__ Co,
    int M, int K, int ldc, int Ncols)
{
    __shared__ short A_s[128][64];
    __shared__ short B_s[128][64];
    int bx = blockIdx.x, by = blockIdx.y;
    xcd_swz(gridDim.x, gridDim.y, bx, by);
    const int tid = threadIdx.x;
    const int w = tid >> 6, l = tid & 63;
    const int row0 = by * 128, col0 = bx * 128;
    const int wm = (w >> 1) << 6, wn = (w & 1) << 6;
    f32x4 acc[4][4] = {};

    const int lr = l >> 3;
    const int sslot = (l & 7) ^ lr;
    int arow[4], brow[4];
    #pragma unroll
    for (int i = 0; i < 4; i++) {
        int r = (4 * w + i) * 8 + lr;
        arow[i] = min(row0 + r, M - 1);
        brow[i] = min(col0 + r, Ncols - 1);
    }
    for (int k0 = 0; k0 < K; k0 += 64) {
        __syncthreads();
        #pragma unroll
        for (int i = 0; i < 4; i++) {
            int ch = 4 * w + i;
            gload_lds16((const void*)(A + (size_t)arow[i] * K + k0 + (sslot << 3)),
                        (void*)(&A_s[ch * 8][0]));
            gload_lds16((const void*)(BT + (size_t)brow[i] * K + k0 + (sslot << 3)),
                        (void*)(&B_s[ch * 8][0]));
        }
        __syncthreads();
        #pragma unroll
        for (int ks = 0; ks < 2; ks++) {
            const int s16 = (ks << 2) + (l >> 4);
            short8 av[4], bv[4];
            #pragma unroll
            for (int i = 0; i < 4; i++) {
                int ar = wm + i * 16 + (l & 15);
                av[i] = *(const short8*)((const char*)&A_s[ar][0] + ((s16 ^ (ar & 7)) << 4));
                int br = wn + i * 16 + (l & 15);
                bv[i] = *(const short8*)((const char*)&B_s[br][0] + ((s16 ^ (br & 7)) << 4));
            }
            #pragma unroll
            for (int i = 0; i < 4; i++)
                #pragma unroll
                for (int j = 0; j < 4; j++)
                    acc[i][j] = __builtin_amdgcn_mfma_f32_16x16x32_bf16(av[i], bv[j], acc[i][j], 0, 0, 0);
        }
    }
    const int rbase = row0 + wm + ((l >> 4) << 2);
    const int cbase = col0 + wn + (l & 15);
    #pragma unroll
    for (int i = 0; i < 4; i++) {
        #pragma unroll
        for (int q = 0; q < 4; q++) {
            int rr = rbase + i * 16 + q;
            if (rr >= M) continue;
            #pragma unroll
            for (int j = 0; j < 4; j++) {
                int c = cbase + j * 16;
                if (c >= Ncols) continue;
                float v = acc[i][j][q] + bias[c];
                if (EPI == 0) {
                    int orow = rr + rr / VNPAT + 1;
                    ((float*)Co)[(size_t)orow * ldc + c] = v;
                } else if (EPI == 1) {
                    ((__hip_bfloat16*)Co)[(size_t)rr * ldc + c] = __float2bfloat16(v);
                } else if (EPI == 2) {
                    ((float*)Co)[(size_t)rr * ldc + c] += v;
                } else if (EPI == 3) {
                    ((__hip_bfloat16*)Co)[(size_t)rr * ldc + c] = __float2bfloat16(gelu_f(v));
                } else {
                    ((float*)Co)[(size_t)rr * ldc + c] = v;
                }
            }
        }
    }
}

// ---------------------------------------------------------------------------
// bgemm8_k (LEAN): 256x256 tile, 512 threads (8 waves, 2M x 4N, per-wave
// 128x64), BK=32 K-tiles in a 3-slot LDS ring (96 KB).
// ONE barrier per K-tile (the boundary publish), counted vmcnt(4).
// Ledger:
//  - slot publish: at boundary each wave waits vmcnt(4) (own tile-t+1 loads
//    landed; tile-t+2's 4 may pend) THEN s_barrier -> all waves' tile-t+1
//    data visible before any wave reads it in iter t+1.
//  - overwrite: iter t+1's STG writes slot t%3; tile t's reads completed
//    (lgkmcnt 0 precedes MFMA precedes boundary) before the boundary barrier
//    every wave crossed; STG issues after it.
//  - own-reads -> MFMA ordering: lgkmcnt(0) + sched_barrier(0) (rule #18).
// Requires N mult of 256, K mult of 32, K/32 >= 3. M clamped.
// EPI: 1 = bf16 store; 3 = fast-GELU -> bf16 store.
// ---------------------------------------------------------------------------
template<int EPI>
__global__ __launch_bounds__(512) void bgemm8_k(
    const __hip_bfloat16* __restrict__ A,
    const __hip_bfloat16* __restrict__ BT,
    const float* __restrict__ bias,
    __hip_bfloat16* __restrict__ Co,
    int M, int K, int ldc)
{
    __shared__ short SA[3][256][32];
    __shared__ short SB[3][256][32];
    const int tid = threadIdx.x;
    const int w = tid >> 6, l = tid & 63;
    const int fr = l & 15, g = l >> 4;
    const int wr = w >> 2, wc = w & 3;
    const int row0 = blockIdx.y * 256, col0 = blockIdx.x * 256;
    f32x4 acc[8][4] = {};

    const int sr = tid >> 2;
    const int sslot = (tid & 3) ^ ((sr >> 1) & 3);
    const __hip_bfloat16* aS[2]; const __hip_bfloat16* bS[2];
    #pragma unroll
    for (int u = 0; u < 2; u++) {
        aS[u] = A  + (size_t)min(row0 + u * 128 + sr, M - 1) * K + sslot * 8;
        bS[u] = BT + (size_t)(col0 + u * 128 + sr) * K + sslot * 8;
    }
    const int doff = sr * 64 + (tid & 3) * 16;

    #define STG_A(ring, t) { const int k0 = (t) << 5;                          \
        gload_lds16(aS[0] + k0, (char*)&SA[ring][0][0] + doff);                \
        gload_lds16(aS[1] + k0, (char*)&SA[ring][0][0] + 8192 + doff); }
    #define STG_B(ring, t) { const int k0 = (t) << 5;                          \
        gload_lds16(bS[0] + k0, (char*)&SB[ring][0][0] + doff);                \
        gload_lds16(bS[1] + k0, (char*)&SB[ring][0][0] + 8192 + doff); }

    const int nt = K >> 5;
    STG_A(0, 0); STG_B(0, 0);
    STG_A(1, 1); STG_B(1, 1);
    asm volatile("s_waitcnt vmcnt(4)" ::: "memory");
    __builtin_amdgcn_s_barrier();

    short8 breg[4];
    for (int t = 0; t < nt; t++) {
        const int ring = t % 3;
        const int rs   = (t + 2) % 3;
        const char* sa = (const char*)&SA[ring][0][0];
        const char* sb = (const char*)&SB[ring][0][0];
        short8 areg[4];
        // ---- phase 0: B-frags + A-frags 0..3; stage A of tile t+2 ----
        #pragma unroll
        for (int n = 0; n < 4; n++) {
            int br = wc * 64 + n * 16 + fr;
            breg[n] = *(const short8*)(sb + br * 64 + ((g ^ ((br >> 1) & 3)) << 4));
        }
        #pragma unroll
        for (int m = 0; m < 4; m++) {
            int ar = wr * 128 + m * 16 + fr;
            areg[m] = *(const short8*)(sa + ar * 64 + ((g ^ ((ar >> 1) & 3)) << 4));
        }
        if (t + 2 < nt) STG_A(rs, t + 2);
        asm volatile("s_waitcnt lgkmcnt(0)" ::: "memory");
        __builtin_amdgcn_sched_barrier(0);
        __builtin_amdgcn_s_setprio(1);
        #pragma unroll
        for (int m = 0; m < 4; m++)
            #pragma unroll
            for (int n = 0; n < 4; n++)
                acc[m][n] = __builtin_amdgcn_mfma_f32_16x16x32_bf16(areg[m], breg[n], acc[m][n], 0, 0, 0);
        __builtin_amdgcn_s_setprio(0);
        // ---- phase 1: A-frags 4..7 (reuse breg); stage B of tile t+2 ----
        #pragma unroll
        for (int m = 0; m < 4; m++) {
            int ar = wr * 128 + (m + 4) * 16 + fr;
            areg[m] = *(const short8*)(sa + ar * 64 + ((g ^ ((ar >> 1) & 3)) << 4));
        }
        if (t + 2 < nt) STG_B(rs, t + 2);
        asm volatile("s_waitcnt lgkmcnt(0)" ::: "memory");
        __builtin_amdgcn_sched_barrier(0);
        __builtin_amdgcn_s_setprio(1);
        #pragma unroll
        for (int m = 0; m < 4; m++)
            #pragma unroll
            for (int n = 0; n < 4; n++)
                acc[m + 4][n] = __builtin_amdgcn_mfma_f32_16x16x32_bf16(areg[m], breg[n], acc[m + 4][n], 0, 0, 0);
        __builtin_amdgcn_s_setprio(0);
        // ---- K-tile boundary: counted wait THEN publish barrier ----
        if (t + 2 < nt) {
            asm volatile("s_waitcnt vmcnt(4)" ::: "memory");
            __builtin_amdgcn_s_barrier();
        } else if (t + 1 < nt) {
            asm volatile("s_waitcnt vmcnt(0)" ::: "memory");
            __builtin_amdgcn_s_barrier();
        }
    }
    #undef STG_A
    #undef STG_B

    const int rb = row0 + wr * 128 + (g << 2);
    const int cb = col0 + wc * 64 + fr;
    #pragma unroll
    for (int m = 0; m < 8; m++) {
        #pragma unroll
        for (int q = 0; q < 4; q++) {
            int rr = rb + m * 16 + q;
            if (rr >= M) continue;
            #pragma unroll
            for (int n = 0; n < 4; n++) {
                int c = cb + n * 16;
                float v = acc[m][n][q] + bias[c];
                if (EPI == 3) v = gelu_f(v);
                Co[(size_t)rr * ldc + c] = __float2bfloat16(v);
            }
        }
    }
}

// ---------------------------------------------------------------------------
// Split-K=2 partial GEMM (proj / MLP2).
// ---------------------------------------------------------------------------
__global__ __launch_bounds__(256) void bgemm5_k(
    const __hip_bfloat16* __restrict__ A,
    const __hip_bfloat16* __restrict__ BT,
    float* __restrict__ P,
    int M, int K, int ldc)
{
    __shared__ short A_s[128][64];
    __shared__ short B_s[128][64];
    int bx = blockIdx.x, by = blockIdx.y;
    xcd_swz(gridDim.x, gridDim.y, bx, by);
    const int ks = blockIdx.z;
    const int khalf = K >> 1;
    const __hip_bfloat16* Ab  = A  + (size_t)ks * khalf;
    const __hip_bfloat16* BTb = BT + (size_t)ks * khalf;
    float* Pb = P + (size_t)ks * TOKD;

    const int tid = threadIdx.x;
    const int w = tid >> 6, l = tid & 63;
    const int row0 = by * 128, col0 = bx * 128;
    const int wm = (w >> 1) << 6, wn = (w & 1) << 6;
    f32x4 acc[4][4] = {};

    const int lr = l >> 3;
    const int sslot = (l & 7) ^ lr;
    int arow[4], brow[4];
    #pragma unroll
    for (int i = 0; i < 4; i++) {
        int r = (4 * w + i) * 8 + lr;
        arow[i] = min(row0 + r, M - 1);
        brow[i] = col0 + r;
    }
    for (int k0 = 0; k0 < khalf; k0 += 64) {
        __syncthreads();
        #pragma unroll
        for (int i = 0; i < 4; i++) {
            int ch = 4 * w + i;
            gload_lds16((const void*)(Ab + (size_t)arow[i] * K + k0 + (sslot << 3)),
                        (void*)(&A_s[ch * 8][0]));
            gload_lds16((const void*)(BTb + (size_t)brow[i] * K + k0 + (sslot << 3)),
                        (void*)(&B_s[ch * 8][0]));
        }
        __syncthreads();
        #pragma unroll
        for (int ks2 = 0; ks2 < 2; ks2++) {
            const int s16 = (ks2 << 2) + (l >> 4);
            short8 av[4], bv[4];
            #pragma unroll
            for (int i = 0; i < 4; i++) {
                int ar = wm + i * 16 + (l & 15);
                av[i] = *(const short8*)((const char*)&A_s[ar][0] + ((s16 ^ (ar & 7)) << 4));
                int br = wn + i * 16 + (l & 15);
                bv[i] = *(const short8*)((const char*)&B_s[br][0] + ((s16 ^ (br & 7)) << 4));
            }
            #pragma unroll
            for (int i = 0; i < 4; i++)
                #pragma unroll
                for (int j = 0; j < 4; j++)
                    acc[i][j] = __builtin_amdgcn_mfma_f32_16x16x32_bf16(av[i], bv[j], acc[i][j], 0, 0, 0);
        }
    }
    const int rbase = row0 + wm + ((l >> 4) << 2);
    const int cbase = col0 + wn + (l & 15);
    #pragma unroll
    for (int i = 0; i < 4; i++) {
        #pragma unroll
        for (int q = 0; q < 4; q++) {
            int rr = rbase + i * 16 + q;
            if (rr >= M) continue;
            #pragma unroll
            for (int j = 0; j < 4; j++) {
                int c = cbase + j * 16;
                Pb[(size_t)rr * ldc + c] = acc[i][j][q];
            }
        }
    }
}

// ---------------------------------------------------------------------------
// MFMA attention. Two blocks per (b,h), 256 threads, 4 waves.
// ---------------------------------------------------------------------------
__device__ __forceinline__ int swz_idx(int row, int k) {
    return row * 256 + (((k >> 3) ^ (row & 7)) << 3) + (k & 7);
}

__global__ __launch_bounds__(256) void attn3_k(
    const __hip_bfloat16* __restrict__ qkv, __hip_bfloat16* __restrict__ o)
{
    __shared__ short V_t[64 * 256];
    __shared__ short P_s[4][16 * 256];
    const int half = blockIdx.x;
    const int bh = blockIdx.y;
    const int b = bh / VNH, h = bh % VNH;
    const int tid = threadIdx.x, w = tid >> 6, l = tid & 63;
    const int g = l >> 4, c16 = l & 15;

    const __hip_bfloat16* base = qkv + (size_t)(b * VS) * (3 * VD) + h * VDQ;

    {
        const __hip_bfloat16* vbase = base + 2 * VD;
        int t = tid & 31, e0 = (tid >> 5) * 8;
        #pragma unroll
        for (int it = 0; it < 7; it++) {
            int tt = it * 32 + t;
            if (tt < VS) {
                short8 vv = *(const short8*)(vbase + (size_t)tt * (3 * VD) + e0);
                #pragma unroll
                for (int j = 0; j < 8; j++) V_t[swz_idx(e0 + j, tt)] = vv[j];
            }
        }
        for (int idx = tid; idx < 64 * 27; idx += 256) {
            int e = idx / 27, k = 197 + idx % 27;
            V_t[swz_idx(e, k)] = 0;
        }
    }
    {
        unsigned* p0 = (unsigned*)&P_s[w][swz_idx(c16, 208 + g * 4)];
        p0[0] = 0; p0[1] = 0;
    }
    __syncthreads();

    const int qt_end = half ? 13 : 7;
    for (int qt = 7 * half + w; qt < qt_end; qt += 4) {
        const int q0 = qt * 16;
        int qr = min(q0 + c16, VS - 1);
        const __hip_bfloat16* qp = base + (size_t)qr * (3 * VD) + g * 8;
        short8 qa0 = *(const short8*)(qp);
        short8 qa1 = *(const short8*)(qp + 32);

        f32x4 st[13];
        __builtin_amdgcn_s_setprio(1);
        #pragma unroll
        for (int t = 0; t < 13; t++) {
            int kr = min(t * 16 + c16, VS - 1);
            const __hip_bfloat16* kp = base + VD + (size_t)kr * (3 * VD) + g * 8;
            short8 ka0 = *(const short8*)(kp);
            short8 ka1 = *(const short8*)(kp + 32);
            f32x4 z = {};
            z = __builtin_amdgcn_mfma_f32_16x16x32_bf16(ka0, qa0, z, 0, 0, 0);
            z = __builtin_amdgcn_mfma_f32_16x16x32_bf16(ka1, qa1, z, 0, 0, 0);
            st[t] = z;
        }
        __builtin_amdgcn_s_setprio(0);
        #pragma unroll
        for (int t = 0; t < 13; t++) {
            #pragma unroll
            for (int r = 0; r < 4; r++) {
                float v = st[t][r] * 0.125f;
                if (t == 12 && (4 * g + r) >= 5) v = -3.0e38f;
                st[t][r] = v;
            }
        }
        float m = -3.0e38f;
        #pragma unroll
        for (int t = 0; t < 13; t++)
            #pragma unroll
            for (int r = 0; r < 4; r++) m = fmaxf(m, st[t][r]);
        m = fmaxf(m, __shfl_xor(m, 16));
        m = fmaxf(m, __shfl_xor(m, 32));
        float sum = 0.f;
        #pragma unroll
        for (int t = 0; t < 13; t++)
            #pragma unroll
            for (int r = 0; r < 4; r++) { float e = expf(st[t][r] - m); st[t][r] = e; sum += e; }
        sum += __shfl_xor(sum, 16);
        sum += __shfl_xor(sum, 32);
        float inv = 1.f / sum;
        #pragma unroll
        for (int t = 0; t < 13; t++) {
            int k0 = 16 * t + 4 * g;
            unsigned* pp = (unsigned*)&P_s[w][swz_idx(c16, k0)];
            pp[0] = pack2bf(st[t][0] * inv, st[t][1] * inv);
            pp[1] = pack2bf(st[t][2] * inv, st[t][3] * inv);
        }
        f32x4 acc[4] = {};
        __builtin_amdgcn_s_setprio(1);
        #pragma unroll
        for (int ki = 0; ki < 7; ki++) {
            int k0 = ki * 32 + g * 8;
            short8 pa = *(const short8*)&P_s[w][swz_idx(c16, k0)];
            #pragma unroll
            for (int et = 0; et < 4; et++) {
                short8 vbf = *(const short8*)&V_t[swz_idx(et * 16 + c16, k0)];
                acc[et] = __builtin_amdgcn_mfma_f32_16x16x32_bf16(pa, vbf, acc[et], 0, 0, 0);
            }
        }
        __builtin_amdgcn_s_setprio(0);
        #pragma unroll
        for (int et = 0; et < 4; et++) {
            #pragma unroll
            for (int r = 0; r < 4; r++) {
                int q = q0 + 4 * g + r;
                if (q < VS)
                    o[((size_t)(b * VS) + q) * VD + h * VDQ + et * 16 + c16] =
                        __float2bfloat16(acc[et][r]);
            }
        }
    }
}

// ---------------------------------------------------------------------------
extern "C" void kernel_launch(void* const* d_in, const int* in_sizes, int n_in,
                              void* d_out, int out_size, void* d_ws, size_t ws_size,
                              hipStream_t stream) {
    (void)in_sizes; (void)n_in; (void)out_size; (void)ws_size;
    const float* X       = (const float*)d_in[0];
    const float* patch_W = (const float*)d_in[1];
    const float* patch_b = (const float*)d_in[2];
    const float* cls_tok = (const float*)d_in[3];
    const float* ln1_g   = (const float*)d_in[4];
    const float* ln1_b   = (const float*)d_in[5];
    const float* Wq      = (const float*)d_in[6];
    const float* bq      = (const float*)d_in[7];
    const float* Wk      = (const float*)d_in[8];
    const float* bk      = (const float*)d_in[9];
    const float* Wv      = (const float*)d_in[10];
    const float* bv      = (const float*)d_in[11];
    const float* proj_W  = (const float*)d_in[12];
    const float* proj_b  = (const float*)d_in[13];
    const float* ln2_g   = (const float*)d_in[14];
    const float* ln2_b   = (const float*)d_in[15];
    const float* mlp_W1  = (const float*)d_in[16];
    const float* mlp_b1  = (const float*)d_in[17];
    const float* mlp_W2  = (const float*)d_in[18];
    const float* mlp_b2  = (const float*)d_in[19];
    const float* head_W  = (const float*)d_in[20];
    const float* head_b  = (const float*)d_in[21];

    char* ws = (char*)d_ws;
    float*          x    = (float*)ws;                            // 19.37 MB fp32
    __hip_bfloat16* tb   = (__hip_bfloat16*)(ws + 19365888);      // 9.68 MB bf16
    __hip_bfloat16* big  = (__hip_bfloat16*)(ws + 29048832);      // 38.73 MB
    __hip_bfloat16* wT   = (__hip_bfloat16*)(ws + 67780608);      // 14.16 MB
    float*          cbA  = (float*)(ws + 81936384);               // 110 KB
    float*          pbuf = (float*)(ws + 82046976);               // 38.73 MB

    cball_k<<<(VL * 3 * VD + 255) / 256, 256, 0, stream>>>(bq, bk, bv, cbA);

    patchify_k<<<(VB * VNPAT * VP + 255) / 256, 256, 0, stream>>>(X, big);
    {
        dim3 g(VD / 32, VP / 32);
        tpose_k<<<g, 256, 0, stream>>>(patch_W, wT, VP, VD);
    }
    {
        dim3 g(VD / 128, VB * VNPAT / 128);
        bgemm_k<0><<<g, 256, 0, stream>>>(big, wT, patch_b, x, VB * VNPAT, VP, VD, VD);
    }
    pos_cls_k<<<(unsigned)((TOKD + 255) / 256), 256, 0, stream>>>(x, cls_tok);

    const size_t WSZ = (size_t)VNH * VD * VDQ;
    for (int l = 0; l < VL; l++) {
        wprep_k<<<6912, 256, 0, stream>>>(
            Wq + l * WSZ, Wk + l * WSZ, Wv + l * WSZ,
            proj_W + (size_t)l * VD * VD,
            mlp_W1 + (size_t)l * VD * VMLP,
            mlp_W2 + (size_t)l * VMLP * VD, wT);

        if (l == 0)
            layernorm_k<<<VTOK, 256, 0, stream>>>(x, tb, ln1_g, ln1_b);

        {
            // fused QKV GEMM: lean 256² 3-ring, grid 9 x 25
            dim3 g(3 * VD / 256, (VTOK + 255) / 256);
            bgemm8_k<1><<<g, 512, 0, stream>>>(tb, wT, cbA + l * 3 * VD, big,
                                               VTOK, VD, 3 * VD);
        }
        {
            dim3 ga(2, VB * VNH);
            attn3_k<<<ga, 256, 0, stream>>>(big, tb);
        }
        {
            dim3 g(VD / 128, (VTOK + 127) / 128, 2);
            bgemm5_k<<<g, 256, 0, stream>>>(tb, wT + OFF_PROJ, pbuf, VTOK, VD, VD);
            combineln_k<1><<<VTOK, 256, 0, stream>>>(
                x, pbuf, pbuf + TOKD, proj_b + l * VD,
                ln2_g + l * VD, ln2_b + l * VD, tb);
        }
        {
            // MLP1: lean 256² 3-ring + fast-GELU, grid 12 x 25
            dim3 g(VMLP / 256, (VTOK + 255) / 256);
            bgemm8_k<3><<<g, 512, 0, stream>>>(tb, wT + OFF_M1, mlp_b1 + l * VMLP, big,
                                               VTOK, VD, VMLP);
        }
        {
            dim3 g(VD / 128, (VTOK + 127) / 128, 2);
            bgemm5_k<<<g, 256, 0, stream>>>(big, wT + OFF_M2, pbuf, VTOK, VMLP, VD);
            if (l + 1 < VL)
                combineln_k<1><<<VTOK, 256, 0, stream>>>(
                    x, pbuf, pbuf + TOKD, mlp_b2 + l * VD,
                    ln1_g + (l + 1) * VD, ln1_b + (l + 1) * VD, tb);
            else
                combineln_k<0><<<VTOK, 256, 0, stream>>>(
                    x, pbuf, pbuf + TOKD, mlp_b2 + l * VD,
                    nullptr, nullptr, nullptr);
        }
    }
    cls_k<<<(VB * VD + 255) / 256, 256, 0, stream>>>(x, tb);
    {
        dim3 gt((VC + 31) / 32, VD / 32);
        tpose_k<<<gt, 256, 0, stream>>>(head_W, wT, VD, VC);
        dim3 g((VC + 127) / 128, 1);
        bgemm_k<4><<<g, 256, 0, stream>>>(tb, wT, head_b, (float*)d_out,
                                          VB, VD, VC, VC);
    }
}

// Round 12
// 2797.039 us; speedup vs baseline: 1.8779x; 1.0845x over previous
//
#include <hip/hip_runtime.h>
#include <hip/hip_bf16.h>
#include <math.h>
#include <stdint.h>

// ViT config
#define VB   32
#define VS   197
#define VD   768
#define VNH  12
#define VDQ  64
#define VL   12
#define VMLP 3072
#define VC   1000
#define VP   256
#define VNPAT 196
#define VTOK (VB * VS)            // 6304
#define TOKD ((size_t)VTOK * VD)  // 4841472 floats

typedef __attribute__((ext_vector_type(4))) float f32x4;
typedef __attribute__((ext_vector_type(8))) short short8;

typedef __attribute__((address_space(1))) const unsigned int GU;
typedef __attribute__((address_space(3))) unsigned int LU;

__device__ __forceinline__ void gload_lds16(const void* g, void* l) {
    __builtin_amdgcn_global_load_lds((GU*)(uintptr_t)g, (LU*)(uintptr_t)l, 16, 0, 0);
}

// T1: bijective XCD-aware block swizzle (m204).
__device__ __forceinline__ void xcd_swz(int gx, int gy, int& bx, int& by) {
    int nwg = gx * gy;
    int hw = by * gx + bx;
    int q = nwg >> 3, r = nwg & 7;
    int xcd = hw & 7, off = hw >> 3;
    int lid = (xcd < r ? xcd * (q + 1) : r * (q + 1) + (xcd - r) * q) + off;
    bx = lid % gx; by = lid / gx;
}

// Fast tanh-form GELU.
__device__ __forceinline__ float gelu_f(float x) {
    float t = 0.7978845608f * x * fmaf(0.044715f, x * x, 1.0f);
    float a = fminf(t * 2.8853900818f, 80.0f);
    float e = __builtin_amdgcn_exp2f(a);
    return x * e * __builtin_amdgcn_rcpf(1.0f + e);
}

// ---------------------------------------------------------------------------
__global__ void patchify_k(const float* __restrict__ X, __hip_bfloat16* __restrict__ P) {
    int idx = blockIdx.x * 256 + threadIdx.x;
    const int total = VB * VNPAT * VP;
    if (idx >= total) return;
    int i  = idx & 255;
    int p  = (idx >> 8) % VNPAT;
    int b  = (idx >> 8) / VNPAT;
    int pr = p / 14, pc = p % 14;
    int a  = i >> 4, c2 = i & 15;
    P[idx] = __float2bfloat16(X[((size_t)b * 224 + pr * 16 + a) * 224 + pc * 16 + c2]);
}

__global__ void pos_cls_k(float* __restrict__ x, const float* __restrict__ cls) {
    size_t idx = (size_t)blockIdx.x * 256 + threadIdx.x;
    if (idx >= TOKD) return;
    int j = (int)(idx % VD);
    int s = (int)((idx / VD) % VS);
    float jj = (float)(j & ~1);
    float freq = expf(-(jj / (float)VD) * 9.2103403719761836f);
    float ang  = (float)s * freq;
    float pe   = (j & 1) ? cosf(ang) : sinf(ang);
    if (s == 0) x[idx] = cls[j] + pe;
    else        x[idx] += pe;
}

__global__ __launch_bounds__(256) void layernorm_k(
    const float* __restrict__ x, __hip_bfloat16* __restrict__ y,
    const float* __restrict__ g, const float* __restrict__ bta)
{
    int t = blockIdx.x;
    const float* xr = x + (size_t)t * VD;
    __hip_bfloat16* yr = y + (size_t)t * VD;
    int tid = threadIdx.x;
    float v[3];
    float s = 0.f;
    #pragma unroll
    for (int i = 0; i < 3; i++) { v[i] = xr[tid + i * 256]; s += v[i]; }
    __shared__ float red[8];
    #pragma unroll
    for (int off = 32; off; off >>= 1) s += __shfl_xor(s, off);
    int lane = tid & 63, w = tid >> 6;
    if (!lane) red[w] = s;
    __syncthreads();
    float mu = (red[0] + red[1] + red[2] + red[3]) * (1.f / VD);
    float s2 = 0.f;
    #pragma unroll
    for (int i = 0; i < 3; i++) { float d0 = v[i] - mu; s2 += d0 * d0; }
    #pragma unroll
    for (int off = 32; off; off >>= 1) s2 += __shfl_xor(s2, off);
    if (!lane) red[4 + w] = s2;
    __syncthreads();
    float var = (red[4] + red[5] + red[6] + red[7]) * (1.f / VD);
    float rs = rsqrtf(var + 1e-5f);
    #pragma unroll
    for (int i = 0; i < 3; i++) {
        int j = tid + i * 256;
        yr[j] = __float2bfloat16((v[i] - mu) * rs * g[j] + bta[j]);
    }
}

template<int DO_LN>
__global__ __launch_bounds__(256) void combineln_k(
    float* __restrict__ x, const float* __restrict__ p0, const float* __restrict__ p1,
    const float* __restrict__ bias, const float* __restrict__ g,
    const float* __restrict__ bta, __hip_bfloat16* __restrict__ y)
{
    int t = blockIdx.x;
    size_t base = (size_t)t * VD;
    int tid = threadIdx.x;
    float v[3];
    float s = 0.f;
    #pragma unroll
    for (int i = 0; i < 3; i++) {
        int j = tid + i * 256;
        float val = x[base + j] + p0[base + j] + p1[base + j] + bias[j];
        x[base + j] = val;
        v[i] = val; s += val;
    }
    if (DO_LN) {
        __shared__ float red[8];
        #pragma unroll
        for (int off = 32; off; off >>= 1) s += __shfl_xor(s, off);
        int lane = tid & 63, w = tid >> 6;
        if (!lane) red[w] = s;
        __syncthreads();
        float mu = (red[0] + red[1] + red[2] + red[3]) * (1.f / VD);
        float s2 = 0.f;
        #pragma unroll
        for (int i = 0; i < 3; i++) { float d0 = v[i] - mu; s2 += d0 * d0; }
        #pragma unroll
        for (int off = 32; off; off >>= 1) s2 += __shfl_xor(s2, off);
        if (!lane) red[4 + w] = s2;
        __syncthreads();
        float var = (red[4] + red[5] + red[6] + red[7]) * (1.f / VD);
        float rs = rsqrtf(var + 1e-5f);
        #pragma unroll
        for (int i = 0; i < 3; i++) {
            int j = tid + i * 256;
            y[base + j] = __float2bfloat16((v[i] - mu) * rs * g[j] + bta[j]);
        }
    }
}

__global__ __launch_bounds__(256) void tpose_k(
    const float* __restrict__ in, __hip_bfloat16* __restrict__ out, int R, int C)
{
    __shared__ float t[32][33];
    int c0 = blockIdx.x * 32, r0 = blockIdx.y * 32;
    int tc = threadIdx.x & 31, tr = threadIdx.x >> 5;
    #pragma unroll
    for (int p = 0; p < 4; p++) {
        int r = r0 + tr + p * 8;
        t[tr + p * 8][tc] = (r < R && c0 + tc < C) ? in[(size_t)r * C + c0 + tc] : 0.f;
    }
    __syncthreads();
    #pragma unroll
    for (int p = 0; p < 4; p++) {
        int c = c0 + tr + p * 8;
        if (c < C && r0 + tc < R)
            out[(size_t)c * R + r0 + tc] = __float2bfloat16(t[tc][tr + p * 8]);
    }
}

#define OFF_PROJ (2304 * 768)
#define OFF_M1   (OFF_PROJ + 768 * 768)
#define OFF_M2   (OFF_M1 + 3072 * 768)

__device__ __forceinline__ unsigned pack2bf(float a, float b) {
    __hip_bfloat16 x = __float2bfloat16(a), y = __float2bfloat16(b);
    unsigned short ux = *(unsigned short*)&x, uy = *(unsigned short*)&y;
    return (unsigned)ux | ((unsigned)uy << 16);
}

__global__ __launch_bounds__(256) void wprep_k(
    const float* __restrict__ Wq, const float* __restrict__ Wk,
    const float* __restrict__ Wv, const float* __restrict__ Wp,
    const float* __restrict__ W1, const float* __restrict__ W2,
    __hip_bfloat16* __restrict__ wT)
{
    __shared__ float t[32][33];
    int z = blockIdx.x;
    const float* src; __hip_bfloat16* dst;
    int C, ldd, r0, c0;
    if (z < 1728) {
        int head = z / 48, tt = z % 48;
        int m = head / VNH, h = head % VNH;
        src = (m == 0 ? Wq : m == 1 ? Wk : Wv) + (size_t)h * VD * VDQ;
        dst = wT + ((size_t)m * VD + h * VDQ) * VD;
        C = VDQ; ldd = VD;
        r0 = (tt >> 1) * 32; c0 = (tt & 1) * 32;
    } else if (z < 2304) {
        int z2 = z - 1728;
        src = Wp; dst = wT + OFF_PROJ;
        C = VD; ldd = VD;
        r0 = (z2 / 24) * 32; c0 = (z2 % 24) * 32;
    } else if (z < 4608) {
        int z3 = z - 2304;
        src = W1; dst = wT + OFF_M1;
        C = VMLP; ldd = VD;
        r0 = (z3 / 96) * 32; c0 = (z3 % 96) * 32;
    } else {
        int z4 = z - 4608;
        src = W2; dst = wT + OFF_M2;
        C = VD; ldd = VMLP;
        r0 = (z4 / 24) * 32; c0 = (z4 % 24) * 32;
    }
    int tid = threadIdx.x;
    {
        int r = tid >> 3, cq = (tid & 7) << 2;
        float4 v = *(const float4*)&src[(size_t)(r0 + r) * C + c0 + cq];
        t[r][cq] = v.x; t[r][cq + 1] = v.y; t[r][cq + 2] = v.z; t[r][cq + 3] = v.w;
    }
    __syncthreads();
    {
        int c = tid >> 3, rq = (tid & 7) << 2;
        unsigned u0 = pack2bf(t[rq][c],     t[rq + 1][c]);
        unsigned u1 = pack2bf(t[rq + 2][c], t[rq + 3][c]);
        unsigned* dp = (unsigned*)&dst[(size_t)(c0 + c) * ldd + r0 + rq];
        dp[0] = u0; dp[1] = u1;
    }
}

__global__ void cball_k(const float* __restrict__ bq, const float* __restrict__ bk,
                        const float* __restrict__ bv, float* __restrict__ cb) {
    int idx = blockIdx.x * 256 + threadIdx.x;
    if (idx >= VL * 3 * VD) return;
    int l = idx / (3 * VD), n = idx % (3 * VD);
    int m = n / VD, wi = n % VD;
    const float* p = (m == 0) ? bq : (m == 1) ? bk : bv;
    cb[idx] = p[l * VD + wi];
}

__global__ void cls_k(const float* __restrict__ x, __hip_bfloat16* __restrict__ out) {
    int idx = blockIdx.x * 256 + threadIdx.x;
    if (idx >= VB * VD) return;
    int b = idx / VD, d = idx % VD;
    out[idx] = __float2bfloat16(x[(size_t)b * VS * VD + d]);
}

// ---------------------------------------------------------------------------
// bf16 MFMA GEMM (m97-style 128x128) + XCD swizzle — patch/head.
// ---------------------------------------------------------------------------
template<int EPI>
__global__ __launch_bounds__(256) void bgemm_k(
    const __hip_bfloat16* __restrict__ A,
    const __hip_bfloat16* __restrict__ BT,
    const float* __restrict__ bias,
    void* __restrict__ Co,
    int M, int K, int ldc, int Ncols)
{
    __shared__ short A_s[128][64];
    __shared__ short B_s[128][64];
    int bx = blockIdx.x, by = blockIdx.y;
    xcd_swz(gridDim.x, gridDim.y, bx, by);
    const int tid = threadIdx.x;
    const int w = tid >> 6, l = tid & 63;
    const int row0 = by * 128, col0 = bx * 128;
    const int wm = (w >> 1) << 6, wn = (w & 1) << 6;
    f32x4 acc[4][4] = {};

    const int lr = l >> 3;
    const int sslot = (l & 7) ^ lr;
    int arow[4], brow[4];
    #pragma unroll
    for (int i = 0; i < 4; i++) {
        int r = (4 * w + i) * 8 + lr;
        arow[i] = min(row0 + r, M - 1);
        brow[i] = min(col0 + r, Ncols - 1);
    }
    for (int k0 = 0; k0 < K; k0 += 64) {
        __syncthreads();
        #pragma unroll
        for (int i = 0; i < 4; i++) {
            int ch = 4 * w + i;
            gload_lds16((const void*)(A + (size_t)arow[i] * K + k0 + (sslot << 3)),
                        (void*)(&A_s[ch * 8][0]));
            gload_lds16((const void*)(BT + (size_t)brow[i] * K + k0 + (sslot << 3)),
                        (void*)(&B_s[ch * 8][0]));
        }
        __syncthreads();
        #pragma unroll
        for (int ks = 0; ks < 2; ks++) {
            const int s16 = (ks << 2) + (l >> 4);
            short8 av[4], bv[4];
            #pragma unroll
            for (int i = 0; i < 4; i++) {
                int ar = wm + i * 16 + (l & 15);
                av[i] = *(const short8*)((const char*)&A_s[ar][0] + ((s16 ^ (ar & 7)) << 4));
                int br = wn + i * 16 + (l & 15);
                bv[i] = *(const short8*)((const char*)&B_s[br][0] + ((s16 ^ (br & 7)) << 4));
            }
            #pragma unroll
            for (int i = 0; i < 4; i++)
                #pragma unroll
                for (int j = 0; j < 4; j++)
                    acc[i][j] = __builtin_amdgcn_mfma_f32_16x16x32_bf16(av[i], bv[j], acc[i][j], 0, 0, 0);
        }
    }
    const int rbase = row0 + wm + ((l >> 4) << 2);
    const int cbase = col0 + wn + (l & 15);
    #pragma unroll
    for (int i = 0; i < 4; i++) {
        #pragma unroll
        for (int q = 0; q < 4; q++) {
            int rr = rbase + i * 16 + q;
            if (rr >= M) continue;
            #pragma unroll
            for (int j = 0; j < 4; j++) {
                int c = cbase + j * 16;
                if (c >= Ncols) continue;
                float v = acc[i][j][q] + bias[c];
                if (EPI == 0) {
                    int orow = rr + rr / VNPAT + 1;
                    ((float*)Co)[(size_t)orow * ldc + c] = v;
                } else if (EPI == 1) {
                    ((__hip_bfloat16*)Co)[(size_t)rr * ldc + c] = __float2bfloat16(v);
                } else if (EPI == 2) {
                    ((float*)Co)[(size_t)rr * ldc + c] += v;
                } else if (EPI == 3) {
                    ((__hip_bfloat16*)Co)[(size_t)rr * ldc + c] = __float2bfloat16(gelu_f(v));
                } else {
                    ((float*)Co)[(size_t)rr * ldc + c] = v;
                }
            }
        }
    }
}

// ---------------------------------------------------------------------------
// bgemm8_k (LEAN): 256x256 tile, 512 threads, 3-slot ring, counted vmcnt(4).
// (unchanged from r11 champion)
// ---------------------------------------------------------------------------
template<int EPI>
__global__ __launch_bounds__(512) void bgemm8_k(
    const __hip_bfloat16* __restrict__ A,
    const __hip_bfloat16* __restrict__ BT,
    const float* __restrict__ bias,
    __hip_bfloat16* __restrict__ Co,
    int M, int K, int ldc)
{
    __shared__ short SA[3][256][32];
    __shared__ short SB[3][256][32];
    const int tid = threadIdx.x;
    const int w = tid >> 6, l = tid & 63;
    const int fr = l & 15, g = l >> 4;
    const int wr = w >> 2, wc = w & 3;
    const int row0 = blockIdx.y * 256, col0 = blockIdx.x * 256;
    f32x4 acc[8][4] = {};

    const int sr = tid >> 2;
    const int sslot = (tid & 3) ^ ((sr >> 1) & 3);
    const __hip_bfloat16* aS[2]; const __hip_bfloat16* bS[2];
    #pragma unroll
    for (int u = 0; u < 2; u++) {
        aS[u] = A  + (size_t)min(row0 + u * 128 + sr, M - 1) * K + sslot * 8;
        bS[u] = BT + (size_t)(col0 + u * 128 + sr) * K + sslot * 8;
    }
    const int doff = sr * 64 + (tid & 3) * 16;

    #define STG_A(ring, t) { const int k0 = (t) << 5;                          \
        gload_lds16(aS[0] + k0, (char*)&SA[ring][0][0] + doff);                \
        gload_lds16(aS[1] + k0, (char*)&SA[ring][0][0] + 8192 + doff); }
    #define STG_B(ring, t) { const int k0 = (t) << 5;                          \
        gload_lds16(bS[0] + k0, (char*)&SB[ring][0][0] + doff);                \
        gload_lds16(bS[1] + k0, (char*)&SB[ring][0][0] + 8192 + doff); }

    const int nt = K >> 5;
    STG_A(0, 0); STG_B(0, 0);
    STG_A(1, 1); STG_B(1, 1);
    asm volatile("s_waitcnt vmcnt(4)" ::: "memory");
    __builtin_amdgcn_s_barrier();

    short8 breg[4];
    for (int t = 0; t < nt; t++) {
        const int ring = t % 3;
        const int rs   = (t + 2) % 3;
        const char* sa = (const char*)&SA[ring][0][0];
        const char* sb = (const char*)&SB[ring][0][0];
        short8 areg[4];
        #pragma unroll
        for (int n = 0; n < 4; n++) {
            int br = wc * 64 + n * 16 + fr;
            breg[n] = *(const short8*)(sb + br * 64 + ((g ^ ((br >> 1) & 3)) << 4));
        }
        #pragma unroll
        for (int m = 0; m < 4; m++) {
            int ar = wr * 128 + m * 16 + fr;
            areg[m] = *(const short8*)(sa + ar * 64 + ((g ^ ((ar >> 1) & 3)) << 4));
        }
        if (t + 2 < nt) STG_A(rs, t + 2);
        asm volatile("s_waitcnt lgkmcnt(0)" ::: "memory");
        __builtin_amdgcn_sched_barrier(0);
        __builtin_amdgcn_s_setprio(1);
        #pragma unroll
        for (int m = 0; m < 4; m++)
            #pragma unroll
            for (int n = 0; n < 4; n++)
                acc[m][n] = __builtin_amdgcn_mfma_f32_16x16x32_bf16(areg[m], breg[n], acc[m][n], 0, 0, 0);
        __builtin_amdgcn_s_setprio(0);
        #pragma unroll
        for (int m = 0; m < 4; m++) {
            int ar = wr * 128 + (m + 4) * 16 + fr;
            areg[m] = *(const short8*)(sa + ar * 64 + ((g ^ ((ar >> 1) & 3)) << 4));
        }
        if (t + 2 < nt) STG_B(rs, t + 2);
        asm volatile("s_waitcnt lgkmcnt(0)" ::: "memory");
        __builtin_amdgcn_sched_barrier(0);
        __builtin_amdgcn_s_setprio(1);
        #pragma unroll
        for (int m = 0; m < 4; m++)
            #pragma unroll
            for (int n = 0; n < 4; n++)
                acc[m + 4][n] = __builtin_amdgcn_mfma_f32_16x16x32_bf16(areg[m], breg[n], acc[m + 4][n], 0, 0, 0);
        __builtin_amdgcn_s_setprio(0);
        if (t + 2 < nt) {
            asm volatile("s_waitcnt vmcnt(4)" ::: "memory");
            __builtin_amdgcn_s_barrier();
        } else if (t + 1 < nt) {
            asm volatile("s_waitcnt vmcnt(0)" ::: "memory");
            __builtin_amdgcn_s_barrier();
        }
    }
    #undef STG_A
    #undef STG_B

    const int rb = row0 + wr * 128 + (g << 2);
    const int cb = col0 + wc * 64 + fr;
    #pragma unroll
    for (int m = 0; m < 8; m++) {
        #pragma unroll
        for (int q = 0; q < 4; q++) {
            int rr = rb + m * 16 + q;
            if (rr >= M) continue;
            #pragma unroll
            for (int n = 0; n < 4; n++) {
                int c = cb + n * 16;
                float v = acc[m][n][q] + bias[c];
                if (EPI == 3) v = gelu_f(v);
                Co[(size_t)rr * ldc + c] = __float2bfloat16(v);
            }
        }
    }
}

// ---------------------------------------------------------------------------
// bgemm9_k: split-K=2 partial GEMM with the LEAN 3-ring schedule at 128x128.
// 256 threads (4 waves, 2x2, per-wave 64x64), BK=32 tiles, 48 KB LDS ring ->
// 3 blocks/CU. One K-tile iter: {8 ds_read_b128 -> stage tile t+2 (4 gloads)
// -> lgkmcnt(0)+sched_barrier -> 16 MFMA -> boundary vmcnt(4)+s_barrier}.
// Same ledger as bgemm8 (own t+1 loads landed before publish; overwritten
// slot last read one barrier-epoch ago; dst linear tid*16 = wave-uniform
// base + lane*16). P[ks][M][ldc] = A[:, ks*K/2 ...] @ BT^T partials (fp32).
// Requires khalf mult of 32, khalf/32 >= 3.
// ---------------------------------------------------------------------------
__global__ __launch_bounds__(256) void bgemm9_k(
    const __hip_bfloat16* __restrict__ A,
    const __hip_bfloat16* __restrict__ BT,
    float* __restrict__ P,
    int M, int K, int ldc)
{
    __shared__ short SA[3][128][32];
    __shared__ short SB[3][128][32];
    int bx = blockIdx.x, by = blockIdx.y;
    xcd_swz(gridDim.x, gridDim.y, bx, by);
    const int ks = blockIdx.z;
    const int khalf = K >> 1;
    const __hip_bfloat16* Ab  = A  + (size_t)ks * khalf;
    const __hip_bfloat16* BTb = BT + (size_t)ks * khalf;
    float* Pb = P + (size_t)ks * TOKD;

    const int tid = threadIdx.x;
    const int w = tid >> 6, l = tid & 63;
    const int fr = l & 15, g = l >> 4;
    const int row0 = by * 128, col0 = bx * 128;
    const int wm = (w >> 1) << 6, wn = (w & 1) << 6;
    f32x4 acc[4][4] = {};

    // staging: 512 16B chunks per matrix per tile; 2 per thread per matrix.
    // chunk idx = tid + q*256: row = idx>>2, slot = idx&3 (64B rows).
    const __hip_bfloat16* aS[2]; const __hip_bfloat16* bS[2];
    int doff[2];
    #pragma unroll
    for (int q = 0; q < 2; q++) {
        int idx = tid + (q << 8);
        int r = idx >> 2;
        int s = (idx & 3) ^ ((r >> 1) & 3);          // pre-swizzled source slot
        aS[q] = Ab  + (size_t)min(row0 + r, M - 1) * K + s * 8;
        bS[q] = BTb + (size_t)(col0 + r) * K + s * 8;
        doff[q] = idx << 4;                          // linear dst byte offset
    }

    #define STG9(ring, t) { const int k0 = (t) << 5;                           \
        gload_lds16(aS[0] + k0, (char*)&SA[ring][0][0] + doff[0]);             \
        gload_lds16(aS[1] + k0, (char*)&SA[ring][0][0] + doff[1]);             \
        gload_lds16(bS[0] + k0, (char*)&SB[ring][0][0] + doff[0]);             \
        gload_lds16(bS[1] + k0, (char*)&SB[ring][0][0] + doff[1]); }

    const int nt = khalf >> 5;
    STG9(0, 0);
    STG9(1, 1);
    asm volatile("s_waitcnt vmcnt(4)" ::: "memory");
    __builtin_amdgcn_s_barrier();

    for (int t = 0; t < nt; t++) {
        const int ring = t % 3;
        const int rs   = (t + 2) % 3;
        const char* sa = (const char*)&SA[ring][0][0];
        const char* sb = (const char*)&SB[ring][0][0];
        short8 av[4], bv[4];
        #pragma unroll
        for (int i = 0; i < 4; i++) {
            int ar = wm + i * 16 + fr;
            av[i] = *(const short8*)(sa + ar * 64 + ((g ^ ((ar >> 1) & 3)) << 4));
            int br = wn + i * 16 + fr;
            bv[i] = *(const short8*)(sb + br * 64 + ((g ^ ((br >> 1) & 3)) << 4));
        }
        if (t + 2 < nt) STG9(rs, t + 2);
        asm volatile("s_waitcnt lgkmcnt(0)" ::: "memory");
        __builtin_amdgcn_sched_barrier(0);
        __builtin_amdgcn_s_setprio(1);
        #pragma unroll
        for (int i = 0; i < 4; i++)
            #pragma unroll
            for (int j = 0; j < 4; j++)
                acc[i][j] = __builtin_amdgcn_mfma_f32_16x16x32_bf16(av[i], bv[j], acc[i][j], 0, 0, 0);
        __builtin_amdgcn_s_setprio(0);
        if (t + 2 < nt) {
            asm volatile("s_waitcnt vmcnt(4)" ::: "memory");
            __builtin_amdgcn_s_barrier();
        } else if (t + 1 < nt) {
            asm volatile("s_waitcnt vmcnt(0)" ::: "memory");
            __builtin_amdgcn_s_barrier();
        }
    }
    #undef STG9

    const int rbase = row0 + wm + (g << 2);
    const int cbase = col0 + wn + fr;
    #pragma unroll
    for (int i = 0; i < 4; i++) {
        #pragma unroll
        for (int q = 0; q < 4; q++) {
            int rr = rbase + i * 16 + q;
            if (rr >= M) continue;
            #pragma unroll
            for (int j = 0; j < 4; j++) {
                int c = cbase + j * 16;
                Pb[(size_t)rr * ldc + c] = acc[i][j][q];
            }
        }
    }
}

// ---------------------------------------------------------------------------
// MFMA attention. Two blocks per (b,h), 256 threads, 4 waves.
// ---------------------------------------------------------------------------
__device__ __forceinline__ int swz_idx(int row, int k) {
    return row * 256 + (((k >> 3) ^ (row & 7)) << 3) + (k & 7);
}

__global__ __launch_bounds__(256) void attn3_k(
    const __hip_bfloat16* __restrict__ qkv, __hip_bfloat16* __restrict__ o)
{
    __shared__ short V_t[64 * 256];
    __shared__ short P_s[4][16 * 256];
    const int half = blockIdx.x;
    const int bh = blockIdx.y;
    const int b = bh / VNH, h = bh % VNH;
    const int tid = threadIdx.x, w = tid >> 6, l = tid & 63;
    const int g = l >> 4, c16 = l & 15;

    const __hip_bfloat16* base = qkv + (size_t)(b * VS) * (3 * VD) + h * VDQ;

    {
        const __hip_bfloat16* vbase = base + 2 * VD;
        int t = tid & 31, e0 = (tid >> 5) * 8;
        #pragma unroll
        for (int it = 0; it < 7; it++) {
            int tt = it * 32 + t;
            if (tt < VS) {
                short8 vv = *(const short8*)(vbase + (size_t)tt * (3 * VD) + e0);
                #pragma unroll
                for (int j = 0; j < 8; j++) V_t[swz_idx(e0 + j, tt)] = vv[j];
            }
        }
        for (int idx = tid; idx < 64 * 27; idx += 256) {
            int e = idx / 27, k = 197 + idx % 27;
            V_t[swz_idx(e, k)] = 0;
        }
    }
    {
        unsigned* p0 = (unsigned*)&P_s[w][swz_idx(c16, 208 + g * 4)];
        p0[0] = 0; p0[1] = 0;
    }
    __syncthreads();

    const int qt_end = half ? 13 : 7;
    for (int qt = 7 * half + w; qt < qt_end; qt += 4) {
        const int q0 = qt * 16;
        int qr = min(q0 + c16, VS - 1);
        const __hip_bfloat16* qp = base + (size_t)qr * (3 * VD) + g * 8;
        short8 qa0 = *(const short8*)(qp);
        short8 qa1 = *(const short8*)(qp + 32);

        f32x4 st[13];
        __builtin_amdgcn_s_setprio(1);
        #pragma unroll
        for (int t = 0; t < 13; t++) {
            int kr = min(t * 16 + c16, VS - 1);
            const __hip_bfloat16* kp = base + VD + (size_t)kr * (3 * VD) + g * 8;
            short8 ka0 = *(const short8*)(kp);
            short8 ka1 = *(const short8*)(kp + 32);
            f32x4 z = {};
            z = __builtin_amdgcn_mfma_f32_16x16x32_bf16(ka0, qa0, z, 0, 0, 0);
            z = __builtin_amdgcn_mfma_f32_16x16x32_bf16(ka1, qa1, z, 0, 0, 0);
            st[t] = z;
        }
        __builtin_amdgcn_s_setprio(0);
        #pragma unroll
        for (int t = 0; t < 13; t++) {
            #pragma unroll
            for (int r = 0; r < 4; r++) {
                float v = st[t][r] * 0.125f;
                if (t == 12 && (4 * g + r) >= 5) v = -3.0e38f;
                st[t][r] = v;
            }
        }
        float m = -3.0e38f;
        #pragma unroll
        for (int t = 0; t < 13; t++)
            #pragma unroll
            for (int r = 0; r < 4; r++) m = fmaxf(m, st[t][r]);
        m = fmaxf(m, __shfl_xor(m, 16));
        m = fmaxf(m, __shfl_xor(m, 32));
        float sum = 0.f;
        #pragma unroll
        for (int t = 0; t < 13; t++)
            #pragma unroll
            for (int r = 0; r < 4; r++) { float e = expf(st[t][r] - m); st[t][r] = e; sum += e; }
        sum += __shfl_xor(sum, 16);
        sum += __shfl_xor(sum, 32);
        float inv = 1.f / sum;
        #pragma unroll
        for (int t = 0; t < 13; t++) {
            int k0 = 16 * t + 4 * g;
            unsigned* pp = (unsigned*)&P_s[w][swz_idx(c16, k0)];
            pp[0] = pack2bf(st[t][0] * inv, st[t][1] * inv);
            pp[1] = pack2bf(st[t][2] * inv, st[t][3] * inv);
        }
        f32x4 acc[4] = {};
        __builtin_amdgcn_s_setprio(1);
        #pragma unroll
        for (int ki = 0; ki < 7; ki++) {
            int k0 = ki * 32 + g * 8;
            short8 pa = *(const short8*)&P_s[w][swz_idx(c16, k0)];
            #pragma unroll
            for (int et = 0; et < 4; et++) {
                short8 vbf = *(const short8*)&V_t[swz_idx(et * 16 + c16, k0)];
                acc[et] = __builtin_amdgcn_mfma_f32_16x16x32_bf16(pa, vbf, acc[et], 0, 0, 0);
            }
        }
        __builtin_amdgcn_s_setprio(0);
        #pragma unroll
        for (int et = 0; et < 4; et++) {
            #pragma unroll
            for (int r = 0; r < 4; r++) {
                int q = q0 + 4 * g + r;
                if (q < VS)
                    o[((size_t)(b * VS) + q) * VD + h * VDQ + et * 16 + c16] =
                        __float2bfloat16(acc[et][r]);
            }
        }
    }
}

// ---------------------------------------------------------------------------
extern "C" void kernel_launch(void* const* d_in, const int* in_sizes, int n_in,
                              void* d_out, int out_size, void* d_ws, size_t ws_size,
                              hipStream_t stream) {
    (void)in_sizes; (void)n_in; (void)out_size; (void)ws_size;
    const float* X       = (const float*)d_in[0];
    const float* patch_W = (const float*)d_in[1];
    const float* patch_b = (const float*)d_in[2];
    const float* cls_tok = (const float*)d_in[3];
    const float* ln1_g   = (const float*)d_in[4];
    const float* ln1_b   = (const float*)d_in[5];
    const float* Wq      = (const float*)d_in[6];
    const float* bq      = (const float*)d_in[7];
    const float* Wk      = (const float*)d_in[8];
    const float* bk      = (const float*)d_in[9];
    const float* Wv      = (const float*)d_in[10];
    const float* bv      = (const float*)d_in[11];
    const float* proj_W  = (const float*)d_in[12];
    const float* proj_b  = (const float*)d_in[13];
    const float* ln2_g   = (const float*)d_in[14];
    const float* ln2_b   = (const float*)d_in[15];
    const float* mlp_W1  = (const float*)d_in[16];
    const float* mlp_b1  = (const float*)d_in[17];
    const float* mlp_W2  = (const float*)d_in[18];
    const float* mlp_b2  = (const float*)d_in[19];
    const float* head_W  = (const float*)d_in[20];
    const float* head_b  = (const float*)d_in[21];

    char* ws = (char*)d_ws;
    float*          x    = (float*)ws;                            // 19.37 MB fp32
    __hip_bfloat16* tb   = (__hip_bfloat16*)(ws + 19365888);      // 9.68 MB bf16
    __hip_bfloat16* big  = (__hip_bfloat16*)(ws + 29048832);      // 38.73 MB
    __hip_bfloat16* wT   = (__hip_bfloat16*)(ws + 67780608);      // 14.16 MB
    float*          cbA  = (float*)(ws + 81936384);               // 110 KB
    float*          pbuf = (float*)(ws + 82046976);               // 38.73 MB

    cball_k<<<(VL * 3 * VD + 255) / 256, 256, 0, stream>>>(bq, bk, bv, cbA);

    patchify_k<<<(VB * VNPAT * VP + 255) / 256, 256, 0, stream>>>(X, big);
    {
        dim3 g(VD / 32, VP / 32);
        tpose_k<<<g, 256, 0, stream>>>(patch_W, wT, VP, VD);
    }
    {
        dim3 g(VD / 128, VB * VNPAT / 128);
        bgemm_k<0><<<g, 256, 0, stream>>>(big, wT, patch_b, x, VB * VNPAT, VP, VD, VD);
    }
    pos_cls_k<<<(unsigned)((TOKD + 255) / 256), 256, 0, stream>>>(x, cls_tok);

    const size_t WSZ = (size_t)VNH * VD * VDQ;
    for (int l = 0; l < VL; l++) {
        wprep_k<<<6912, 256, 0, stream>>>(
            Wq + l * WSZ, Wk + l * WSZ, Wv + l * WSZ,
            proj_W + (size_t)l * VD * VD,
            mlp_W1 + (size_t)l * VD * VMLP,
            mlp_W2 + (size_t)l * VMLP * VD, wT);

        if (l == 0)
            layernorm_k<<<VTOK, 256, 0, stream>>>(x, tb, ln1_g, ln1_b);

        {
            // fused QKV GEMM: lean 256² 3-ring, grid 9 x 25
            dim3 g(3 * VD / 256, (VTOK + 255) / 256);
            bgemm8_k<1><<<g, 512, 0, stream>>>(tb, wT, cbA + l * 3 * VD, big,
                                               VTOK, VD, 3 * VD);
        }
        {
            dim3 ga(2, VB * VNH);
            attn3_k<<<ga, 256, 0, stream>>>(big, tb);
        }
        {
            // proj split-K=2 (lean 3-ring), then combine + residual + LN2
            dim3 g(VD / 128, (VTOK + 127) / 128, 2);
            bgemm9_k<<<g, 256, 0, stream>>>(tb, wT + OFF_PROJ, pbuf, VTOK, VD, VD);
            combineln_k<1><<<VTOK, 256, 0, stream>>>(
                x, pbuf, pbuf + TOKD, proj_b + l * VD,
                ln2_g + l * VD, ln2_b + l * VD, tb);
        }
        {
            // MLP1: lean 256² 3-ring + fast-GELU, grid 12 x 25
            dim3 g(VMLP / 256, (VTOK + 255) / 256);
            bgemm8_k<3><<<g, 512, 0, stream>>>(tb, wT + OFF_M1, mlp_b1 + l * VMLP, big,
                                               VTOK, VD, VMLP);
        }
        {
            // MLP2 split-K=2 (lean 3-ring), then combine + residual (+ next LN1)
            dim3 g(VD / 128, (VTOK + 127) / 128, 2);
            bgemm9_k<<<g, 256, 0, stream>>>(big, wT + OFF_M2, pbuf, VTOK, VMLP, VD);
            if (l + 1 < VL)
                combineln_k<1><<<VTOK, 256, 0, stream>>>(
                    x, pbuf, pbuf + TOKD, mlp_b2 + l * VD,
                    ln1_g + (l + 1) * VD, ln1_b + (l + 1) * VD, tb);
            else
                combineln_k<0><<<VTOK, 256, 0, stream>>>(
                    x, pbuf, pbuf + TOKD, mlp_b2 + l * VD,
                    nullptr, nullptr, nullptr);
        }
    }
    cls_k<<<(VB * VD + 255) / 256, 256, 0, stream>>>(x, tb);
    {
        dim3 gt((VC + 31) / 32, VD / 32);
        tpose_k<<<gt, 256, 0, stream>>>(head_W, wT, VD, VC);
        dim3 g((VC + 127) / 128, 1);
        bgemm_k<4><<<g, 256, 0, stream>>>(tb, wT, head_b, (float*)d_out,
                                          VB, VD, VC, VC);
    }
}

// Round 13
// 2740.275 us; speedup vs baseline: 1.9168x; 1.0207x over previous
//
#include <hip/hip_runtime.h>
#include <hip/hip_bf16.h>
#include <math.h>
#include <stdint.h>

// ViT config
#define VB   32
#define VS   197
#define VD   768
#define VNH  12
#define VDQ  64
#define VL   12
#define VMLP 3072
#define VC   1000
#define VP   256
#define VNPAT 196
#define VTOK (VB * VS)            // 6304
#define TOKD ((size_t)VTOK * VD)  // 4841472 floats

typedef __attribute__((ext_vector_type(4))) float f32x4;
typedef __attribute__((ext_vector_type(8))) short short8;

typedef __attribute__((address_space(1))) const unsigned int GU;
typedef __attribute__((address_space(3))) unsigned int LU;

__device__ __forceinline__ void gload_lds16(const void* g, void* l) {
    __builtin_amdgcn_global_load_lds((GU*)(uintptr_t)g, (LU*)(uintptr_t)l, 16, 0, 0);
}

// T1: bijective XCD-aware block swizzle (m204).
__device__ __forceinline__ void xcd_swz(int gx, int gy, int& bx, int& by) {
    int nwg = gx * gy;
    int hw = by * gx + bx;
    int q = nwg >> 3, r = nwg & 7;
    int xcd = hw & 7, off = hw >> 3;
    int lid = (xcd < r ? xcd * (q + 1) : r * (q + 1) + (xcd - r) * q) + off;
    bx = lid % gx; by = lid / gx;
}

// Fast tanh-form GELU.
__device__ __forceinline__ float gelu_f(float x) {
    float t = 0.7978845608f * x * fmaf(0.044715f, x * x, 1.0f);
    float a = fminf(t * 2.8853900818f, 80.0f);
    float e = __builtin_amdgcn_exp2f(a);
    return x * e * __builtin_amdgcn_rcpf(1.0f + e);
}

// ---------------------------------------------------------------------------
__global__ void patchify_k(const float* __restrict__ X, __hip_bfloat16* __restrict__ P) {
    int idx = blockIdx.x * 256 + threadIdx.x;
    const int total = VB * VNPAT * VP;
    if (idx >= total) return;
    int i  = idx & 255;
    int p  = (idx >> 8) % VNPAT;
    int b  = (idx >> 8) / VNPAT;
    int pr = p / 14, pc = p % 14;
    int a  = i >> 4, c2 = i & 15;
    P[idx] = __float2bfloat16(X[((size_t)b * 224 + pr * 16 + a) * 224 + pc * 16 + c2]);
}

__global__ void pos_cls_k(float* __restrict__ x, const float* __restrict__ cls) {
    size_t idx = (size_t)blockIdx.x * 256 + threadIdx.x;
    if (idx >= TOKD) return;
    int j = (int)(idx % VD);
    int s = (int)((idx / VD) % VS);
    float jj = (float)(j & ~1);
    float freq = expf(-(jj / (float)VD) * 9.2103403719761836f);
    float ang  = (float)s * freq;
    float pe   = (j & 1) ? cosf(ang) : sinf(ang);
    if (s == 0) x[idx] = cls[j] + pe;
    else        x[idx] += pe;
}

__global__ __launch_bounds__(256) void layernorm_k(
    const float* __restrict__ x, __hip_bfloat16* __restrict__ y,
    const float* __restrict__ g, const float* __restrict__ bta)
{
    int t = blockIdx.x;
    const float* xr = x + (size_t)t * VD;
    __hip_bfloat16* yr = y + (size_t)t * VD;
    int tid = threadIdx.x;
    float v[3];
    float s = 0.f;
    #pragma unroll
    for (int i = 0; i < 3; i++) { v[i] = xr[tid + i * 256]; s += v[i]; }
    __shared__ float red[8];
    #pragma unroll
    for (int off = 32; off; off >>= 1) s += __shfl_xor(s, off);
    int lane = tid & 63, w = tid >> 6;
    if (!lane) red[w] = s;
    __syncthreads();
    float mu = (red[0] + red[1] + red[2] + red[3]) * (1.f / VD);
    float s2 = 0.f;
    #pragma unroll
    for (int i = 0; i < 3; i++) { float d0 = v[i] - mu; s2 += d0 * d0; }
    #pragma unroll
    for (int off = 32; off; off >>= 1) s2 += __shfl_xor(s2, off);
    if (!lane) red[4 + w] = s2;
    __syncthreads();
    float var = (red[4] + red[5] + red[6] + red[7]) * (1.f / VD);
    float rs = rsqrtf(var + 1e-5f);
    #pragma unroll
    for (int i = 0; i < 3; i++) {
        int j = tid + i * 256;
        yr[j] = __float2bfloat16((v[i] - mu) * rs * g[j] + bta[j]);
    }
}

template<int DO_LN>
__global__ __launch_bounds__(256) void combineln_k(
    float* __restrict__ x, const float* __restrict__ p0, const float* __restrict__ p1,
    const float* __restrict__ bias, const float* __restrict__ g,
    const float* __restrict__ bta, __hip_bfloat16* __restrict__ y)
{
    int t = blockIdx.x;
    size_t base = (size_t)t * VD;
    int tid = threadIdx.x;
    float v[3];
    float s = 0.f;
    #pragma unroll
    for (int i = 0; i < 3; i++) {
        int j = tid + i * 256;
        float val = x[base + j] + p0[base + j] + p1[base + j] + bias[j];
        x[base + j] = val;
        v[i] = val; s += val;
    }
    if (DO_LN) {
        __shared__ float red[8];
        #pragma unroll
        for (int off = 32; off; off >>= 1) s += __shfl_xor(s, off);
        int lane = tid & 63, w = tid >> 6;
        if (!lane) red[w] = s;
        __syncthreads();
        float mu = (red[0] + red[1] + red[2] + red[3]) * (1.f / VD);
        float s2 = 0.f;
        #pragma unroll
        for (int i = 0; i < 3; i++) { float d0 = v[i] - mu; s2 += d0 * d0; }
        #pragma unroll
        for (int off = 32; off; off >>= 1) s2 += __shfl_xor(s2, off);
        if (!lane) red[4 + w] = s2;
        __syncthreads();
        float var = (red[4] + red[5] + red[6] + red[7]) * (1.f / VD);
        float rs = rsqrtf(var + 1e-5f);
        #pragma unroll
        for (int i = 0; i < 3; i++) {
            int j = tid + i * 256;
            y[base + j] = __float2bfloat16((v[i] - mu) * rs * g[j] + bta[j]);
        }
    }
}

__global__ __launch_bounds__(256) void tpose_k(
    const float* __restrict__ in, __hip_bfloat16* __restrict__ out, int R, int C)
{
    __shared__ float t[32][33];
    int c0 = blockIdx.x * 32, r0 = blockIdx.y * 32;
    int tc = threadIdx.x & 31, tr = threadIdx.x >> 5;
    #pragma unroll
    for (int p = 0; p < 4; p++) {
        int r = r0 + tr + p * 8;
        t[tr + p * 8][tc] = (r < R && c0 + tc < C) ? in[(size_t)r * C + c0 + tc] : 0.f;
    }
    __syncthreads();
    #pragma unroll
    for (int p = 0; p < 4; p++) {
        int c = c0 + tr + p * 8;
        if (c < C && r0 + tc < R)
            out[(size_t)c * R + r0 + tc] = __float2bfloat16(t[tc][tr + p * 8]);
    }
}

#define OFF_PROJ (2304 * 768)
#define OFF_M1   (OFF_PROJ + 768 * 768)
#define OFF_M2   (OFF_M1 + 3072 * 768)

__device__ __forceinline__ unsigned pack2bf(float a, float b) {
    __hip_bfloat16 x = __float2bfloat16(a), y = __float2bfloat16(b);
    unsigned short ux = *(unsigned short*)&x, uy = *(unsigned short*)&y;
    return (unsigned)ux | ((unsigned)uy << 16);
}

__global__ __launch_bounds__(256) void wprep_k(
    const float* __restrict__ Wq, const float* __restrict__ Wk,
    const float* __restrict__ Wv, const float* __restrict__ Wp,
    const float* __restrict__ W1, const float* __restrict__ W2,
    __hip_bfloat16* __restrict__ wT)
{
    __shared__ float t[32][33];
    int z = blockIdx.x;
    const float* src; __hip_bfloat16* dst;
    int C, ldd, r0, c0;
    if (z < 1728) {
        int head = z / 48, tt = z % 48;
        int m = head / VNH, h = head % VNH;
        src = (m == 0 ? Wq : m == 1 ? Wk : Wv) + (size_t)h * VD * VDQ;
        dst = wT + ((size_t)m * VD + h * VDQ) * VD;
        C = VDQ; ldd = VD;
        r0 = (tt >> 1) * 32; c0 = (tt & 1) * 32;
    } else if (z < 2304) {
        int z2 = z - 1728;
        src = Wp; dst = wT + OFF_PROJ;
        C = VD; ldd = VD;
        r0 = (z2 / 24) * 32; c0 = (z2 % 24) * 32;
    } else if (z < 4608) {
        int z3 = z - 2304;
        src = W1; dst = wT + OFF_M1;
        C = VMLP; ldd = VD;
        r0 = (z3 / 96) * 32; c0 = (z3 % 96) * 32;
    } else {
        int z4 = z - 4608;
        src = W2; dst = wT + OFF_M2;
        C = VD; ldd = VMLP;
        r0 = (z4 / 24) * 32; c0 = (z4 % 24) * 32;
    }
    int tid = threadIdx.x;
    {
        int r = tid >> 3, cq = (tid & 7) << 2;
        float4 v = *(const float4*)&src[(size_t)(r0 + r) * C + c0 + cq];
        t[r][cq] = v.x; t[r][cq + 1] = v.y; t[r][cq + 2] = v.z; t[r][cq + 3] = v.w;
    }
    __syncthreads();
    {
        int c = tid >> 3, rq = (tid & 7) << 2;
        unsigned u0 = pack2bf(t[rq][c],     t[rq + 1][c]);
        unsigned u1 = pack2bf(t[rq + 2][c], t[rq + 3][c]);
        unsigned* dp = (unsigned*)&dst[(size_t)(c0 + c) * ldd + r0 + rq];
        dp[0] = u0; dp[1] = u1;
    }
}

__global__ void cball_k(const float* __restrict__ bq, const float* __restrict__ bk,
                        const float* __restrict__ bv, float* __restrict__ cb) {
    int idx = blockIdx.x * 256 + threadIdx.x;
    if (idx >= VL * 3 * VD) return;
    int l = idx / (3 * VD), n = idx % (3 * VD);
    int m = n / VD, wi = n % VD;
    const float* p = (m == 0) ? bq : (m == 1) ? bk : bv;
    cb[idx] = p[l * VD + wi];
}

__global__ void cls_k(const float* __restrict__ x, __hip_bfloat16* __restrict__ out) {
    int idx = blockIdx.x * 256 + threadIdx.x;
    if (idx >= VB * VD) return;
    int b = idx / VD, d = idx % VD;
    out[idx] = __float2bfloat16(x[(size_t)b * VS * VD + d]);
}

// ---------------------------------------------------------------------------
// bf16 MFMA GEMM (m97-style 128x128) + XCD swizzle — patch/head only.
// ---------------------------------------------------------------------------
template<int EPI>
__global__ __launch_bounds__(256) void bgemm_k(
    const __hip_bfloat16* __restrict__ A,
    const __hip_bfloat16* __restrict__ BT,
    const float* __restrict__ bias,
    void* __restrict__ Co,
    int M, int K, int ldc, int Ncols)
{
    __shared__ short A_s[128][64];
    __shared__ short B_s[128][64];
    int bx = blockIdx.x, by = blockIdx.y;
    xcd_swz(gridDim.x, gridDim.y, bx, by);
    const int tid = threadIdx.x;
    const int w = tid >> 6, l = tid & 63;
    const int row0 = by * 128, col0 = bx * 128;
    const int wm = (w >> 1) << 6, wn = (w & 1) << 6;
    f32x4 acc[4][4] = {};

    const int lr = l >> 3;
    const int sslot = (l & 7) ^ lr;
    int arow[4], brow[4];
    #pragma unroll
    for (int i = 0; i < 4; i++) {
        int r = (4 * w + i) * 8 + lr;
        arow[i] = min(row0 + r, M - 1);
        brow[i] = min(col0 + r, Ncols - 1);
    }
    for (int k0 = 0; k0 < K; k0 += 64) {
        __syncthreads();
        #pragma unroll
        for (int i = 0; i < 4; i++) {
            int ch = 4 * w + i;
            gload_lds16((const void*)(A + (size_t)arow[i] * K + k0 + (sslot << 3)),
                        (void*)(&A_s[ch * 8][0]));
            gload_lds16((const void*)(BT + (size_t)brow[i] * K + k0 + (sslot << 3)),
                        (void*)(&B_s[ch * 8][0]));
        }
        __syncthreads();
        #pragma unroll
        for (int ks = 0; ks < 2; ks++) {
            const int s16 = (ks << 2) + (l >> 4);
            short8 av[4], bv[4];
            #pragma unroll
            for (int i = 0; i < 4; i++) {
                int ar = wm + i * 16 + (l & 15);
                av[i] = *(const short8*)((const char*)&A_s[ar][0] + ((s16 ^ (ar & 7)) << 4));
                int br = wn + i * 16 + (l & 15);
                bv[i] = *(const short8*)((const char*)&B_s[br][0] + ((s16 ^ (br & 7)) << 4));
            }
            #pragma unroll
            for (int i = 0; i < 4; i++)
                #pragma unroll
                for (int j = 0; j < 4; j++)
                    acc[i][j] = __builtin_amdgcn_mfma_f32_16x16x32_bf16(av[i], bv[j], acc[i][j], 0, 0, 0);
        }
    }
    const int rbase = row0 + wm + ((l >> 4) << 2);
    const int cbase = col0 + wn + (l & 15);
    #pragma unroll
    for (int i = 0; i < 4; i++) {
        #pragma unroll
        for (int q = 0; q < 4; q++) {
            int rr = rbase + i * 16 + q;
            if (rr >= M) continue;
            #pragma unroll
            for (int j = 0; j < 4; j++) {
                int c = cbase + j * 16;
                if (c >= Ncols) continue;
                float v = acc[i][j][q] + bias[c];
                if (EPI == 0) {
                    int orow = rr + rr / VNPAT + 1;
                    ((float*)Co)[(size_t)orow * ldc + c] = v;
                } else if (EPI == 1) {
                    ((__hip_bfloat16*)Co)[(size_t)rr * ldc + c] = __float2bfloat16(v);
                } else if (EPI == 2) {
                    ((float*)Co)[(size_t)rr * ldc + c] += v;
                } else if (EPI == 3) {
                    ((__hip_bfloat16*)Co)[(size_t)rr * ldc + c] = __float2bfloat16(gelu_f(v));
                } else {
                    ((float*)Co)[(size_t)rr * ldc + c] = v;
                }
            }
        }
    }
}

// ---------------------------------------------------------------------------
// bgemm10_k: lean 3-ring 128x128 full-K GEMM (bgemm9 structure, no split-K)
// with bias + epilogue. 256 threads (4 waves 2x2, per-wave 64x64), BK=32
// K-tiles in a 3-slot 48 KB LDS ring -> 3 blocks/CU (12 waves/CU).
// Per K-tile: {8 ds_read_b128 -> stage tile t+2 (4 gloads/thr) ->
// lgkmcnt(0)+sched_barrier -> setprio(1) 16 MFMA -> vmcnt(4)+s_barrier}.
// Ledger identical to bgemm9 (proven r12). K mult of 32, K/32 >= 3.
// EPI: 1 = bf16 store; 3 = fast-GELU -> bf16 store.
// ---------------------------------------------------------------------------
template<int EPI>
__global__ __launch_bounds__(256) void bgemm10_k(
    const __hip_bfloat16* __restrict__ A,
    const __hip_bfloat16* __restrict__ BT,
    const float* __restrict__ bias,
    __hip_bfloat16* __restrict__ Co,
    int M, int K, int ldc)
{
    __shared__ short SA[3][128][32];
    __shared__ short SB[3][128][32];
    int bx = blockIdx.x, by = blockIdx.y;
    xcd_swz(gridDim.x, gridDim.y, bx, by);

    const int tid = threadIdx.x;
    const int w = tid >> 6, l = tid & 63;
    const int fr = l & 15, g = l >> 4;
    const int row0 = by * 128, col0 = bx * 128;
    const int wm = (w >> 1) << 6, wn = (w & 1) << 6;
    f32x4 acc[4][4] = {};

    const __hip_bfloat16* aS[2]; const __hip_bfloat16* bS[2];
    int doff[2];
    #pragma unroll
    for (int q = 0; q < 2; q++) {
        int idx = tid + (q << 8);
        int r = idx >> 2;
        int s = (idx & 3) ^ ((r >> 1) & 3);          // pre-swizzled source slot
        aS[q] = A  + (size_t)min(row0 + r, M - 1) * K + s * 8;
        bS[q] = BT + (size_t)(col0 + r) * K + s * 8;
        doff[q] = idx << 4;
    }

    #define STG10(ring, t) { const int k0 = (t) << 5;                          \
        gload_lds16(aS[0] + k0, (char*)&SA[ring][0][0] + doff[0]);             \
        gload_lds16(aS[1] + k0, (char*)&SA[ring][0][0] + doff[1]);             \
        gload_lds16(bS[0] + k0, (char*)&SB[ring][0][0] + doff[0]);             \
        gload_lds16(bS[1] + k0, (char*)&SB[ring][0][0] + doff[1]); }

    const int nt = K >> 5;
    STG10(0, 0);
    STG10(1, 1);
    asm volatile("s_waitcnt vmcnt(4)" ::: "memory");
    __builtin_amdgcn_s_barrier();

    for (int t = 0; t < nt; t++) {
        const int ring = t % 3;
        const int rs   = (t + 2) % 3;
        const char* sa = (const char*)&SA[ring][0][0];
        const char* sb = (const char*)&SB[ring][0][0];
        short8 av[4], bv[4];
        #pragma unroll
        for (int i = 0; i < 4; i++) {
            int ar = wm + i * 16 + fr;
            av[i] = *(const short8*)(sa + ar * 64 + ((g ^ ((ar >> 1) & 3)) << 4));
            int br = wn + i * 16 + fr;
            bv[i] = *(const short8*)(sb + br * 64 + ((g ^ ((br >> 1) & 3)) << 4));
        }
        if (t + 2 < nt) STG10(rs, t + 2);
        asm volatile("s_waitcnt lgkmcnt(0)" ::: "memory");
        __builtin_amdgcn_sched_barrier(0);
        __builtin_amdgcn_s_setprio(1);
        #pragma unroll
        for (int i = 0; i < 4; i++)
            #pragma unroll
            for (int j = 0; j < 4; j++)
                acc[i][j] = __builtin_amdgcn_mfma_f32_16x16x32_bf16(av[i], bv[j], acc[i][j], 0, 0, 0);
        __builtin_amdgcn_s_setprio(0);
        if (t + 2 < nt) {
            asm volatile("s_waitcnt vmcnt(4)" ::: "memory");
            __builtin_amdgcn_s_barrier();
        } else if (t + 1 < nt) {
            asm volatile("s_waitcnt vmcnt(0)" ::: "memory");
            __builtin_amdgcn_s_barrier();
        }
    }
    #undef STG10

    const int rbase = row0 + wm + (g << 2);
    const int cbase = col0 + wn + fr;
    #pragma unroll
    for (int i = 0; i < 4; i++) {
        #pragma unroll
        for (int q = 0; q < 4; q++) {
            int rr = rbase + i * 16 + q;
            if (rr >= M) continue;
            #pragma unroll
            for (int j = 0; j < 4; j++) {
                int c = cbase + j * 16;
                float v = acc[i][j][q] + bias[c];
                if (EPI == 3) v = gelu_f(v);
                Co[(size_t)rr * ldc + c] = __float2bfloat16(v);
            }
        }
    }
}

// ---------------------------------------------------------------------------
// bgemm9_k: split-K=2 partial GEMM, lean 3-ring 128x128 (proj / MLP2).
// ---------------------------------------------------------------------------
__global__ __launch_bounds__(256) void bgemm9_k(
    const __hip_bfloat16* __restrict__ A,
    const __hip_bfloat16* __restrict__ BT,
    float* __restrict__ P,
    int M, int K, int ldc)
{
    __shared__ short SA[3][128][32];
    __shared__ short SB[3][128][32];
    int bx = blockIdx.x, by = blockIdx.y;
    xcd_swz(gridDim.x, gridDim.y, bx, by);
    const int ks = blockIdx.z;
    const int khalf = K >> 1;
    const __hip_bfloat16* Ab  = A  + (size_t)ks * khalf;
    const __hip_bfloat16* BTb = BT + (size_t)ks * khalf;
    float* Pb = P + (size_t)ks * TOKD;

    const int tid = threadIdx.x;
    const int w = tid >> 6, l = tid & 63;
    const int fr = l & 15, g = l >> 4;
    const int row0 = by * 128, col0 = bx * 128;
    const int wm = (w >> 1) << 6, wn = (w & 1) << 6;
    f32x4 acc[4][4] = {};

    const __hip_bfloat16* aS[2]; const __hip_bfloat16* bS[2];
    int doff[2];
    #pragma unroll
    for (int q = 0; q < 2; q++) {
        int idx = tid + (q << 8);
        int r = idx >> 2;
        int s = (idx & 3) ^ ((r >> 1) & 3);
        aS[q] = Ab  + (size_t)min(row0 + r, M - 1) * K + s * 8;
        bS[q] = BTb + (size_t)(col0 + r) * K + s * 8;
        doff[q] = idx << 4;
    }

    #define STG9(ring, t) { const int k0 = (t) << 5;                           \
        gload_lds16(aS[0] + k0, (char*)&SA[ring][0][0] + doff[0]);             \
        gload_lds16(aS[1] + k0, (char*)&SA[ring][0][0] + doff[1]);             \
        gload_lds16(bS[0] + k0, (char*)&SB[ring][0][0] + doff[0]);             \
        gload_lds16(bS[1] + k0, (char*)&SB[ring][0][0] + doff[1]); }

    const int nt = khalf >> 5;
    STG9(0, 0);
    STG9(1, 1);
    asm volatile("s_waitcnt vmcnt(4)" ::: "memory");
    __builtin_amdgcn_s_barrier();

    for (int t = 0; t < nt; t++) {
        const int ring = t % 3;
        const int rs   = (t + 2) % 3;
        const char* sa = (const char*)&SA[ring][0][0];
        const char* sb = (const char*)&SB[ring][0][0];
        short8 av[4], bv[4];
        #pragma unroll
        for (int i = 0; i < 4; i++) {
            int ar = wm + i * 16 + fr;
            av[i] = *(const short8*)(sa + ar * 64 + ((g ^ ((ar >> 1) & 3)) << 4));
            int br = wn + i * 16 + fr;
            bv[i] = *(const short8*)(sb + br * 64 + ((g ^ ((br >> 1) & 3)) << 4));
        }
        if (t + 2 < nt) STG9(rs, t + 2);
        asm volatile("s_waitcnt lgkmcnt(0)" ::: "memory");
        __builtin_amdgcn_sched_barrier(0);
        __builtin_amdgcn_s_setprio(1);
        #pragma unroll
        for (int i = 0; i < 4; i++)
            #pragma unroll
            for (int j = 0; j < 4; j++)
                acc[i][j] = __builtin_amdgcn_mfma_f32_16x16x32_bf16(av[i], bv[j], acc[i][j], 0, 0, 0);
        __builtin_amdgcn_s_setprio(0);
        if (t + 2 < nt) {
            asm volatile("s_waitcnt vmcnt(4)" ::: "memory");
            __builtin_amdgcn_s_barrier();
        } else if (t + 1 < nt) {
            asm volatile("s_waitcnt vmcnt(0)" ::: "memory");
            __builtin_amdgcn_s_barrier();
        }
    }
    #undef STG9

    const int rbase = row0 + wm + (g << 2);
    const int cbase = col0 + wn + fr;
    #pragma unroll
    for (int i = 0; i < 4; i++) {
        #pragma unroll
        for (int q = 0; q < 4; q++) {
            int rr = rbase + i * 16 + q;
            if (rr >= M) continue;
            #pragma unroll
            for (int j = 0; j < 4; j++) {
                int c = cbase + j * 16;
                Pb[(size_t)rr * ldc + c] = acc[i][j][q];
            }
        }
    }
}

// ---------------------------------------------------------------------------
// MFMA attention. Two blocks per (b,h), 256 threads, 4 waves.
// ---------------------------------------------------------------------------
__device__ __forceinline__ int swz_idx(int row, int k) {
    return row * 256 + (((k >> 3) ^ (row & 7)) << 3) + (k & 7);
}

__global__ __launch_bounds__(256) void attn3_k(
    const __hip_bfloat16* __restrict__ qkv, __hip_bfloat16* __restrict__ o)
{
    __shared__ short V_t[64 * 256];
    __shared__ short P_s[4][16 * 256];
    const int half = blockIdx.x;
    const int bh = blockIdx.y;
    const int b = bh / VNH, h = bh % VNH;
    const int tid = threadIdx.x, w = tid >> 6, l = tid & 63;
    const int g = l >> 4, c16 = l & 15;

    const __hip_bfloat16* base = qkv + (size_t)(b * VS) * (3 * VD) + h * VDQ;

    {
        const __hip_bfloat16* vbase = base + 2 * VD;
        int t = tid & 31, e0 = (tid >> 5) * 8;
        #pragma unroll
        for (int it = 0; it < 7; it++) {
            int tt = it * 32 + t;
            if (tt < VS) {
                short8 vv = *(const short8*)(vbase + (size_t)tt * (3 * VD) + e0);
                #pragma unroll
                for (int j = 0; j < 8; j++) V_t[swz_idx(e0 + j, tt)] = vv[j];
            }
        }
        for (int idx = tid; idx < 64 * 27; idx += 256) {
            int e = idx / 27, k = 197 + idx % 27;
            V_t[swz_idx(e, k)] = 0;
        }
    }
    {
        unsigned* p0 = (unsigned*)&P_s[w][swz_idx(c16, 208 + g * 4)];
        p0[0] = 0; p0[1] = 0;
    }
    __syncthreads();

    const int qt_end = half ? 13 : 7;
    for (int qt = 7 * half + w; qt < qt_end; qt += 4) {
        const int q0 = qt * 16;
        int qr = min(q0 + c16, VS - 1);
        const __hip_bfloat16* qp = base + (size_t)qr * (3 * VD) + g * 8;
        short8 qa0 = *(const short8*)(qp);
        short8 qa1 = *(const short8*)(qp + 32);

        f32x4 st[13];
        __builtin_amdgcn_s_setprio(1);
        #pragma unroll
        for (int t = 0; t < 13; t++) {
            int kr = min(t * 16 + c16, VS - 1);
            const __hip_bfloat16* kp = base + VD + (size_t)kr * (3 * VD) + g * 8;
            short8 ka0 = *(const short8*)(kp);
            short8 ka1 = *(const short8*)(kp + 32);
            f32x4 z = {};
            z = __builtin_amdgcn_mfma_f32_16x16x32_bf16(ka0, qa0, z, 0, 0, 0);
            z = __builtin_amdgcn_mfma_f32_16x16x32_bf16(ka1, qa1, z, 0, 0, 0);
            st[t] = z;
        }
        __builtin_amdgcn_s_setprio(0);
        #pragma unroll
        for (int t = 0; t < 13; t++) {
            #pragma unroll
            for (int r = 0; r < 4; r++) {
                float v = st[t][r] * 0.125f;
                if (t == 12 && (4 * g + r) >= 5) v = -3.0e38f;
                st[t][r] = v;
            }
        }
        float m = -3.0e38f;
        #pragma unroll
        for (int t = 0; t < 13; t++)
            #pragma unroll
            for (int r = 0; r < 4; r++) m = fmaxf(m, st[t][r]);
        m = fmaxf(m, __shfl_xor(m, 16));
        m = fmaxf(m, __shfl_xor(m, 32));
        float sum = 0.f;
        #pragma unroll
        for (int t = 0; t < 13; t++)
            #pragma unroll
            for (int r = 0; r < 4; r++) { float e = expf(st[t][r] - m); st[t][r] = e; sum += e; }
        sum += __shfl_xor(sum, 16);
        sum += __shfl_xor(sum, 32);
        float inv = 1.f / sum;
        #pragma unroll
        for (int t = 0; t < 13; t++) {
            int k0 = 16 * t + 4 * g;
            unsigned* pp = (unsigned*)&P_s[w][swz_idx(c16, k0)];
            pp[0] = pack2bf(st[t][0] * inv, st[t][1] * inv);
            pp[1] = pack2bf(st[t][2] * inv, st[t][3] * inv);
        }
        f32x4 acc[4] = {};
        __builtin_amdgcn_s_setprio(1);
        #pragma unroll
        for (int ki = 0; ki < 7; ki++) {
            int k0 = ki * 32 + g * 8;
            short8 pa = *(const short8*)&P_s[w][swz_idx(c16, k0)];
            #pragma unroll
            for (int et = 0; et < 4; et++) {
                short8 vbf = *(const short8*)&V_t[swz_idx(et * 16 + c16, k0)];
                acc[et] = __builtin_amdgcn_mfma_f32_16x16x32_bf16(pa, vbf, acc[et], 0, 0, 0);
            }
        }
        __builtin_amdgcn_s_setprio(0);
        #pragma unroll
        for (int et = 0; et < 4; et++) {
            #pragma unroll
            for (int r = 0; r < 4; r++) {
                int q = q0 + 4 * g + r;
                if (q < VS)
                    o[((size_t)(b * VS) + q) * VD + h * VDQ + et * 16 + c16] =
                        __float2bfloat16(acc[et][r]);
            }
        }
    }
}

// ---------------------------------------------------------------------------
extern "C" void kernel_launch(void* const* d_in, const int* in_sizes, int n_in,
                              void* d_out, int out_size, void* d_ws, size_t ws_size,
                              hipStream_t stream) {
    (void)in_sizes; (void)n_in; (void)out_size; (void)ws_size;
    const float* X       = (const float*)d_in[0];
    const float* patch_W = (const float*)d_in[1];
    const float* patch_b = (const float*)d_in[2];
    const float* cls_tok = (const float*)d_in[3];
    const float* ln1_g   = (const float*)d_in[4];
    const float* ln1_b   = (const float*)d_in[5];
    const float* Wq      = (const float*)d_in[6];
    const float* bq      = (const float*)d_in[7];
    const float* Wk      = (const float*)d_in[8];
    const float* bk      = (const float*)d_in[9];
    const float* Wv      = (const float*)d_in[10];
    const float* bv      = (const float*)d_in[11];
    const float* proj_W  = (const float*)d_in[12];
    const float* proj_b  = (const float*)d_in[13];
    const float* ln2_g   = (const float*)d_in[14];
    const float* ln2_b   = (const float*)d_in[15];
    const float* mlp_W1  = (const float*)d_in[16];
    const float* mlp_b1  = (const float*)d_in[17];
    const float* mlp_W2  = (const float*)d_in[18];
    const float* mlp_b2  = (const float*)d_in[19];
    const float* head_W  = (const float*)d_in[20];
    const float* head_b  = (const float*)d_in[21];

    char* ws = (char*)d_ws;
    float*          x    = (float*)ws;                            // 19.37 MB fp32
    __hip_bfloat16* tb   = (__hip_bfloat16*)(ws + 19365888);      // 9.68 MB bf16
    __hip_bfloat16* big  = (__hip_bfloat16*)(ws + 29048832);      // 38.73 MB
    __hip_bfloat16* wT   = (__hip_bfloat16*)(ws + 67780608);      // 14.16 MB
    float*          cbA  = (float*)(ws + 81936384);               // 110 KB
    float*          pbuf = (float*)(ws + 82046976);               // 38.73 MB

    cball_k<<<(VL * 3 * VD + 255) / 256, 256, 0, stream>>>(bq, bk, bv, cbA);

    patchify_k<<<(VB * VNPAT * VP + 255) / 256, 256, 0, stream>>>(X, big);
    {
        dim3 g(VD / 32, VP / 32);
        tpose_k<<<g, 256, 0, stream>>>(patch_W, wT, VP, VD);
    }
    {
        dim3 g(VD / 128, VB * VNPAT / 128);
        bgemm_k<0><<<g, 256, 0, stream>>>(big, wT, patch_b, x, VB * VNPAT, VP, VD, VD);
    }
    pos_cls_k<<<(unsigned)((TOKD + 255) / 256), 256, 0, stream>>>(x, cls_tok);

    const size_t WSZ = (size_t)VNH * VD * VDQ;
    for (int l = 0; l < VL; l++) {
        wprep_k<<<6912, 256, 0, stream>>>(
            Wq + l * WSZ, Wk + l * WSZ, Wv + l * WSZ,
            proj_W + (size_t)l * VD * VD,
            mlp_W1 + (size_t)l * VD * VMLP,
            mlp_W2 + (size_t)l * VMLP * VD, wT);

        if (l == 0)
            layernorm_k<<<VTOK, 256, 0, stream>>>(x, tb, ln1_g, ln1_b);

        {
            // fused QKV GEMM: lean 128² 3-ring, grid 18 x 50 = 900 blocks
            dim3 g(3 * VD / 128, (VTOK + 127) / 128);
            bgemm10_k<1><<<g, 256, 0, stream>>>(tb, wT, cbA + l * 3 * VD, big,
                                                VTOK, VD, 3 * VD);
        }
        {
            dim3 ga(2, VB * VNH);
            attn3_k<<<ga, 256, 0, stream>>>(big, tb);
        }
        {
            // proj split-K=2 (lean 3-ring), then combine + residual + LN2
            dim3 g(VD / 128, (VTOK + 127) / 128, 2);
            bgemm9_k<<<g, 256, 0, stream>>>(tb, wT + OFF_PROJ, pbuf, VTOK, VD, VD);
            combineln_k<1><<<VTOK, 256, 0, stream>>>(
                x, pbuf, pbuf + TOKD, proj_b + l * VD,
                ln2_g + l * VD, ln2_b + l * VD, tb);
        }
        {
            // MLP1: lean 128² 3-ring + fast-GELU, grid 24 x 50 = 1200 blocks
            dim3 g(VMLP / 128, (VTOK + 127) / 128);
            bgemm10_k<3><<<g, 256, 0, stream>>>(tb, wT + OFF_M1, mlp_b1 + l * VMLP, big,
                                                VTOK, VD, VMLP);
        }
        {
            // MLP2 split-K=2 (lean 3-ring), then combine + residual (+ next LN1)
            dim3 g(VD / 128, (VTOK + 127) / 128, 2);
            bgemm9_k<<<g, 256, 0, stream>>>(big, wT + OFF_M2, pbuf, VTOK, VMLP, VD);
            if (l + 1 < VL)
                combineln_k<1><<<VTOK, 256, 0, stream>>>(
                    x, pbuf, pbuf + TOKD, mlp_b2 + l * VD,
                    ln1_g + (l + 1) * VD, ln1_b + (l + 1) * VD, tb);
            else
                combineln_k<0><<<VTOK, 256, 0, stream>>>(
                    x, pbuf, pbuf + TOKD, mlp_b2 + l * VD,
                    nullptr, nullptr, nullptr);
        }
    }
    cls_k<<<(VB * VD + 255) / 256, 256, 0, stream>>>(x, tb);
    {
        dim3 gt((VC + 31) / 32, VD / 32);
        tpose_k<<<gt, 256, 0, stream>>>(head_W, wT, VD, VC);
        dim3 g((VC + 127) / 128, 1);
        bgemm_k<4><<<g, 256, 0, stream>>>(tb, wT, head_b, (float*)d_out,
                                          VB, VD, VC, VC);
    }
}

// Round 14
// 2674.842 us; speedup vs baseline: 1.9637x; 1.0245x over previous
//
#include <hip/hip_runtime.h>
#include <hip/hip_bf16.h>
#include <math.h>
#include <stdint.h>

// ViT config
#define VB   32
#define VS   197
#define VD   768
#define VNH  12
#define VDQ  64
#define VL   12
#define VMLP 3072
#define VC   1000
#define VP   256
#define VNPAT 196
#define VTOK (VB * VS)            // 6304
#define TOKD ((size_t)VTOK * VD)  // 4841472 elems

typedef __attribute__((ext_vector_type(4))) float f32x4;
typedef __attribute__((ext_vector_type(8))) short short8;

typedef __attribute__((address_space(1))) const unsigned int GU;
typedef __attribute__((address_space(3))) unsigned int LU;

__device__ __forceinline__ void gload_lds16(const void* g, void* l) {
    __builtin_amdgcn_global_load_lds((GU*)(uintptr_t)g, (LU*)(uintptr_t)l, 16, 0, 0);
}

// T1: bijective XCD-aware block swizzle (m204).
__device__ __forceinline__ void xcd_swz(int gx, int gy, int& bx, int& by) {
    int nwg = gx * gy;
    int hw = by * gx + bx;
    int q = nwg >> 3, r = nwg & 7;
    int xcd = hw & 7, off = hw >> 3;
    int lid = (xcd < r ? xcd * (q + 1) : r * (q + 1) + (xcd - r) * q) + off;
    bx = lid % gx; by = lid / gx;
}

// Fast tanh-form GELU.
__device__ __forceinline__ float gelu_f(float x) {
    float t = 0.7978845608f * x * fmaf(0.044715f, x * x, 1.0f);
    float a = fminf(t * 2.8853900818f, 80.0f);
    float e = __builtin_amdgcn_exp2f(a);
    return x * e * __builtin_amdgcn_rcpf(1.0f + e);
}

// ---------------------------------------------------------------------------
__global__ void patchify_k(const float* __restrict__ X, __hip_bfloat16* __restrict__ P) {
    int idx = blockIdx.x * 256 + threadIdx.x;
    const int total = VB * VNPAT * VP;
    if (idx >= total) return;
    int i  = idx & 255;
    int p  = (idx >> 8) % VNPAT;
    int b  = (idx >> 8) / VNPAT;
    int pr = p / 14, pc = p % 14;
    int a  = i >> 4, c2 = i & 15;
    P[idx] = __float2bfloat16(X[((size_t)b * 224 + pr * 16 + a) * 224 + pc * 16 + c2]);
}

__global__ void pos_cls_k(float* __restrict__ x, const float* __restrict__ cls) {
    size_t idx = (size_t)blockIdx.x * 256 + threadIdx.x;
    if (idx >= TOKD) return;
    int j = (int)(idx % VD);
    int s = (int)((idx / VD) % VS);
    float jj = (float)(j & ~1);
    float freq = expf(-(jj / (float)VD) * 9.2103403719761836f);
    float ang  = (float)s * freq;
    float pe   = (j & 1) ? cosf(ang) : sinf(ang);
    if (s == 0) x[idx] = cls[j] + pe;
    else        x[idx] += pe;
}

__global__ __launch_bounds__(256) void layernorm_k(
    const float* __restrict__ x, __hip_bfloat16* __restrict__ y,
    const float* __restrict__ g, const float* __restrict__ bta)
{
    int t = blockIdx.x;
    const float* xr = x + (size_t)t * VD;
    __hip_bfloat16* yr = y + (size_t)t * VD;
    int tid = threadIdx.x;
    float v[3];
    float s = 0.f;
    #pragma unroll
    for (int i = 0; i < 3; i++) { v[i] = xr[tid + i * 256]; s += v[i]; }
    __shared__ float red[8];
    #pragma unroll
    for (int off = 32; off; off >>= 1) s += __shfl_xor(s, off);
    int lane = tid & 63, w = tid >> 6;
    if (!lane) red[w] = s;
    __syncthreads();
    float mu = (red[0] + red[1] + red[2] + red[3]) * (1.f / VD);
    float s2 = 0.f;
    #pragma unroll
    for (int i = 0; i < 3; i++) { float d0 = v[i] - mu; s2 += d0 * d0; }
    #pragma unroll
    for (int off = 32; off; off >>= 1) s2 += __shfl_xor(s2, off);
    if (!lane) red[4 + w] = s2;
    __syncthreads();
    float var = (red[4] + red[5] + red[6] + red[7]) * (1.f / VD);
    float rs = rsqrtf(var + 1e-5f);
    #pragma unroll
    for (int i = 0; i < 3; i++) {
        int j = tid + i * 256;
        yr[j] = __float2bfloat16((v[i] - mu) * rs * g[j] + bta[j]);
    }
}

// ---------------------------------------------------------------------------
// Fused split-K combine (bf16 partials) + residual + (optional) LayerNorm.
// ---------------------------------------------------------------------------
template<int DO_LN>
__global__ __launch_bounds__(256) void combineln_k(
    float* __restrict__ x, const __hip_bfloat16* __restrict__ p0,
    const __hip_bfloat16* __restrict__ p1,
    const float* __restrict__ bias, const float* __restrict__ g,
    const float* __restrict__ bta, __hip_bfloat16* __restrict__ y)
{
    int t = blockIdx.x;
    size_t base = (size_t)t * VD;
    int tid = threadIdx.x;
    float v[3];
    float s = 0.f;
    #pragma unroll
    for (int i = 0; i < 3; i++) {
        int j = tid + i * 256;
        float val = x[base + j] + __bfloat162float(p0[base + j])
                  + __bfloat162float(p1[base + j]) + bias[j];
        x[base + j] = val;
        v[i] = val; s += val;
    }
    if (DO_LN) {
        __shared__ float red[8];
        #pragma unroll
        for (int off = 32; off; off >>= 1) s += __shfl_xor(s, off);
        int lane = tid & 63, w = tid >> 6;
        if (!lane) red[w] = s;
        __syncthreads();
        float mu = (red[0] + red[1] + red[2] + red[3]) * (1.f / VD);
        float s2 = 0.f;
        #pragma unroll
        for (int i = 0; i < 3; i++) { float d0 = v[i] - mu; s2 += d0 * d0; }
        #pragma unroll
        for (int off = 32; off; off >>= 1) s2 += __shfl_xor(s2, off);
        if (!lane) red[4 + w] = s2;
        __syncthreads();
        float var = (red[4] + red[5] + red[6] + red[7]) * (1.f / VD);
        float rs = rsqrtf(var + 1e-5f);
        #pragma unroll
        for (int i = 0; i < 3; i++) {
            int j = tid + i * 256;
            y[base + j] = __float2bfloat16((v[i] - mu) * rs * g[j] + bta[j]);
        }
    }
}

__global__ __launch_bounds__(256) void tpose_k(
    const float* __restrict__ in, __hip_bfloat16* __restrict__ out, int R, int C)
{
    __shared__ float t[32][33];
    int c0 = blockIdx.x * 32, r0 = blockIdx.y * 32;
    int tc = threadIdx.x & 31, tr = threadIdx.x >> 5;
    #pragma unroll
    for (int p = 0; p < 4; p++) {
        int r = r0 + tr + p * 8;
        t[tr + p * 8][tc] = (r < R && c0 + tc < C) ? in[(size_t)r * C + c0 + tc] : 0.f;
    }
    __syncthreads();
    #pragma unroll
    for (int p = 0; p < 4; p++) {
        int c = c0 + tr + p * 8;
        if (c < C && r0 + tc < R)
            out[(size_t)c * R + r0 + tc] = __float2bfloat16(t[tc][tr + p * 8]);
    }
}

#define OFF_PROJ (2304 * 768)
#define OFF_M1   (OFF_PROJ + 768 * 768)
#define OFF_M2   (OFF_M1 + 3072 * 768)

__device__ __forceinline__ unsigned pack2bf(float a, float b) {
    __hip_bfloat16 x = __float2bfloat16(a), y = __float2bfloat16(b);
    unsigned short ux = *(unsigned short*)&x, uy = *(unsigned short*)&y;
    return (unsigned)ux | ((unsigned)uy << 16);
}

__global__ __launch_bounds__(256) void wprep_k(
    const float* __restrict__ Wq, const float* __restrict__ Wk,
    const float* __restrict__ Wv, const float* __restrict__ Wp,
    const float* __restrict__ W1, const float* __restrict__ W2,
    __hip_bfloat16* __restrict__ wT)
{
    __shared__ float t[32][33];
    int z = blockIdx.x;
    const float* src; __hip_bfloat16* dst;
    int C, ldd, r0, c0;
    if (z < 1728) {
        int head = z / 48, tt = z % 48;
        int m = head / VNH, h = head % VNH;
        src = (m == 0 ? Wq : m == 1 ? Wk : Wv) + (size_t)h * VD * VDQ;
        dst = wT + ((size_t)m * VD + h * VDQ) * VD;
        C = VDQ; ldd = VD;
        r0 = (tt >> 1) * 32; c0 = (tt & 1) * 32;
    } else if (z < 2304) {
        int z2 = z - 1728;
        src = Wp; dst = wT + OFF_PROJ;
        C = VD; ldd = VD;
        r0 = (z2 / 24) * 32; c0 = (z2 % 24) * 32;
    } else if (z < 4608) {
        int z3 = z - 2304;
        src = W1; dst = wT + OFF_M1;
        C = VMLP; ldd = VD;
        r0 = (z3 / 96) * 32; c0 = (z3 % 96) * 32;
    } else {
        int z4 = z - 4608;
        src = W2; dst = wT + OFF_M2;
        C = VD; ldd = VMLP;
        r0 = (z4 / 24) * 32; c0 = (z4 % 24) * 32;
    }
    int tid = threadIdx.x;
    {
        int r = tid >> 3, cq = (tid & 7) << 2;
        float4 v = *(const float4*)&src[(size_t)(r0 + r) * C + c0 + cq];
        t[r][cq] = v.x; t[r][cq + 1] = v.y; t[r][cq + 2] = v.z; t[r][cq + 3] = v.w;
    }
    __syncthreads();
    {
        int c = tid >> 3, rq = (tid & 7) << 2;
        unsigned u0 = pack2bf(t[rq][c],     t[rq + 1][c]);
        unsigned u1 = pack2bf(t[rq + 2][c], t[rq + 3][c]);
        unsigned* dp = (unsigned*)&dst[(size_t)(c0 + c) * ldd + r0 + rq];
        dp[0] = u0; dp[1] = u1;
    }
}

__global__ void cball_k(const float* __restrict__ bq, const float* __restrict__ bk,
                        const float* __restrict__ bv, float* __restrict__ cb) {
    int idx = blockIdx.x * 256 + threadIdx.x;
    if (idx >= VL * 3 * VD) return;
    int l = idx / (3 * VD), n = idx % (3 * VD);
    int m = n / VD, wi = n % VD;
    const float* p = (m == 0) ? bq : (m == 1) ? bk : bv;
    cb[idx] = p[l * VD + wi];
}

__global__ void cls_k(const float* __restrict__ x, __hip_bfloat16* __restrict__ out) {
    int idx = blockIdx.x * 256 + threadIdx.x;
    if (idx >= VB * VD) return;
    int b = idx / VD, d = idx % VD;
    out[idx] = __float2bfloat16(x[(size_t)b * VS * VD + d]);
}

// ---------------------------------------------------------------------------
// bf16 MFMA GEMM (m97-style 128x128) + XCD swizzle — patch/head only.
// ---------------------------------------------------------------------------
template<int EPI>
__global__ __launch_bounds__(256) void bgemm_k(
    const __hip_bfloat16* __restrict__ A,
    const __hip_bfloat16* __restrict__ BT,
    const float* __restrict__ bias,
    void* __restrict__ Co,
    int M, int K, int ldc, int Ncols)
{
    __shared__ short A_s[128][64];
    __shared__ short B_s[128][64];
    int bx = blockIdx.x, by = blockIdx.y;
    xcd_swz(gridDim.x, gridDim.y, bx, by);
    const int tid = threadIdx.x;
    const int w = tid >> 6, l = tid & 63;
    const int row0 = by * 128, col0 = bx * 128;
    const int wm = (w >> 1) << 6, wn = (w & 1) << 6;
    f32x4 acc[4][4] = {};

    const int lr = l >> 3;
    const int sslot = (l & 7) ^ lr;
    int arow[4], brow[4];
    #pragma unroll
    for (int i = 0; i < 4; i++) {
        int r = (4 * w + i) * 8 + lr;
        arow[i] = min(row0 + r, M - 1);
        brow[i] = min(col0 + r, Ncols - 1);
    }
    for (int k0 = 0; k0 < K; k0 += 64) {
        __syncthreads();
        #pragma unroll
        for (int i = 0; i < 4; i++) {
            int ch = 4 * w + i;
            gload_lds16((const void*)(A + (size_t)arow[i] * K + k0 + (sslot << 3)),
                        (void*)(&A_s[ch * 8][0]));
            gload_lds16((const void*)(BT + (size_t)brow[i] * K + k0 + (sslot << 3)),
                        (void*)(&B_s[ch * 8][0]));
        }
        __syncthreads();
        #pragma unroll
        for (int ks = 0; ks < 2; ks++) {
            const int s16 = (ks << 2) + (l >> 4);
            short8 av[4], bv[4];
            #pragma unroll
            for (int i = 0; i < 4; i++) {
                int ar = wm + i * 16 + (l & 15);
                av[i] = *(const short8*)((const char*)&A_s[ar][0] + ((s16 ^ (ar & 7)) << 4));
                int br = wn + i * 16 + (l & 15);
                bv[i] = *(const short8*)((const char*)&B_s[br][0] + ((s16 ^ (br & 7)) << 4));
            }
            #pragma unroll
            for (int i = 0; i < 4; i++)
                #pragma unroll
                for (int j = 0; j < 4; j++)
                    acc[i][j] = __builtin_amdgcn_mfma_f32_16x16x32_bf16(av[i], bv[j], acc[i][j], 0, 0, 0);
        }
    }
    const int rbase = row0 + wm + ((l >> 4) << 2);
    const int cbase = col0 + wn + (l & 15);
    #pragma unroll
    for (int i = 0; i < 4; i++) {
        #pragma unroll
        for (int q = 0; q < 4; q++) {
            int rr = rbase + i * 16 + q;
            if (rr >= M) continue;
            #pragma unroll
            for (int j = 0; j < 4; j++) {
                int c = cbase + j * 16;
                if (c >= Ncols) continue;
                float v = acc[i][j][q] + bias[c];
                if (EPI == 0) {
                    int orow = rr + rr / VNPAT + 1;
                    ((float*)Co)[(size_t)orow * ldc + c] = v;
                } else if (EPI == 1) {
                    ((__hip_bfloat16*)Co)[(size_t)rr * ldc + c] = __float2bfloat16(v);
                } else if (EPI == 2) {
                    ((float*)Co)[(size_t)rr * ldc + c] += v;
                } else if (EPI == 3) {
                    ((__hip_bfloat16*)Co)[(size_t)rr * ldc + c] = __float2bfloat16(gelu_f(v));
                } else {
                    ((float*)Co)[(size_t)rr * ldc + c] = v;
                }
            }
        }
    }
}

// ---------------------------------------------------------------------------
// bgemm10_k: lean 3-ring 128x128 full-K GEMM with bias + epilogue.
// (unchanged from r13 champion)
// ---------------------------------------------------------------------------
template<int EPI>
__global__ __launch_bounds__(256) void bgemm10_k(
    const __hip_bfloat16* __restrict__ A,
    const __hip_bfloat16* __restrict__ BT,
    const float* __restrict__ bias,
    __hip_bfloat16* __restrict__ Co,
    int M, int K, int ldc)
{
    __shared__ short SA[3][128][32];
    __shared__ short SB[3][128][32];
    int bx = blockIdx.x, by = blockIdx.y;
    xcd_swz(gridDim.x, gridDim.y, bx, by);

    const int tid = threadIdx.x;
    const int w = tid >> 6, l = tid & 63;
    const int fr = l & 15, g = l >> 4;
    const int row0 = by * 128, col0 = bx * 128;
    const int wm = (w >> 1) << 6, wn = (w & 1) << 6;
    f32x4 acc[4][4] = {};

    const __hip_bfloat16* aS[2]; const __hip_bfloat16* bS[2];
    int doff[2];
    #pragma unroll
    for (int q = 0; q < 2; q++) {
        int idx = tid + (q << 8);
        int r = idx >> 2;
        int s = (idx & 3) ^ ((r >> 1) & 3);
        aS[q] = A  + (size_t)min(row0 + r, M - 1) * K + s * 8;
        bS[q] = BT + (size_t)(col0 + r) * K + s * 8;
        doff[q] = idx << 4;
    }

    #define STG10(ring, t) { const int k0 = (t) << 5;                          \
        gload_lds16(aS[0] + k0, (char*)&SA[ring][0][0] + doff[0]);             \
        gload_lds16(aS[1] + k0, (char*)&SA[ring][0][0] + doff[1]);             \
        gload_lds16(bS[0] + k0, (char*)&SB[ring][0][0] + doff[0]);             \
        gload_lds16(bS[1] + k0, (char*)&SB[ring][0][0] + doff[1]); }

    const int nt = K >> 5;
    STG10(0, 0);
    STG10(1, 1);
    asm volatile("s_waitcnt vmcnt(4)" ::: "memory");
    __builtin_amdgcn_s_barrier();

    for (int t = 0; t < nt; t++) {
        const int ring = t % 3;
        const int rs   = (t + 2) % 3;
        const char* sa = (const char*)&SA[ring][0][0];
        const char* sb = (const char*)&SB[ring][0][0];
        short8 av[4], bv[4];
        #pragma unroll
        for (int i = 0; i < 4; i++) {
            int ar = wm + i * 16 + fr;
            av[i] = *(const short8*)(sa + ar * 64 + ((g ^ ((ar >> 1) & 3)) << 4));
            int br = wn + i * 16 + fr;
            bv[i] = *(const short8*)(sb + br * 64 + ((g ^ ((br >> 1) & 3)) << 4));
        }
        if (t + 2 < nt) STG10(rs, t + 2);
        asm volatile("s_waitcnt lgkmcnt(0)" ::: "memory");
        __builtin_amdgcn_sched_barrier(0);
        __builtin_amdgcn_s_setprio(1);
        #pragma unroll
        for (int i = 0; i < 4; i++)
            #pragma unroll
            for (int j = 0; j < 4; j++)
                acc[i][j] = __builtin_amdgcn_mfma_f32_16x16x32_bf16(av[i], bv[j], acc[i][j], 0, 0, 0);
        __builtin_amdgcn_s_setprio(0);
        if (t + 2 < nt) {
            asm volatile("s_waitcnt vmcnt(4)" ::: "memory");
            __builtin_amdgcn_s_barrier();
        } else if (t + 1 < nt) {
            asm volatile("s_waitcnt vmcnt(0)" ::: "memory");
            __builtin_amdgcn_s_barrier();
        }
    }
    #undef STG10

    const int rbase = row0 + wm + (g << 2);
    const int cbase = col0 + wn + fr;
    #pragma unroll
    for (int i = 0; i < 4; i++) {
        #pragma unroll
        for (int q = 0; q < 4; q++) {
            int rr = rbase + i * 16 + q;
            if (rr >= M) continue;
            #pragma unroll
            for (int j = 0; j < 4; j++) {
                int c = cbase + j * 16;
                float v = acc[i][j][q] + bias[c];
                if (EPI == 3) v = gelu_f(v);
                Co[(size_t)rr * ldc + c] = __float2bfloat16(v);
            }
        }
    }
}

// ---------------------------------------------------------------------------
// bgemm9_k: split-K=2 partial GEMM, lean 3-ring 128x128 (proj / MLP2).
// NOW writes bf16 partials (halves write + combine-read traffic; partial
// magnitudes O(0.5) -> bf16 round err ~2e-3, negligible vs 0.071 threshold).
// ---------------------------------------------------------------------------
__global__ __launch_bounds__(256) void bgemm9_k(
    const __hip_bfloat16* __restrict__ A,
    const __hip_bfloat16* __restrict__ BT,
    __hip_bfloat16* __restrict__ P,
    int M, int K, int ldc)
{
    __shared__ short SA[3][128][32];
    __shared__ short SB[3][128][32];
    int bx = blockIdx.x, by = blockIdx.y;
    xcd_swz(gridDim.x, gridDim.y, bx, by);
    const int ks = blockIdx.z;
    const int khalf = K >> 1;
    const __hip_bfloat16* Ab  = A  + (size_t)ks * khalf;
    const __hip_bfloat16* BTb = BT + (size_t)ks * khalf;
    __hip_bfloat16* Pb = P + (size_t)ks * TOKD;

    const int tid = threadIdx.x;
    const int w = tid >> 6, l = tid & 63;
    const int fr = l & 15, g = l >> 4;
    const int row0 = by * 128, col0 = bx * 128;
    const int wm = (w >> 1) << 6, wn = (w & 1) << 6;
    f32x4 acc[4][4] = {};

    const __hip_bfloat16* aS[2]; const __hip_bfloat16* bS[2];
    int doff[2];
    #pragma unroll
    for (int q = 0; q < 2; q++) {
        int idx = tid + (q << 8);
        int r = idx >> 2;
        int s = (idx & 3) ^ ((r >> 1) & 3);
        aS[q] = Ab  + (size_t)min(row0 + r, M - 1) * K + s * 8;
        bS[q] = BTb + (size_t)(col0 + r) * K + s * 8;
        doff[q] = idx << 4;
    }

    #define STG9(ring, t) { const int k0 = (t) << 5;                           \
        gload_lds16(aS[0] + k0, (char*)&SA[ring][0][0] + doff[0]);             \
        gload_lds16(aS[1] + k0, (char*)&SA[ring][0][0] + doff[1]);             \
        gload_lds16(bS[0] + k0, (char*)&SB[ring][0][0] + doff[0]);             \
        gload_lds16(bS[1] + k0, (char*)&SB[ring][0][0] + doff[1]); }

    const int nt = khalf >> 5;
    STG9(0, 0);
    STG9(1, 1);
    asm volatile("s_waitcnt vmcnt(4)" ::: "memory");
    __builtin_amdgcn_s_barrier();

    for (int t = 0; t < nt; t++) {
        const int ring = t % 3;
        const int rs   = (t + 2) % 3;
        const char* sa = (const char*)&SA[ring][0][0];
        const char* sb = (const char*)&SB[ring][0][0];
        short8 av[4], bv[4];
        #pragma unroll
        for (int i = 0; i < 4; i++) {
            int ar = wm + i * 16 + fr;
            av[i] = *(const short8*)(sa + ar * 64 + ((g ^ ((ar >> 1) & 3)) << 4));
            int br = wn + i * 16 + fr;
            bv[i] = *(const short8*)(sb + br * 64 + ((g ^ ((br >> 1) & 3)) << 4));
        }
        if (t + 2 < nt) STG9(rs, t + 2);
        asm volatile("s_waitcnt lgkmcnt(0)" ::: "memory");
        __builtin_amdgcn_sched_barrier(0);
        __builtin_amdgcn_s_setprio(1);
        #pragma unroll
        for (int i = 0; i < 4; i++)
            #pragma unroll
            for (int j = 0; j < 4; j++)
                acc[i][j] = __builtin_amdgcn_mfma_f32_16x16x32_bf16(av[i], bv[j], acc[i][j], 0, 0, 0);
        __builtin_amdgcn_s_setprio(0);
        if (t + 2 < nt) {
            asm volatile("s_waitcnt vmcnt(4)" ::: "memory");
            __builtin_amdgcn_s_barrier();
        } else if (t + 1 < nt) {
            asm volatile("s_waitcnt vmcnt(0)" ::: "memory");
            __builtin_amdgcn_s_barrier();
        }
    }
    #undef STG9

    const int rbase = row0 + wm + (g << 2);
    const int cbase = col0 + wn + fr;
    #pragma unroll
    for (int i = 0; i < 4; i++) {
        #pragma unroll
        for (int q = 0; q < 4; q++) {
            int rr = rbase + i * 16 + q;
            if (rr >= M) continue;
            #pragma unroll
            for (int j = 0; j < 4; j++) {
                int c = cbase + j * 16;
                Pb[(size_t)rr * ldc + c] = __float2bfloat16(acc[i][j][q]);
            }
        }
    }
}

// ---------------------------------------------------------------------------
// MFMA attention. Two blocks per (b,h), 256 threads, 4 waves.
// ---------------------------------------------------------------------------
__device__ __forceinline__ int swz_idx(int row, int k) {
    return row * 256 + (((k >> 3) ^ (row & 7)) << 3) + (k & 7);
}

__global__ __launch_bounds__(256) void attn3_k(
    const __hip_bfloat16* __restrict__ qkv, __hip_bfloat16* __restrict__ o)
{
    __shared__ short V_t[64 * 256];
    __shared__ short P_s[4][16 * 256];
    const int half = blockIdx.x;
    const int bh = blockIdx.y;
    const int b = bh / VNH, h = bh % VNH;
    const int tid = threadIdx.x, w = tid >> 6, l = tid & 63;
    const int g = l >> 4, c16 = l & 15;

    const __hip_bfloat16* base = qkv + (size_t)(b * VS) * (3 * VD) + h * VDQ;

    {
        const __hip_bfloat16* vbase = base + 2 * VD;
        int t = tid & 31, e0 = (tid >> 5) * 8;
        #pragma unroll
        for (int it = 0; it < 7; it++) {
            int tt = it * 32 + t;
            if (tt < VS) {
                short8 vv = *(const short8*)(vbase + (size_t)tt * (3 * VD) + e0);
                #pragma unroll
                for (int j = 0; j < 8; j++) V_t[swz_idx(e0 + j, tt)] = vv[j];
            }
        }
        for (int idx = tid; idx < 64 * 27; idx += 256) {
            int e = idx / 27, k = 197 + idx % 27;
            V_t[swz_idx(e, k)] = 0;
        }
    }
    {
        unsigned* p0 = (unsigned*)&P_s[w][swz_idx(c16, 208 + g * 4)];
        p0[0] = 0; p0[1] = 0;
    }
    __syncthreads();

    const int qt_end = half ? 13 : 7;
    for (int qt = 7 * half + w; qt < qt_end; qt += 4) {
        const int q0 = qt * 16;
        int qr = min(q0 + c16, VS - 1);
        const __hip_bfloat16* qp = base + (size_t)qr * (3 * VD) + g * 8;
        short8 qa0 = *(const short8*)(qp);
        short8 qa1 = *(const short8*)(qp + 32);

        f32x4 st[13];
        __builtin_amdgcn_s_setprio(1);
        #pragma unroll
        for (int t = 0; t < 13; t++) {
            int kr = min(t * 16 + c16, VS - 1);
            const __hip_bfloat16* kp = base + VD + (size_t)kr * (3 * VD) + g * 8;
            short8 ka0 = *(const short8*)(kp);
            short8 ka1 = *(const short8*)(kp + 32);
            f32x4 z = {};
            z = __builtin_amdgcn_mfma_f32_16x16x32_bf16(ka0, qa0, z, 0, 0, 0);
            z = __builtin_amdgcn_mfma_f32_16x16x32_bf16(ka1, qa1, z, 0, 0, 0);
            st[t] = z;
        }
        __builtin_amdgcn_s_setprio(0);
        #pragma unroll
        for (int t = 0; t < 13; t++) {
            #pragma unroll
            for (int r = 0; r < 4; r++) {
                float v = st[t][r] * 0.125f;
                if (t == 12 && (4 * g + r) >= 5) v = -3.0e38f;
                st[t][r] = v;
            }
        }
        float m = -3.0e38f;
        #pragma unroll
        for (int t = 0; t < 13; t++)
            #pragma unroll
            for (int r = 0; r < 4; r++) m = fmaxf(m, st[t][r]);
        m = fmaxf(m, __shfl_xor(m, 16));
        m = fmaxf(m, __shfl_xor(m, 32));
        float sum = 0.f;
        #pragma unroll
        for (int t = 0; t < 13; t++)
            #pragma unroll
            for (int r = 0; r < 4; r++) { float e = expf(st[t][r] - m); st[t][r] = e; sum += e; }
        sum += __shfl_xor(sum, 16);
        sum += __shfl_xor(sum, 32);
        float inv = 1.f / sum;
        #pragma unroll
        for (int t = 0; t < 13; t++) {
            int k0 = 16 * t + 4 * g;
            unsigned* pp = (unsigned*)&P_s[w][swz_idx(c16, k0)];
            pp[0] = pack2bf(st[t][0] * inv, st[t][1] * inv);
            pp[1] = pack2bf(st[t][2] * inv, st[t][3] * inv);
        }
        f32x4 acc[4] = {};
        __builtin_amdgcn_s_setprio(1);
        #pragma unroll
        for (int ki = 0; ki < 7; ki++) {
            int k0 = ki * 32 + g * 8;
            short8 pa = *(const short8*)&P_s[w][swz_idx(c16, k0)];
            #pragma unroll
            for (int et = 0; et < 4; et++) {
                short8 vbf = *(const short8*)&V_t[swz_idx(et * 16 + c16, k0)];
                acc[et] = __builtin_amdgcn_mfma_f32_16x16x32_bf16(pa, vbf, acc[et], 0, 0, 0);
            }
        }
        __builtin_amdgcn_s_setprio(0);
        #pragma unroll
        for (int et = 0; et < 4; et++) {
            #pragma unroll
            for (int r = 0; r < 4; r++) {
                int q = q0 + 4 * g + r;
                if (q < VS)
                    o[((size_t)(b * VS) + q) * VD + h * VDQ + et * 16 + c16] =
                        __float2bfloat16(acc[et][r]);
            }
        }
    }
}

// ---------------------------------------------------------------------------
extern "C" void kernel_launch(void* const* d_in, const int* in_sizes, int n_in,
                              void* d_out, int out_size, void* d_ws, size_t ws_size,
                              hipStream_t stream) {
    (void)in_sizes; (void)n_in; (void)out_size; (void)ws_size;
    const float* X       = (const float*)d_in[0];
    const float* patch_W = (const float*)d_in[1];
    const float* patch_b = (const float*)d_in[2];
    const float* cls_tok = (const float*)d_in[3];
    const float* ln1_g   = (const float*)d_in[4];
    const float* ln1_b   = (const float*)d_in[5];
    const float* Wq      = (const float*)d_in[6];
    const float* bq      = (const float*)d_in[7];
    const float* Wk      = (const float*)d_in[8];
    const float* bk      = (const float*)d_in[9];
    const float* Wv      = (const float*)d_in[10];
    const float* bv      = (const float*)d_in[11];
    const float* proj_W  = (const float*)d_in[12];
    const float* proj_b  = (const float*)d_in[13];
    const float* ln2_g   = (const float*)d_in[14];
    const float* ln2_b   = (const float*)d_in[15];
    const float* mlp_W1  = (const float*)d_in[16];
    const float* mlp_b1  = (const float*)d_in[17];
    const float* mlp_W2  = (const float*)d_in[18];
    const float* mlp_b2  = (const float*)d_in[19];
    const float* head_W  = (const float*)d_in[20];
    const float* head_b  = (const float*)d_in[21];

    char* ws = (char*)d_ws;
    float*          x    = (float*)ws;                            // 19.37 MB fp32
    __hip_bfloat16* tb   = (__hip_bfloat16*)(ws + 19365888);      // 9.68 MB bf16
    __hip_bfloat16* big  = (__hip_bfloat16*)(ws + 29048832);      // 38.73 MB
    __hip_bfloat16* wT   = (__hip_bfloat16*)(ws + 67780608);      // 14.16 MB
    float*          cbA  = (float*)(ws + 81936384);               // 110 KB
    __hip_bfloat16* pbuf = (__hip_bfloat16*)(ws + 82046976);      // 19.37 MB (2x TOKD bf16)

    cball_k<<<(VL * 3 * VD + 255) / 256, 256, 0, stream>>>(bq, bk, bv, cbA);

    patchify_k<<<(VB * VNPAT * VP + 255) / 256, 256, 0, stream>>>(X, big);
    {
        dim3 g(VD / 32, VP / 32);
        tpose_k<<<g, 256, 0, stream>>>(patch_W, wT, VP, VD);
    }
    {
        dim3 g(VD / 128, VB * VNPAT / 128);
        bgemm_k<0><<<g, 256, 0, stream>>>(big, wT, patch_b, x, VB * VNPAT, VP, VD, VD);
    }
    pos_cls_k<<<(unsigned)((TOKD + 255) / 256), 256, 0, stream>>>(x, cls_tok);

    const size_t WSZ = (size_t)VNH * VD * VDQ;
    for (int l = 0; l < VL; l++) {
        wprep_k<<<6912, 256, 0, stream>>>(
            Wq + l * WSZ, Wk + l * WSZ, Wv + l * WSZ,
            proj_W + (size_t)l * VD * VD,
            mlp_W1 + (size_t)l * VD * VMLP,
            mlp_W2 + (size_t)l * VMLP * VD, wT);

        if (l == 0)
            layernorm_k<<<VTOK, 256, 0, stream>>>(x, tb, ln1_g, ln1_b);

        {
            // fused QKV GEMM: lean 128² 3-ring, grid 18 x 50
            dim3 g(3 * VD / 128, (VTOK + 127) / 128);
            bgemm10_k<1><<<g, 256, 0, stream>>>(tb, wT, cbA + l * 3 * VD, big,
                                                VTOK, VD, 3 * VD);
        }
        {
            dim3 ga(2, VB * VNH);
            attn3_k<<<ga, 256, 0, stream>>>(big, tb);
        }
        {
            // proj split-K=2 (bf16 partials), then combine + residual + LN2
            dim3 g(VD / 128, (VTOK + 127) / 128, 2);
            bgemm9_k<<<g, 256, 0, stream>>>(tb, wT + OFF_PROJ, pbuf, VTOK, VD, VD);
            combineln_k<1><<<VTOK, 256, 0, stream>>>(
                x, pbuf, pbuf + TOKD, proj_b + l * VD,
                ln2_g + l * VD, ln2_b + l * VD, tb);
        }
        {
            // MLP1: lean 128² 3-ring + fast-GELU, grid 24 x 50
            dim3 g(VMLP / 128, (VTOK + 127) / 128);
            bgemm10_k<3><<<g, 256, 0, stream>>>(tb, wT + OFF_M1, mlp_b1 + l * VMLP, big,
                                                VTOK, VD, VMLP);
        }
        {
            // MLP2 split-K=2 (bf16 partials), then combine + residual (+ next LN1)
            dim3 g(VD / 128, (VTOK + 127) / 128, 2);
            bgemm9_k<<<g, 256, 0, stream>>>(big, wT + OFF_M2, pbuf, VTOK, VMLP, VD);
            if (l + 1 < VL)
                combineln_k<1><<<VTOK, 256, 0, stream>>>(
                    x, pbuf, pbuf + TOKD, mlp_b2 + l * VD,
                    ln1_g + (l + 1) * VD, ln1_b + (l + 1) * VD, tb);
            else
                combineln_k<0><<<VTOK, 256, 0, stream>>>(
                    x, pbuf, pbuf + TOKD, mlp_b2 + l * VD,
                    nullptr, nullptr, nullptr);
        }
    }
    cls_k<<<(VB * VD + 255) / 256, 256, 0, stream>>>(x, tb);
    {
        dim3 gt((VC + 31) / 32, VD / 32);
        tpose_k<<<gt, 256, 0, stream>>>(head_W, wT, VD, VC);
        dim3 g((VC + 127) / 128, 1);
        bgemm_k<4><<<g, 256, 0, stream>>>(tb, wT, head_b, (float*)d_out,
                                          VB, VD, VC, VC);
    }
}